// Round 1
// baseline (514.471 us; speedup 1.0000x reference)
//
#include <hip/hip_runtime.h>
#include <math.h>

#define NB 2
#define NN 2304        // 48*48
#define CIN 256
#define NHEADS 8
#define DH 32
#define KSPLIT 6
#define KCHUNK (NN / KSPLIT)   // 384

// ---------------- weight transposes (tiny, once per call) ----------------
__global__ void k_transpose(const float* __restrict__ wqkv, const float* __restrict__ wproj,
                            const float* __restrict__ wg, const float* __restrict__ wbt,
                            const float* __restrict__ wc2,
                            float* __restrict__ tqkv, float* __restrict__ tproj,
                            float* __restrict__ tg, float* __restrict__ tbt,
                            float* __restrict__ tc2) {
    int i = blockIdx.x * 256 + threadIdx.x;
    if (i < 768 * 256) {                 // wqkv [768][256] -> tqkv [256][768]
        int o = i / 256, c = i % 256;
        tqkv[c * 768 + o] = wqkv[i];
    }
    if (i < 256 * 256) {                 // wproj [256][256] -> tproj [256][256]
        int o = i / 256, c = i % 256;
        tproj[c * 256 + o] = wproj[i];
    }
    if (i < 256 * 128) {                 // wg/wbt [256][128] -> [128][256]
        int o = i / 128, c = i % 128;
        tg[c * 256 + o] = wg[i];
        tbt[c * 256 + o] = wbt[i];
    }
    if (i < 128 * 128 * 9) {             // wc2 [o=128][ic=128][3][3] -> [ic][9][o=128]
        int o = i / 1152;
        int rem = i % 1152;
        int ic = rem / 9, kk = rem % 9;
        tc2[(ic * 9 + kk) * 128 + o] = wc2[i];
    }
}

// ---------------- conv1: luma(1) -> h1(128), 3x3, relu ----------------
__global__ void k_conv1(const float* __restrict__ luma, const float* __restrict__ w,
                        const float* __restrict__ bias, float* __restrict__ h1) {
    int idx = blockIdx.x * 256 + threadIdx.x;      // NB*128*NN
    if (idx >= NB * 128 * NN) return;
    int x = idx % 48, y = (idx / 48) % 48, c = (idx / NN) % 128, b = idx / (128 * NN);
    const float* lb = luma + b * NN;
    float acc = bias[c];
#pragma unroll
    for (int ky = 0; ky < 3; ++ky) {
        int yy = y + ky - 1;
        if (yy < 0 || yy >= 48) continue;
#pragma unroll
        for (int kx = 0; kx < 3; ++kx) {
            int xx = x + kx - 1;
            if (xx < 0 || xx >= 48) continue;
            acc += w[c * 9 + ky * 3 + kx] * lb[yy * 48 + xx];
        }
    }
    h1[idx] = fmaxf(acc, 0.f);
}

// ---------------- conv2: h1(128) -> h2(128), 3x3, relu ----------------
// block 256: tid%128 = out channel c (coalesced weight reads), tid/128 = spatial half
// grid: NB * 144 (each block covers 16 spatial positions, row-aligned since 48%16==0)
__global__ void k_conv2(const float* __restrict__ h1, const float* __restrict__ tw,
                        const float* __restrict__ bias, float* __restrict__ h2) {
    int c = threadIdx.x & 127;
    int half = threadIdx.x >> 7;
    int sp = blockIdx.x % 144;
    int b = blockIdx.x / 144;
    int n0 = sp * 16 + half * 8;
    int y = n0 / 48, x0 = n0 % 48;
    float bv = bias[c];
    float acc[8];
#pragma unroll
    for (int i = 0; i < 8; ++i) acc[i] = bv;
    const float* h1b = h1 + b * 128 * NN;
    for (int ky = 0; ky < 3; ++ky) {
        int yy = y + ky - 1;
        if (yy < 0 || yy >= 48) continue;
        for (int ic = 0; ic < 128; ++ic) {
            const float* row = h1b + ic * NN + yy * 48;
            float win[10];
#pragma unroll
            for (int t = 0; t < 10; ++t) {
                int xx = x0 - 1 + t;
                win[t] = (xx >= 0 && xx < 48) ? row[xx] : 0.f;
            }
            const float* wp = tw + (ic * 9 + ky * 3) * 128 + c;
            float w0 = wp[0], w1 = wp[128], w2 = wp[256];
#pragma unroll
            for (int i = 0; i < 8; ++i)
                acc[i] += w0 * win[i] + w1 * win[i + 1] + w2 * win[i + 2];
        }
    }
    float* out = h2 + b * 128 * NN + c * NN + n0;
#pragma unroll
    for (int i = 0; i < 8; ++i) out[i] = fmaxf(acc[i], 0.f);
}

// ---------------- gamma/beta 1x1 convs -> transposed [b][n][256] ----------------
// grid: NB*144, block 256 (thread = out channel o), 16 n per thread
__global__ void k_gammabeta(const float* __restrict__ h2, const float* __restrict__ twg,
                            const float* __restrict__ twbt, const float* __restrict__ bg,
                            const float* __restrict__ bbt,
                            float* __restrict__ gt, float* __restrict__ btt) {
    int o = threadIdx.x;
    int nc = blockIdx.x % 144, b = blockIdx.x / 144;
    int n0 = nc * 16;
    float ag[16], ab[16];
    float bgv = bg[o], bbv = bbt[o];
#pragma unroll
    for (int i = 0; i < 16; ++i) { ag[i] = bgv; ab[i] = bbv; }
    const float* h2b = h2 + b * 128 * NN + n0;
    for (int ic = 0; ic < 128; ++ic) {
        float wgv = twg[ic * 256 + o];
        float wbv = twbt[ic * 256 + o];
        const float* hp = h2b + ic * NN;
#pragma unroll
        for (int i = 0; i < 16; ++i) {
            float hv = hp[i];
            ag[i] += wgv * hv;
            ab[i] += wbv * hv;
        }
    }
#pragma unroll
    for (int i = 0; i < 16; ++i) {
        gt[(b * NN + n0 + i) * 256 + o] = ag[i];
        btt[(b * NN + n0 + i) * 256 + o] = ab[i];
    }
}

// ---------------- invL: avgpool3x3(1-luma) centered per batch ----------------
__global__ void k_invl(const float* __restrict__ luma, float* __restrict__ invl) {
    __shared__ float red[256];
    int b = blockIdx.x;
    const float* lb = luma + b * NN;
    float pooled[9];
    float local = 0.f;
#pragma unroll
    for (int it = 0; it < 9; ++it) {
        int n = it * 256 + threadIdx.x;
        int y = n / 48, x = n % 48;
        float s = 0.f;
        for (int ky = 0; ky < 3; ++ky) {
            int yy = y + ky - 1;
            if (yy < 0 || yy >= 48) continue;
            for (int kx = 0; kx < 3; ++kx) {
                int xx = x + kx - 1;
                if (xx < 0 || xx >= 48) continue;
                s += 1.f - lb[yy * 48 + xx];
            }
        }
        s *= (1.f / 9.f);
        pooled[it] = s;
        local += s;
    }
    red[threadIdx.x] = local;
    __syncthreads();
    for (int off = 128; off > 0; off >>= 1) {
        if (threadIdx.x < off) red[threadIdx.x] += red[threadIdx.x + off];
        __syncthreads();
    }
    float mean = red[0] * (1.f / NN);
#pragma unroll
    for (int it = 0; it < 9; ++it) {
        int n = it * 256 + threadIdx.x;
        invl[b * NN + n] = pooled[it] - mean;
    }
}

// ---------------- qkv 1x1 conv + gamma/beta modulation + invL bias ----------------
// grid: NB*3*144, block 256 (thread = channel within q/k/v), 16 n per thread
__global__ void k_qkv(const float* __restrict__ x, const float* __restrict__ twqkv,
                      const float* __restrict__ bqkv, const float* __restrict__ gt,
                      const float* __restrict__ btt, const float* __restrict__ invl,
                      const float* __restrict__ alpha_p,
                      float* __restrict__ q, float* __restrict__ k, float* __restrict__ v) {
    int lane_o = threadIdx.x;
    int blk = blockIdx.x;
    int nc = blk % 144;
    int which = (blk / 144) % 3;
    int b = blk / (144 * 3);
    int oc = which * 256 + lane_o;
    int n0 = nc * 16;
    float acc[16];
    float bv = bqkv[oc];
#pragma unroll
    for (int i = 0; i < 16; ++i) acc[i] = bv;
    const float* xb = x + b * CIN * NN + n0;
    for (int ic = 0; ic < CIN; ++ic) {
        float w = twqkv[ic * 768 + oc];
        const float* xp = xb + ic * NN;
#pragma unroll
        for (int i = 0; i < 16; ++i) acc[i] += w * xp[i];
    }
    int c = lane_o;
    int h = c >> 5, d = c & 31;
    float alpha = *alpha_p;
    float* dst = (which == 0) ? q : (which == 1) ? k : v;
#pragma unroll
    for (int i = 0; i < 16; ++i) {
        int n = n0 + i;
        float g = gt[(b * NN + n) * 256 + c];
        float bt = btt[(b * NN + n) * 256 + c];
        float val = g * acc[i] + bt;
        if (which == 0) val += alpha * invl[b * NN + n];
        dst[((b * NHEADS + h) * NN + n) * DH + d] = val;
    }
}

// ---------------- attention partials: flash-style online softmax ----------------
// grid: 16 * 36 * KSPLIT blocks, block = 64 (1 wave, thread = query row)
__global__ void k_attn(const float* __restrict__ q, const float* __restrict__ k,
                       const float* __restrict__ v, float* __restrict__ pm,
                       float* __restrict__ pl, float* __restrict__ pacc) {
    int blk = blockIdx.x;
    int ks = blk % KSPLIT;
    int qt = (blk / KSPLIT) % 36;
    int bh = blk / (KSPLIT * 36);
    int r = qt * 64 + threadIdx.x;
    const float scale = 0.17677669529663687f;   // 32^-0.5
    float qr[DH];
    const float* qp = q + (bh * NN + r) * DH;
#pragma unroll
    for (int d = 0; d < DH; ++d) qr[d] = qp[d] * scale;
    float m = -1e30f, l = 0.f;
    float acc[DH];
#pragma unroll
    for (int d = 0; d < DH; ++d) acc[d] = 0.f;
    const float* kb = k + (bh * NN + ks * KCHUNK) * DH;
    const float* vb = v + (bh * NN + ks * KCHUNK) * DH;
    for (int j = 0; j < KCHUNK; ++j) {
        const float* kp = kb + j * DH;   // wave-uniform address
        float s = 0.f;
#pragma unroll
        for (int d = 0; d < DH; ++d) s += qr[d] * kp[d];
        if (s > m) {
            float corr = __expf(m - s);
            l *= corr;
#pragma unroll
            for (int d = 0; d < DH; ++d) acc[d] *= corr;
            m = s;
        }
        float p = __expf(s - m);
        l += p;
        const float* vp = vb + j * DH;   // wave-uniform address
#pragma unroll
        for (int d = 0; d < DH; ++d) acc[d] += p * vp[d];
    }
    int base = (bh * NN + r) * KSPLIT + ks;
    pm[base] = m;
    pl[base] = l;
    float* pa = pacc + base * DH;
#pragma unroll
    for (int d = 0; d < DH; ++d) pa[d] = acc[d];
}

// ---------------- merge key-splits -> attention out, transposed [b][n][256] ----------------
// thread t -> (bh, r, d), d fastest for coalesced pacc reads
__global__ void k_merge(const float* __restrict__ pm, const float* __restrict__ pl,
                        const float* __restrict__ pacc, float* __restrict__ aot) {
    int t = blockIdx.x * 256 + threadIdx.x;     // 16*NN*32 total
    if (t >= 16 * NN * DH) return;
    int d = t & 31;
    int rr = (t >> 5) % NN;
    int bh = t / (NN * DH);
    int idx = bh * NN + rr;
    float M = -1e30f;
    float mv[KSPLIT];
#pragma unroll
    for (int s = 0; s < KSPLIT; ++s) {
        mv[s] = pm[idx * KSPLIT + s];
        M = fmaxf(M, mv[s]);
    }
    float L = 0.f;
    float ev[KSPLIT];
#pragma unroll
    for (int s = 0; s < KSPLIT; ++s) {
        ev[s] = __expf(mv[s] - M);
        L += pl[idx * KSPLIT + s] * ev[s];
    }
    float a = 0.f;
#pragma unroll
    for (int s = 0; s < KSPLIT; ++s) a += pacc[(idx * KSPLIT + s) * DH + d] * ev[s];
    int b = bh >> 3, h = bh & 7;
    aot[(b * NN + rr) * 256 + h * DH + d] = a / L;
}

// ---------------- output projection ----------------
// grid: NB*144, block 256 (thread = out channel o), 16 n per thread
__global__ void k_proj(const float* __restrict__ aot, const float* __restrict__ twproj,
                       const float* __restrict__ bproj, float* __restrict__ out) {
    int o = threadIdx.x;
    int nc = blockIdx.x % 144, b = blockIdx.x / 144;
    int n0 = nc * 16;
    float acc[16];
    float bv = bproj[o];
#pragma unroll
    for (int i = 0; i < 16; ++i) acc[i] = bv;
    const float* ab = aot + (b * NN + n0) * 256;
    for (int c = 0; c < 256; ++c) {
        float w = twproj[c * 256 + o];
#pragma unroll
        for (int i = 0; i < 16; ++i) acc[i] += w * ab[i * 256 + c];
    }
    float* op = out + (b * 256 + o) * NN + n0;
#pragma unroll
    for (int i = 0; i < 16; ++i) op[i] = acc[i];
}

extern "C" void kernel_launch(void* const* d_in, const int* in_sizes, int n_in,
                              void* d_out, int out_size, void* d_ws, size_t ws_size,
                              hipStream_t stream) {
    const float* x     = (const float*)d_in[0];
    const float* luma  = (const float*)d_in[1];
    const float* wqkv  = (const float*)d_in[2];
    const float* bqkv  = (const float*)d_in[3];
    const float* wproj = (const float*)d_in[4];
    const float* bproj = (const float*)d_in[5];
    const float* wc1   = (const float*)d_in[6];
    const float* bc1   = (const float*)d_in[7];
    const float* wc2   = (const float*)d_in[8];
    const float* bc2   = (const float*)d_in[9];
    const float* wg    = (const float*)d_in[10];
    const float* bg    = (const float*)d_in[11];
    const float* wbt   = (const float*)d_in[12];
    const float* bbt   = (const float*)d_in[13];
    const float* alpha = (const float*)d_in[14];
    float* out = (float*)d_out;

    float* ws = (float*)d_ws;
    size_t off = 0;
    float* tqkv = ws + off;  off += 256 * 768;
    float* tproj = ws + off; off += 256 * 256;
    float* tg = ws + off;    off += 128 * 256;
    float* tbt = ws + off;   off += 128 * 256;
    float* tc2 = ws + off;   off += 128 * 9 * 128;
    float* h1 = ws + off;    off += NB * 128 * NN;
    float* h2 = ws + off;    off += NB * 128 * NN;
    float* gt = ws + off;    off += NB * NN * 256;
    float* btt = ws + off;   off += NB * NN * 256;
    float* invl = ws + off;  off += NB * NN;
    float* q = ws + off;     off += NB * NHEADS * NN * DH;
    float* kk = ws + off;    off += NB * NHEADS * NN * DH;
    float* vv = ws + off;    off += NB * NHEADS * NN * DH;
    float* pm = ws + off;    off += 16 * NN * KSPLIT;
    float* pl = ws + off;    off += 16 * NN * KSPLIT;
    float* pacc = ws + off;  off += 16 * NN * KSPLIT * DH;
    float* aot = ws + off;   off += NB * NN * 256;
    (void)ws_size; (void)in_sizes; (void)n_in; (void)out_size;

    k_transpose<<<768, 256, 0, stream>>>(wqkv, wproj, wg, wbt, wc2, tqkv, tproj, tg, tbt, tc2);
    k_conv1<<<(NB * 128 * NN + 255) / 256, 256, 0, stream>>>(luma, wc1, bc1, h1);
    k_conv2<<<NB * 144, 256, 0, stream>>>(h1, tc2, bc2, h2);
    k_gammabeta<<<NB * 144, 256, 0, stream>>>(h2, tg, tbt, bg, bbt, gt, btt);
    k_invl<<<NB, 256, 0, stream>>>(luma, invl);
    k_qkv<<<NB * 3 * 144, 256, 0, stream>>>(x, tqkv, bqkv, gt, btt, invl, alpha, q, kk, vv);
    k_attn<<<16 * 36 * KSPLIT, 64, 0, stream>>>(q, kk, vv, pm, pl, pacc);
    k_merge<<<(16 * NN * DH + 255) / 256, 256, 0, stream>>>(pm, pl, pacc, aot);
    k_proj<<<NB * 144, 256, 0, stream>>>(aot, tproj, bproj, out);
}

// Round 3
// 287.434 us; speedup vs baseline: 1.7899x; 1.7899x over previous
//
#include <hip/hip_runtime.h>
#include <math.h>

#define NB 2
#define NN 2304        // 48*48
#define CIN 256
#define NHEADS 8
#define DH 32
#define ASPLIT 3
#define AKCH (NN / ASPLIT)   // 768 keys per split

typedef __attribute__((ext_vector_type(8))) short v8s;   // 8 bf16 in 4 VGPRs
typedef __attribute__((ext_vector_type(4))) float v4f;

__device__ inline unsigned short f2b(float f) {          // fp32 -> bf16 (RNE)
    unsigned u = __builtin_bit_cast(unsigned, f);
    unsigned r = u + 0x7FFFu + ((u >> 16) & 1u);
    return (unsigned short)(r >> 16);
}
__device__ inline float b2f(short s) {
    unsigned u = ((unsigned)(unsigned short)s) << 16;
    return __builtin_bit_cast(float, u);
}

// ---------------- weight transposes (tiny, once per call) ----------------
__global__ void k_transpose(const float* __restrict__ wqkv, const float* __restrict__ wproj,
                            const float* __restrict__ wg, const float* __restrict__ wbt,
                            const float* __restrict__ wc2,
                            float* __restrict__ tqkv, float* __restrict__ tproj,
                            float* __restrict__ tg, float* __restrict__ tbt,
                            float* __restrict__ tc2) {
    int i = blockIdx.x * 256 + threadIdx.x;
    if (i < 768 * 256) {                 // wqkv [768][256] -> tqkv [256][768]
        int o = i / 256, c = i % 256;
        tqkv[c * 768 + o] = wqkv[i];
    }
    if (i < 256 * 256) {                 // wproj [256][256] -> tproj [256][256]
        int o = i / 256, c = i % 256;
        tproj[c * 256 + o] = wproj[i];
    }
    if (i < 256 * 128) {                 // wg/wbt [256][128] -> [128][256]
        int o = i / 128, c = i % 128;
        tg[c * 256 + o] = wg[i];
        tbt[c * 256 + o] = wbt[i];
    }
    if (i < 128 * 128 * 9) {             // wc2 [o=128][ic=128][3][3] -> [ic][9][o=128]
        int o = i / 1152;
        int rem = i % 1152;
        int ic = rem / 9, kk = rem % 9;
        tc2[(ic * 9 + kk) * 128 + o] = wc2[i];
    }
}

// ---------------- conv1: luma(1) -> h1(128), 3x3, relu ----------------
__global__ void k_conv1(const float* __restrict__ luma, const float* __restrict__ w,
                        const float* __restrict__ bias, float* __restrict__ h1) {
    int idx = blockIdx.x * 256 + threadIdx.x;      // NB*128*NN
    if (idx >= NB * 128 * NN) return;
    int x = idx % 48, y = (idx / 48) % 48, c = (idx / NN) % 128, b = idx / (128 * NN);
    const float* lb = luma + b * NN;
    float acc = bias[c];
#pragma unroll
    for (int ky = 0; ky < 3; ++ky) {
        int yy = y + ky - 1;
        if (yy < 0 || yy >= 48) continue;
#pragma unroll
        for (int kx = 0; kx < 3; ++kx) {
            int xx = x + kx - 1;
            if (xx < 0 || xx >= 48) continue;
            acc += w[c * 9 + ky * 3 + kx] * lb[yy * 48 + xx];
        }
    }
    h1[idx] = fmaxf(acc, 0.f);
}

// ---------------- conv2: h1(128) -> h2(128), 3x3, relu ----------------
__global__ void k_conv2(const float* __restrict__ h1, const float* __restrict__ tw,
                        const float* __restrict__ bias, float* __restrict__ h2) {
    int c = threadIdx.x & 127;
    int half = threadIdx.x >> 7;
    int sp = blockIdx.x % 144;
    int b = blockIdx.x / 144;
    int n0 = sp * 16 + half * 8;
    int y = n0 / 48, x0 = n0 % 48;
    float bv = bias[c];
    float acc[8];
#pragma unroll
    for (int i = 0; i < 8; ++i) acc[i] = bv;
    const float* h1b = h1 + b * 128 * NN;
    for (int ky = 0; ky < 3; ++ky) {
        int yy = y + ky - 1;
        if (yy < 0 || yy >= 48) continue;
        for (int ic = 0; ic < 128; ++ic) {
            const float* row = h1b + ic * NN + yy * 48;
            float win[10];
#pragma unroll
            for (int t = 0; t < 10; ++t) {
                int xx = x0 - 1 + t;
                win[t] = (xx >= 0 && xx < 48) ? row[xx] : 0.f;
            }
            const float* wp = tw + (ic * 9 + ky * 3) * 128 + c;
            float w0 = wp[0], w1 = wp[128], w2 = wp[256];
#pragma unroll
            for (int i = 0; i < 8; ++i)
                acc[i] += w0 * win[i] + w1 * win[i + 1] + w2 * win[i + 2];
        }
    }
    float* out = h2 + b * 128 * NN + c * NN + n0;
#pragma unroll
    for (int i = 0; i < 8; ++i) out[i] = fmaxf(acc[i], 0.f);
}

// ---------------- gamma/beta 1x1 convs -> transposed [b][n][256] ----------------
__global__ void k_gammabeta(const float* __restrict__ h2, const float* __restrict__ twg,
                            const float* __restrict__ twbt, const float* __restrict__ bg,
                            const float* __restrict__ bbt,
                            float* __restrict__ gt, float* __restrict__ btt) {
    int o = threadIdx.x;
    int nc = blockIdx.x % 144, b = blockIdx.x / 144;
    int n0 = nc * 16;
    float ag[16], ab[16];
    float bgv = bg[o], bbv = bbt[o];
#pragma unroll
    for (int i = 0; i < 16; ++i) { ag[i] = bgv; ab[i] = bbv; }
    const float* h2b = h2 + b * 128 * NN + n0;
    for (int ic = 0; ic < 128; ++ic) {
        float wgv = twg[ic * 256 + o];
        float wbv = twbt[ic * 256 + o];
        const float* hp = h2b + ic * NN;
#pragma unroll
        for (int i = 0; i < 16; ++i) {
            float hv = hp[i];
            ag[i] += wgv * hv;
            ab[i] += wbv * hv;
        }
    }
#pragma unroll
    for (int i = 0; i < 16; ++i) {
        gt[(b * NN + n0 + i) * 256 + o] = ag[i];
        btt[(b * NN + n0 + i) * 256 + o] = ab[i];
    }
}

// ---------------- invL: avgpool3x3(1-luma) centered per batch ----------------
__global__ void k_invl(const float* __restrict__ luma, float* __restrict__ invl) {
    __shared__ float red[256];
    int b = blockIdx.x;
    const float* lb = luma + b * NN;
    float pooled[9];
    float local = 0.f;
#pragma unroll
    for (int it = 0; it < 9; ++it) {
        int n = it * 256 + threadIdx.x;
        int y = n / 48, x = n % 48;
        float s = 0.f;
        for (int ky = 0; ky < 3; ++ky) {
            int yy = y + ky - 1;
            if (yy < 0 || yy >= 48) continue;
            for (int kx = 0; kx < 3; ++kx) {
                int xx = x + kx - 1;
                if (xx < 0 || xx >= 48) continue;
                s += 1.f - lb[yy * 48 + xx];
            }
        }
        s *= (1.f / 9.f);
        pooled[it] = s;
        local += s;
    }
    red[threadIdx.x] = local;
    __syncthreads();
    for (int off = 128; off > 0; off >>= 1) {
        if (threadIdx.x < off) red[threadIdx.x] += red[threadIdx.x + off];
        __syncthreads();
    }
    float mean = red[0] * (1.f / NN);
#pragma unroll
    for (int it = 0; it < 9; ++it) {
        int n = it * 256 + threadIdx.x;
        invl[b * NN + n] = pooled[it] - mean;
    }
}

// ---------------- qkv 1x1 conv + modulation -> bf16 Q(scaled), K, V^T ----------------
// grid: NB*3*144, block 256 (thread = channel within q/k/v), 16 n per thread
__global__ void k_qkv(const float* __restrict__ x, const float* __restrict__ twqkv,
                      const float* __restrict__ bqkv, const float* __restrict__ gt,
                      const float* __restrict__ btt, const float* __restrict__ invl,
                      const float* __restrict__ alpha_p,
                      short* __restrict__ qb, short* __restrict__ kb, short* __restrict__ vt) {
    int lane_o = threadIdx.x;
    int blk = blockIdx.x;
    int nc = blk % 144;
    int which = (blk / 144) % 3;
    int b = blk / (144 * 3);
    int oc = which * 256 + lane_o;
    int n0 = nc * 16;
    float acc[16];
    float bv = bqkv[oc];
#pragma unroll
    for (int i = 0; i < 16; ++i) acc[i] = bv;
    const float* xb = x + b * CIN * NN + n0;
    for (int ic = 0; ic < CIN; ++ic) {
        float w = twqkv[ic * 768 + oc];
        const float* xp = xb + ic * NN;
#pragma unroll
        for (int i = 0; i < 16; ++i) acc[i] += w * xp[i];
    }
    int c = lane_o;
    int h = c >> 5, d = c & 31;
    int bh = b * NHEADS + h;
    const float scale = 0.17677669529663687f;   // 32^-0.5, folded into Q
    if (which == 2) {
        // V: thread holds 16 consecutive n for fixed channel -> transposed row write
        v8s lo, hi;
#pragma unroll
        for (int i = 0; i < 16; ++i) {
            int n = n0 + i;
            float g = gt[(b * NN + n) * 256 + c];
            float bt = btt[(b * NN + n) * 256 + c];
            float val = g * acc[i] + bt;
            if (i < 8) lo[i] = (short)f2b(val); else hi[i - 8] = (short)f2b(val);
        }
        short* row = vt + ((size_t)bh * DH + d) * NN + n0;
        *(v8s*)(row) = lo;
        *(v8s*)(row + 8) = hi;
    } else {
        float alpha = *alpha_p;
        short* dst = (which == 0) ? qb : kb;
#pragma unroll
        for (int i = 0; i < 16; ++i) {
            int n = n0 + i;
            float g = gt[(b * NN + n) * 256 + c];
            float bt = btt[(b * NN + n) * 256 + c];
            float val = g * acc[i] + bt;
            if (which == 0) val = (val + alpha * invl[b * NN + n]) * scale;
            dst[((size_t)bh * NN + n) * DH + d] = (short)f2b(val);
        }
    }
}

// ---------------- V row-sums: vsum[bh*32+d] = sum_n V^T[bh][d][n] ----------------
__global__ __launch_bounds__(64) void k_vsum(const short* __restrict__ vt,
                                             float* __restrict__ vsum) {
    int row = blockIdx.x;            // 16*32 rows
    int lane = threadIdx.x;
    const short* rp = vt + (size_t)row * NN;
    float s = 0.f;
    for (int n = lane; n < NN; n += 64) s += b2f(rp[n]);
#pragma unroll
    for (int off = 32; off > 0; off >>= 1) s += __shfl_xor(s, off);
    if (lane == 0) vsum[row] = s;
}

// ---------------- MFMA attention partials on p' = exp(s)-1 ----------------
// softmax(s) = (1 + p') / (N + sum p'), p' ~ 1e-3 so bf16-safe (centered at 0).
// grid: 16 bh * 72 qtiles * ASPLIT, block 64 (1 wave). Wave owns 32 q rows.
__global__ __launch_bounds__(64) void k_attn(const short* __restrict__ qb,
                                             const short* __restrict__ kbuf,
                                             const short* __restrict__ vt,
                                             float* __restrict__ pl,
                                             float* __restrict__ pacc) {
    int lane = threadIdx.x;
    int l15 = lane & 15, g = lane >> 4;
    int blk = blockIdx.x;
    int ks = blk % ASPLIT;
    int qt = (blk / ASPLIT) % 72;
    int bh = blk / (ASPLIT * 72);
    int qbase = qt * 32;

    const short* qp = qb + ((size_t)bh * NN + qbase) * DH;
    const short* kp = kbuf + ((size_t)bh * NN + ks * AKCH) * DH;
    const short* vp = vt + (size_t)bh * DH * NN + ks * AKCH;

    // Q as B-operand frags: lane: q = l15 (+16), d = 8g..8g+7 (16B contiguous)
    v8s q0 = *(const v8s*)(qp + l15 * DH + 8 * g);
    v8s q1 = *(const v8s*)(qp + (16 + l15) * DH + 8 * g);

    v4f acc00 = {0.f,0.f,0.f,0.f}, acc01 = acc00, acc10 = acc00, acc11 = acc00; // [qtl][dt]
    float ps0 = 0.f, ps1 = 0.f;

    __shared__ short plds[32 * 40];    // P' tile, rows padded to 80B (16B-aligned b128 reads)

    for (int kb = 0; kb < AKCH; kb += 32) {
        // K as A-operand frags: lane: k = l15 (+16), d = 8g..8g+7
        v8s ka0 = *(const v8s*)(kp + (kb + l15) * DH + 8 * g);
        v8s ka1 = *(const v8s*)(kp + (kb + 16 + l15) * DH + 8 * g);
        // S^T[k][q] = K·Q^T  (C layout: col=lane&15 -> q, row=4g+reg -> k)
        v4f s00 = __builtin_amdgcn_mfma_f32_16x16x32_bf16(ka0, q0, (v4f){0.f,0.f,0.f,0.f}, 0, 0, 0);
        v4f s01 = __builtin_amdgcn_mfma_f32_16x16x32_bf16(ka0, q1, (v4f){0.f,0.f,0.f,0.f}, 0, 0, 0);
        v4f s10 = __builtin_amdgcn_mfma_f32_16x16x32_bf16(ka1, q0, (v4f){0.f,0.f,0.f,0.f}, 0, 0, 0);
        v4f s11 = __builtin_amdgcn_mfma_f32_16x16x32_bf16(ka1, q1, (v4f){0.f,0.f,0.f,0.f}, 0, 0, 0);

        // p' = exp(s)-1; accumulate row-sums; stash P'^T -> LDS as row-major P'[q][k] bf16
#define DOFRAG(S, QTL, KT, PS)                                                   \
        {                                                                        \
            float p0 = __expf((S)[0]) - 1.f, p1 = __expf((S)[1]) - 1.f;          \
            float p2 = __expf((S)[2]) - 1.f, p3 = __expf((S)[3]) - 1.f;          \
            PS += p0 + p1 + p2 + p3;                                             \
            unsigned w0 = (unsigned)f2b(p0) | ((unsigned)f2b(p1) << 16);         \
            unsigned w1 = (unsigned)f2b(p2) | ((unsigned)f2b(p3) << 16);         \
            char* bp = (char*)plds + ((QTL) * 16 + l15) * 80 + ((KT) * 16 + 4 * g) * 2; \
            *(unsigned*)(bp) = w0;                                               \
            *(unsigned*)(bp + 4) = w1;                                           \
        }
        DOFRAG(s00, 0, 0, ps0)
        DOFRAG(s01, 1, 0, ps1)
        DOFRAG(s10, 0, 1, ps0)
        DOFRAG(s11, 1, 1, ps1)
#undef DOFRAG
        __syncthreads();
        // P' as A-operand frags: lane: q = l15, k = 8g..8g+7
        v8s pa0 = *(v8s*)((char*)plds + l15 * 80 + 16 * g);
        v8s pa1 = *(v8s*)((char*)plds + (16 + l15) * 80 + 16 * g);
        // V^T as B-operand frags: lane: d = l15, k = 8g..8g+7
        v8s vb0 = *(const v8s*)(vp + (size_t)l15 * NN + kb + 8 * g);
        v8s vb1 = *(const v8s*)(vp + (size_t)(16 + l15) * NN + kb + 8 * g);
        acc00 = __builtin_amdgcn_mfma_f32_16x16x32_bf16(pa0, vb0, acc00, 0, 0, 0);
        acc01 = __builtin_amdgcn_mfma_f32_16x16x32_bf16(pa0, vb1, acc01, 0, 0, 0);
        acc10 = __builtin_amdgcn_mfma_f32_16x16x32_bf16(pa1, vb0, acc10, 0, 0, 0);
        acc11 = __builtin_amdgcn_mfma_f32_16x16x32_bf16(pa1, vb1, acc11, 0, 0, 0);
        __syncthreads();
    }

    // finalize row-sums of p': reduce across the 4 lane-groups
    ps0 += __shfl_xor(ps0, 16); ps0 += __shfl_xor(ps0, 32);
    ps1 += __shfl_xor(ps1, 16); ps1 += __shfl_xor(ps1, 32);
    if (lane < 32) {
        int qq = qbase + ((lane < 16) ? l15 : (16 + l15));
        pl[((size_t)bh * NN + qq) * ASPLIT + ks] = (lane < 16) ? ps0 : ps1;
    }
    // store partial acc: C layout: col=l15 -> d, row=4g+reg -> q
#define STORE(ACC, QTL, DT)                                                        \
    {                                                                              \
        _Pragma("unroll")                                                          \
        for (int r = 0; r < 4; ++r) {                                              \
            int qq = qbase + (QTL) * 16 + 4 * g + r;                               \
            int dd = (DT) * 16 + l15;                                              \
            pacc[(((size_t)bh * NN + qq) * ASPLIT + ks) * DH + dd] = (ACC)[r];     \
        }                                                                          \
    }
    STORE(acc00, 0, 0)
    STORE(acc01, 1, 0)
    STORE(acc10, 0, 1)
    STORE(acc11, 1, 1)
#undef STORE
}

// ---------------- merge splits -> aot [b][n][256] fp32 ----------------
// out[q][d] = (vsum[d] + sum_splits pacc) / (NN + sum_splits pl)
__global__ void k_merge(const float* __restrict__ pl, const float* __restrict__ pacc,
                        const float* __restrict__ vsum, float* __restrict__ aot) {
    int t = blockIdx.x * 256 + threadIdx.x;     // 16*NN*32 total
    if (t >= 16 * NN * DH) return;
    int d = t & 31;
    int q = (t >> 5) % NN;
    int bh = t / (NN * DH);
    size_t idx = (size_t)bh * NN + q;
    float L = (float)NN + pl[idx * ASPLIT + 0] + pl[idx * ASPLIT + 1] + pl[idx * ASPLIT + 2];
    float a = vsum[bh * DH + d]
            + pacc[(idx * ASPLIT + 0) * DH + d] + pacc[(idx * ASPLIT + 1) * DH + d]
            + pacc[(idx * ASPLIT + 2) * DH + d];
    int b = bh >> 3, h = bh & 7;
    aot[((size_t)b * NN + q) * 256 + h * DH + d] = a / L;
}

// ---------------- output projection ----------------
__global__ void k_proj(const float* __restrict__ aot, const float* __restrict__ twproj,
                       const float* __restrict__ bproj, float* __restrict__ out) {
    int o = threadIdx.x;
    int nc = blockIdx.x % 144, b = blockIdx.x / 144;
    int n0 = nc * 16;
    float acc[16];
    float bv = bproj[o];
#pragma unroll
    for (int i = 0; i < 16; ++i) acc[i] = bv;
    const float* ab = aot + ((size_t)b * NN + n0) * 256;
    for (int c = 0; c < 256; ++c) {
        float w = twproj[c * 256 + o];
#pragma unroll
        for (int i = 0; i < 16; ++i) acc[i] += w * ab[i * 256 + c];
    }
    float* op = out + ((size_t)b * 256 + o) * NN + n0;
#pragma unroll
    for (int i = 0; i < 16; ++i) op[i] = acc[i];
}

extern "C" void kernel_launch(void* const* d_in, const int* in_sizes, int n_in,
                              void* d_out, int out_size, void* d_ws, size_t ws_size,
                              hipStream_t stream) {
    const float* x     = (const float*)d_in[0];
    const float* luma  = (const float*)d_in[1];
    const float* wqkv  = (const float*)d_in[2];
    const float* bqkv  = (const float*)d_in[3];
    const float* wproj = (const float*)d_in[4];
    const float* bproj = (const float*)d_in[5];
    const float* wc1   = (const float*)d_in[6];
    const float* bc1   = (const float*)d_in[7];
    const float* wc2   = (const float*)d_in[8];
    const float* bc2   = (const float*)d_in[9];
    const float* wg    = (const float*)d_in[10];
    const float* bg    = (const float*)d_in[11];
    const float* wbt   = (const float*)d_in[12];
    const float* bbt   = (const float*)d_in[13];
    const float* alpha = (const float*)d_in[14];
    float* out = (float*)d_out;

    float* ws = (float*)d_ws;
    size_t off = 0;
    float* tqkv = ws + off;  off += 256 * 768;
    float* tproj = ws + off; off += 256 * 256;
    float* tg = ws + off;    off += 128 * 256;
    float* tbt = ws + off;   off += 128 * 256;
    float* tc2 = ws + off;   off += 128 * 9 * 128;
    float* h1 = ws + off;    off += NB * 128 * NN;
    float* h2 = ws + off;    off += NB * 128 * NN;
    float* gt = ws + off;    off += NB * NN * 256;
    float* btt = ws + off;   off += NB * NN * 256;
    float* invl = ws + off;  off += NB * NN;
    short* qbb = (short*)(ws + off); off += 16 * NN * DH / 2;   // bf16
    short* kbb = (short*)(ws + off); off += 16 * NN * DH / 2;   // bf16
    short* vtt = (short*)(ws + off); off += 16 * NN * DH / 2;   // bf16, [bh*32+d][n]
    float* vsum = ws + off;  off += 16 * DH;
    float* pl = ws + off;    off += 16 * NN * ASPLIT;
    float* pacc = ws + off;  off += (size_t)16 * NN * ASPLIT * DH;
    float* aot = ws + off;   off += NB * NN * 256;
    (void)ws_size; (void)in_sizes; (void)n_in; (void)out_size;

    k_transpose<<<768, 256, 0, stream>>>(wqkv, wproj, wg, wbt, wc2, tqkv, tproj, tg, tbt, tc2);
    k_conv1<<<(NB * 128 * NN + 255) / 256, 256, 0, stream>>>(luma, wc1, bc1, h1);
    k_conv2<<<NB * 144, 256, 0, stream>>>(h1, tc2, bc2, h2);
    k_gammabeta<<<NB * 144, 256, 0, stream>>>(h2, tg, tbt, bg, bbt, gt, btt);
    k_invl<<<NB, 256, 0, stream>>>(luma, invl);
    k_qkv<<<NB * 3 * 144, 256, 0, stream>>>(x, tqkv, bqkv, gt, btt, invl, alpha, qbb, kbb, vtt);
    k_vsum<<<16 * DH, 64, 0, stream>>>(vtt, vsum);
    k_attn<<<16 * 72 * ASPLIT, 64, 0, stream>>>(qbb, kbb, vtt, pl, pacc);
    k_merge<<<(16 * NN * DH + 255) / 256, 256, 0, stream>>>(pl, pacc, vsum, aot);
    k_proj<<<NB * 144, 256, 0, stream>>>(aot, tproj, bproj, out);
}

// Round 4
// 141.665 us; speedup vs baseline: 3.6316x; 2.0290x over previous
//
#include <hip/hip_runtime.h>
#include <math.h>

#define NB 2
#define NN 2304        // 48*48
#define NHEADS 8
#define DH 32
#define ASPLIT 3
#define AKCH (NN / ASPLIT)   // 768 keys per split

typedef __attribute__((ext_vector_type(8))) short v8s;   // 8 bf16 in 4 VGPRs
typedef __attribute__((ext_vector_type(4))) float v4f;

__device__ inline unsigned short f2b(float f) {          // fp32 -> bf16 (RNE)
    unsigned u = __builtin_bit_cast(unsigned, f);
    unsigned r = u + 0x7FFFu + ((u >> 16) & 1u);
    return (unsigned short)(r >> 16);
}
__device__ inline float b2f(short s) {
    unsigned u = ((unsigned)(unsigned short)s) << 16;
    return __builtin_bit_cast(float, u);
}

// ---------------- weight prep: transposes + bf16 conversion ----------------
__global__ void k_prep(const float* __restrict__ wc1, const float* __restrict__ wc2,
                       const float* __restrict__ wqkv, const float* __restrict__ wg,
                       const float* __restrict__ wbt, const float* __restrict__ wproj,
                       float* __restrict__ twc1, short* __restrict__ tc2b,
                       short* __restrict__ wqkvb, short* __restrict__ wgb,
                       short* __restrict__ wbtb, short* __restrict__ wprojb) {
    int i = blockIdx.x * 256 + threadIdx.x;            // 196608 threads
    if (i < 9 * 128) {                                 // twc1[k][c] = wc1[c][k]
        int k = i / 128, c = i % 128;
        twc1[i] = wc1[c * 9 + k];
    }
    if (i < 9 * 128 * 128) {                           // tc2b[s][o][ic] = wc2[o][ic][s]
        int s = i / (128 * 128);
        int rem = i % (128 * 128);
        int o = rem / 128, ic = rem % 128;
        tc2b[i] = (short)f2b(wc2[(o * 128 + ic) * 9 + s]);
    }
    if (i < 768 * 256) wqkvb[i] = (short)f2b(wqkv[i]);
    if (i < 256 * 128) { wgb[i] = (short)f2b(wg[i]); wbtb[i] = (short)f2b(wbt[i]); }
    if (i < 256 * 256) wprojb[i] = (short)f2b(wproj[i]);
}

// ---------------- conv1 -> h1p: padded(50x50) transposed [b][p][128] bf16 ----------------
__global__ void k_conv1(const float* __restrict__ luma, const float* __restrict__ twc1,
                        const float* __restrict__ bc1, short* __restrict__ h1p) {
    int c = threadIdx.x & 127;
    int p = (blockIdx.x % 1250) * 2 + (threadIdx.x >> 7);
    int b = blockIdx.x / 1250;
    int py = p / 50, px = p % 50;
    float val = 0.f;
    if (py >= 1 && py <= 48 && px >= 1 && px <= 48) {
        int y = py - 1, x = px - 1;
        const float* lb = luma + b * NN;
        float acc = bc1[c];
#pragma unroll
        for (int ky = 0; ky < 3; ++ky) {
            int yy = y + ky - 1;
            if (yy < 0 || yy >= 48) continue;
#pragma unroll
            for (int kx = 0; kx < 3; ++kx) {
                int xx = x + kx - 1;
                if (xx < 0 || xx >= 48) continue;
                acc += twc1[(ky * 3 + kx) * 128 + c] * lb[yy * 48 + xx];
            }
        }
        val = fmaxf(acc, 0.f);
    }
    h1p[((size_t)b * 2500 + p) * 128 + c] = (short)f2b(val);
}

// ---------------- x transpose: [b][256][2304] fp32 -> xt [b][2304][256] bf16 ----------------
__global__ void k_xt(const float* __restrict__ x, short* __restrict__ xt) {
    __shared__ unsigned short lds[64 * 66];            // [n][66] pad
    int blk = blockIdx.x;
    int nt = blk % 36, ct = (blk / 36) % 4, b = blk / 144;
    int n0 = nt * 64, c0 = ct * 64;
    int nc = threadIdx.x & 63, cr = threadIdx.x >> 6;
#pragma unroll
    for (int i = 0; i < 16; ++i) {
        int cs = i * 4 + cr;
        float v = x[((size_t)b * 256 + c0 + cs) * NN + n0 + nc];
        lds[nc * 66 + cs] = f2b(v);
    }
    __syncthreads();
    int cc = threadIdx.x & 31, nr = threadIdx.x >> 5;
    unsigned* xt2 = (unsigned*)xt;
#pragma unroll
    for (int j = 0; j < 8; ++j) {
        int ns = j * 8 + nr;
        unsigned w = *(unsigned*)&lds[ns * 66 + 2 * cc];
        xt2[(((size_t)b * NN + n0 + ns) * 256 + c0) / 2 + cc] = w;
    }
}

// ---------------- conv2 as 9-shift MFMA GEMM -> h2t [b][n][128] bf16 (bias+relu) ----------------
// grid: b(2) x ot(8) x ntg(72); 1 wave; wave = 16o x 32n (two 16-wide row-aligned n-tiles)
__global__ __launch_bounds__(64) void k_conv2m(const short* __restrict__ h1p,
                                               const short* __restrict__ tc2b,
                                               const float* __restrict__ bc2,
                                               short* __restrict__ h2t) {
    int lane = threadIdx.x, l15 = lane & 15, g = lane >> 4;
    int blk = blockIdx.x;
    int ntg = blk % 72, ot = (blk / 72) % 8, b = blk / (72 * 8);
    int nta = ntg * 2, ntb = ntg * 2 + 1;
    int ya = nta / 3, xa = (nta % 3) * 16;
    int yb = ntb / 3, xb = (ntb % 3) * 16;
    int p0a = (ya + 1) * 50 + xa + 1;
    int p0b = (yb + 1) * 50 + xb + 1;
    const short* hb = h1p + (size_t)b * 2500 * 128;

    v4f acca = {0.f,0.f,0.f,0.f}, accb = acca;
#pragma unroll
    for (int s = 0; s < 9; ++s) {
        int dp = (s / 3 - 1) * 50 + (s % 3 - 1);
#pragma unroll
        for (int kk = 0; kk < 4; ++kk) {
            v8s A = *(const v8s*)(tc2b + ((size_t)(s * 128 + ot * 16 + l15)) * 128 + kk * 32 + 8 * g);
            v8s Ba = *(const v8s*)(hb + (size_t)(p0a + dp + l15) * 128 + kk * 32 + 8 * g);
            v8s Bb = *(const v8s*)(hb + (size_t)(p0b + dp + l15) * 128 + kk * 32 + 8 * g);
            acca = __builtin_amdgcn_mfma_f32_16x16x32_bf16(A, Ba, acca, 0, 0, 0);
            accb = __builtin_amdgcn_mfma_f32_16x16x32_bf16(A, Bb, accb, 0, 0, 0);
        }
    }
    v4f bias = *(const v4f*)&bc2[ot * 16 + 4 * g];
    int na = ya * 48 + xa + l15, nb = yb * 48 + xb + l15;
    uint2 wa, wb;
    float a0 = fmaxf(acca[0] + bias[0], 0.f), a1 = fmaxf(acca[1] + bias[1], 0.f);
    float a2 = fmaxf(acca[2] + bias[2], 0.f), a3 = fmaxf(acca[3] + bias[3], 0.f);
    wa.x = (unsigned)f2b(a0) | ((unsigned)f2b(a1) << 16);
    wa.y = (unsigned)f2b(a2) | ((unsigned)f2b(a3) << 16);
    float b0 = fmaxf(accb[0] + bias[0], 0.f), b1 = fmaxf(accb[1] + bias[1], 0.f);
    float b2 = fmaxf(accb[2] + bias[2], 0.f), b3 = fmaxf(accb[3] + bias[3], 0.f);
    wb.x = (unsigned)f2b(b0) | ((unsigned)f2b(b1) << 16);
    wb.y = (unsigned)f2b(b2) | ((unsigned)f2b(b3) << 16);
    *(uint2*)&h2t[((size_t)b * NN + na) * 128 + ot * 16 + 4 * g] = wa;
    *(uint2*)&h2t[((size_t)b * NN + nb) * 128 + ot * 16 + 4 * g] = wb;
}

// ---------------- gamma/beta MFMA GEMMs -> gt/btt fp32 [b][n][256] ----------------
// grid: b(2) x ot(16) x ntg(72); wave = 16o x 32n, two A matrices share B-frags
__global__ __launch_bounds__(64) void k_gbm(const short* __restrict__ h2t,
                                            const short* __restrict__ wgb,
                                            const short* __restrict__ wbtb,
                                            const float* __restrict__ bg,
                                            const float* __restrict__ bbt,
                                            float* __restrict__ gt, float* __restrict__ btt) {
    int lane = threadIdx.x, l15 = lane & 15, g = lane >> 4;
    int blk = blockIdx.x;
    int ntg = blk % 72, ot = (blk / 72) % 16, b = blk / (72 * 16);
    int na0 = ntg * 32, nb0 = ntg * 32 + 16;
    const short* hb = h2t + (size_t)b * NN * 128;

    v4f ga = {0.f,0.f,0.f,0.f}, gb = ga, ta = ga, tb = ga;
#pragma unroll
    for (int kk = 0; kk < 4; ++kk) {
        v8s Ag = *(const v8s*)(wgb + (size_t)(ot * 16 + l15) * 128 + kk * 32 + 8 * g);
        v8s At = *(const v8s*)(wbtb + (size_t)(ot * 16 + l15) * 128 + kk * 32 + 8 * g);
        v8s Ba = *(const v8s*)(hb + (size_t)(na0 + l15) * 128 + kk * 32 + 8 * g);
        v8s Bb = *(const v8s*)(hb + (size_t)(nb0 + l15) * 128 + kk * 32 + 8 * g);
        ga = __builtin_amdgcn_mfma_f32_16x16x32_bf16(Ag, Ba, ga, 0, 0, 0);
        gb = __builtin_amdgcn_mfma_f32_16x16x32_bf16(Ag, Bb, gb, 0, 0, 0);
        ta = __builtin_amdgcn_mfma_f32_16x16x32_bf16(At, Ba, ta, 0, 0, 0);
        tb = __builtin_amdgcn_mfma_f32_16x16x32_bf16(At, Bb, tb, 0, 0, 0);
    }
    v4f bgv = *(const v4f*)&bg[ot * 16 + 4 * g];
    v4f bbv = *(const v4f*)&bbt[ot * 16 + 4 * g];
#pragma unroll
    for (int r = 0; r < 4; ++r) { ga[r] += bgv[r]; gb[r] += bgv[r]; ta[r] += bbv[r]; tb[r] += bbv[r]; }
    size_t oa = ((size_t)b * NN + na0 + l15) * 256 + ot * 16 + 4 * g;
    size_t ob = ((size_t)b * NN + nb0 + l15) * 256 + ot * 16 + 4 * g;
    *(v4f*)&gt[oa] = ga;  *(v4f*)&gt[ob] = gb;
    *(v4f*)&btt[oa] = ta; *(v4f*)&btt[ob] = tb;
}

// ---------------- invL: avgpool3x3(1-luma) centered per batch ----------------
__global__ void k_invl(const float* __restrict__ luma, float* __restrict__ invl) {
    __shared__ float red[256];
    int b = blockIdx.x;
    const float* lb = luma + b * NN;
    float pooled[9];
    float local = 0.f;
#pragma unroll
    for (int it = 0; it < 9; ++it) {
        int n = it * 256 + threadIdx.x;
        int y = n / 48, x = n % 48;
        float s = 0.f;
        for (int ky = 0; ky < 3; ++ky) {
            int yy = y + ky - 1;
            if (yy < 0 || yy >= 48) continue;
            for (int kx = 0; kx < 3; ++kx) {
                int xx = x + kx - 1;
                if (xx < 0 || xx >= 48) continue;
                s += 1.f - lb[yy * 48 + xx];
            }
        }
        s *= (1.f / 9.f);
        pooled[it] = s;
        local += s;
    }
    red[threadIdx.x] = local;
    __syncthreads();
    for (int off = 128; off > 0; off >>= 1) {
        if (threadIdx.x < off) red[threadIdx.x] += red[threadIdx.x + off];
        __syncthreads();
    }
    float mean = red[0] * (1.f / NN);
#pragma unroll
    for (int it = 0; it < 9; ++it) {
        int n = it * 256 + threadIdx.x;
        invl[b * NN + n] = pooled[it] - mean;
    }
}

// ---------------- qkv MFMA GEMM + modulation epilogue -> qb, kb, vraw bf16 ----------------
// grid: b(2) x ot(48) x ntg(72); wave = 16oc x 32n
__global__ __launch_bounds__(64) void k_qkvm(const short* __restrict__ xt,
                                             const short* __restrict__ wqkvb,
                                             const float* __restrict__ bqkv,
                                             const float* __restrict__ gt,
                                             const float* __restrict__ btt,
                                             const float* __restrict__ invl,
                                             const float* __restrict__ alpha_p,
                                             short* __restrict__ qb, short* __restrict__ kb,
                                             short* __restrict__ vraw) {
    int lane = threadIdx.x, l15 = lane & 15, g = lane >> 4;
    int blk = blockIdx.x;
    int ntg = blk % 72, ot = (blk / 72) % 48, b = blk / (72 * 48);
    int na0 = ntg * 32, nb0 = ntg * 32 + 16;
    const short* xb = xt + (size_t)b * NN * 256;

    v4f acca = {0.f,0.f,0.f,0.f}, accb = acca;
#pragma unroll
    for (int kk = 0; kk < 8; ++kk) {
        v8s A = *(const v8s*)(wqkvb + (size_t)(ot * 16 + l15) * 256 + kk * 32 + 8 * g);
        v8s Ba = *(const v8s*)(xb + (size_t)(na0 + l15) * 256 + kk * 32 + 8 * g);
        v8s Bb = *(const v8s*)(xb + (size_t)(nb0 + l15) * 256 + kk * 32 + 8 * g);
        acca = __builtin_amdgcn_mfma_f32_16x16x32_bf16(A, Ba, acca, 0, 0, 0);
        accb = __builtin_amdgcn_mfma_f32_16x16x32_bf16(A, Bb, accb, 0, 0, 0);
    }
    int which = ot >> 4;
    int c16 = (ot & 15) * 16;
    int cbase = c16 + 4 * g;
    int h = cbase >> 5, dbase = cbase & 31;
    v4f bias = *(const v4f*)&bqkv[which * 256 + cbase - (4 * g) + 4 * g];  // = bqkv[ot*16+4g]
    const float scale = 0.17677669529663687f;
    float alpha = *alpha_p;
    short* dst = (which == 0) ? qb : (which == 1) ? kb : vraw;
#pragma unroll
    for (int t = 0; t < 2; ++t) {
        int n = (t == 0 ? na0 : nb0) + l15;
        v4f acc = (t == 0) ? acca : accb;
        v4f g4 = *(const v4f*)&gt[((size_t)b * NN + n) * 256 + cbase];
        v4f t4 = *(const v4f*)&btt[((size_t)b * NN + n) * 256 + cbase];
        float iv = (which == 0) ? alpha * invl[b * NN + n] : 0.f;
        float v0 = g4[0] * (acc[0] + bias[0]) + t4[0];
        float v1 = g4[1] * (acc[1] + bias[1]) + t4[1];
        float v2 = g4[2] * (acc[2] + bias[2]) + t4[2];
        float v3 = g4[3] * (acc[3] + bias[3]) + t4[3];
        if (which == 0) {
            v0 = (v0 + iv) * scale; v1 = (v1 + iv) * scale;
            v2 = (v2 + iv) * scale; v3 = (v3 + iv) * scale;
        }
        uint2 w;
        w.x = (unsigned)f2b(v0) | ((unsigned)f2b(v1) << 16);
        w.y = (unsigned)f2b(v2) | ((unsigned)f2b(v3) << 16);
        *(uint2*)&dst[(((size_t)b * NHEADS + h) * NN + n) * DH + dbase] = w;
    }
}

// ---------------- V transpose: vraw [bh][n][32] -> vt [bh][32][2304] ----------------
__global__ void k_vt(const short* __restrict__ vraw, short* __restrict__ vt) {
    __shared__ unsigned short lds[64 * 34];
    int bh = blockIdx.x / 36, nc = blockIdx.x % 36;
    int n0 = nc * 64;
    int dpair = threadIdx.x & 15, nsub = (threadIdx.x >> 4) & 15;
    const unsigned* vr2 = (const unsigned*)vraw;
#pragma unroll
    for (int i = 0; i < 4; ++i) {
        int ns = i * 16 + nsub;
        unsigned v = vr2[((size_t)bh * NN + n0 + ns) * 16 + dpair];
        *(unsigned*)&lds[ns * 34 + 2 * dpair] = v;
    }
    __syncthreads();
    int npair = threadIdx.x & 31, drow = threadIdx.x >> 5;
    unsigned* vt2 = (unsigned*)vt;
#pragma unroll
    for (int j = 0; j < 4; ++j) {
        int d = j * 8 + drow;
        unsigned lo = lds[(2 * npair) * 34 + d];
        unsigned hi = lds[(2 * npair + 1) * 34 + d];
        vt2[((size_t)bh * DH + d) * (NN / 2) + n0 / 2 + npair] = lo | (hi << 16);
    }
}

// ---------------- V row-sums ----------------
__global__ __launch_bounds__(64) void k_vsum(const short* __restrict__ vt,
                                             float* __restrict__ vsum) {
    int row = blockIdx.x;            // 16*32 rows
    int lane = threadIdx.x;
    const short* rp = vt + (size_t)row * NN;
    float s = 0.f;
    for (int n = lane; n < NN; n += 64) s += b2f(rp[n]);
#pragma unroll
    for (int off = 32; off > 0; off >>= 1) s += __shfl_xor(s, off);
    if (lane == 0) vsum[row] = s;
}

// ---------------- MFMA attention partials on p' = exp(s)-1 ----------------
__global__ __launch_bounds__(64) void k_attn(const short* __restrict__ qb,
                                             const short* __restrict__ kbuf,
                                             const short* __restrict__ vt,
                                             float* __restrict__ pl,
                                             float* __restrict__ pacc) {
    int lane = threadIdx.x;
    int l15 = lane & 15, g = lane >> 4;
    int blk = blockIdx.x;
    int ks = blk % ASPLIT;
    int qt = (blk / ASPLIT) % 72;
    int bh = blk / (ASPLIT * 72);
    int qbase = qt * 32;

    const short* qp = qb + ((size_t)bh * NN + qbase) * DH;
    const short* kp = kbuf + ((size_t)bh * NN + ks * AKCH) * DH;
    const short* vp = vt + (size_t)bh * DH * NN + ks * AKCH;

    v8s q0 = *(const v8s*)(qp + l15 * DH + 8 * g);
    v8s q1 = *(const v8s*)(qp + (16 + l15) * DH + 8 * g);

    v4f acc00 = {0.f,0.f,0.f,0.f}, acc01 = acc00, acc10 = acc00, acc11 = acc00;
    float ps0 = 0.f, ps1 = 0.f;

    __shared__ short plds[32 * 40];

    for (int kb = 0; kb < AKCH; kb += 32) {
        v8s ka0 = *(const v8s*)(kp + (kb + l15) * DH + 8 * g);
        v8s ka1 = *(const v8s*)(kp + (kb + 16 + l15) * DH + 8 * g);
        v4f s00 = __builtin_amdgcn_mfma_f32_16x16x32_bf16(ka0, q0, (v4f){0.f,0.f,0.f,0.f}, 0, 0, 0);
        v4f s01 = __builtin_amdgcn_mfma_f32_16x16x32_bf16(ka0, q1, (v4f){0.f,0.f,0.f,0.f}, 0, 0, 0);
        v4f s10 = __builtin_amdgcn_mfma_f32_16x16x32_bf16(ka1, q0, (v4f){0.f,0.f,0.f,0.f}, 0, 0, 0);
        v4f s11 = __builtin_amdgcn_mfma_f32_16x16x32_bf16(ka1, q1, (v4f){0.f,0.f,0.f,0.f}, 0, 0, 0);

#define DOFRAG(S, QTL, KT, PS)                                                   \
        {                                                                        \
            float p0 = __expf((S)[0]) - 1.f, p1 = __expf((S)[1]) - 1.f;          \
            float p2 = __expf((S)[2]) - 1.f, p3 = __expf((S)[3]) - 1.f;          \
            PS += p0 + p1 + p2 + p3;                                             \
            unsigned w0 = (unsigned)f2b(p0) | ((unsigned)f2b(p1) << 16);         \
            unsigned w1 = (unsigned)f2b(p2) | ((unsigned)f2b(p3) << 16);         \
            char* bp = (char*)plds + ((QTL) * 16 + l15) * 80 + ((KT) * 16 + 4 * g) * 2; \
            *(unsigned*)(bp) = w0;                                               \
            *(unsigned*)(bp + 4) = w1;                                           \
        }
        DOFRAG(s00, 0, 0, ps0)
        DOFRAG(s01, 1, 0, ps1)
        DOFRAG(s10, 0, 1, ps0)
        DOFRAG(s11, 1, 1, ps1)
#undef DOFRAG
        __syncthreads();
        v8s pa0 = *(v8s*)((char*)plds + l15 * 80 + 16 * g);
        v8s pa1 = *(v8s*)((char*)plds + (16 + l15) * 80 + 16 * g);
        v8s vb0 = *(const v8s*)(vp + (size_t)l15 * NN + kb + 8 * g);
        v8s vb1 = *(const v8s*)(vp + (size_t)(16 + l15) * NN + kb + 8 * g);
        acc00 = __builtin_amdgcn_mfma_f32_16x16x32_bf16(pa0, vb0, acc00, 0, 0, 0);
        acc01 = __builtin_amdgcn_mfma_f32_16x16x32_bf16(pa0, vb1, acc01, 0, 0, 0);
        acc10 = __builtin_amdgcn_mfma_f32_16x16x32_bf16(pa1, vb0, acc10, 0, 0, 0);
        acc11 = __builtin_amdgcn_mfma_f32_16x16x32_bf16(pa1, vb1, acc11, 0, 0, 0);
        __syncthreads();
    }

    ps0 += __shfl_xor(ps0, 16); ps0 += __shfl_xor(ps0, 32);
    ps1 += __shfl_xor(ps1, 16); ps1 += __shfl_xor(ps1, 32);
    if (lane < 32) {
        int qq = qbase + ((lane < 16) ? l15 : (16 + l15));
        pl[((size_t)bh * NN + qq) * ASPLIT + ks] = (lane < 16) ? ps0 : ps1;
    }
#define STORE(ACC, QTL, DT)                                                        \
    {                                                                              \
        _Pragma("unroll")                                                          \
        for (int r = 0; r < 4; ++r) {                                              \
            int qq = qbase + (QTL) * 16 + 4 * g + r;                               \
            int dd = (DT) * 16 + l15;                                              \
            pacc[(((size_t)bh * NN + qq) * ASPLIT + ks) * DH + dd] = (ACC)[r];     \
        }                                                                          \
    }
    STORE(acc00, 0, 0)
    STORE(acc01, 1, 0)
    STORE(acc10, 0, 1)
    STORE(acc11, 1, 1)
#undef STORE
}

// ---------------- merge splits -> aotb [b][n][256] bf16 ----------------
__global__ void k_merge(const float* __restrict__ pl, const float* __restrict__ pacc,
                        const float* __restrict__ vsum, short* __restrict__ aotb) {
    int t = blockIdx.x * 256 + threadIdx.x;     // 16*NN*32 total
    if (t >= 16 * NN * DH) return;
    int d = t & 31;
    int q = (t >> 5) % NN;
    int bh = t / (NN * DH);
    size_t idx = (size_t)bh * NN + q;
    float L = (float)NN + pl[idx * ASPLIT + 0] + pl[idx * ASPLIT + 1] + pl[idx * ASPLIT + 2];
    float a = vsum[bh * DH + d]
            + pacc[(idx * ASPLIT + 0) * DH + d] + pacc[(idx * ASPLIT + 1) * DH + d]
            + pacc[(idx * ASPLIT + 2) * DH + d];
    int b = bh >> 3, h = bh & 7;
    aotb[((size_t)b * NN + q) * 256 + h * DH + d] = (short)f2b(a / L);
}

// ---------------- output projection MFMA GEMM ----------------
// grid: b(2) x ot(16) x ntg(72); wave = 16o x 32n
__global__ __launch_bounds__(64) void k_projm(const short* __restrict__ aotb,
                                              const short* __restrict__ wprojb,
                                              const float* __restrict__ bproj,
                                              float* __restrict__ out) {
    int lane = threadIdx.x, l15 = lane & 15, g = lane >> 4;
    int blk = blockIdx.x;
    int ntg = blk % 72, ot = (blk / 72) % 16, b = blk / (72 * 16);
    int na0 = ntg * 32, nb0 = ntg * 32 + 16;
    const short* ab = aotb + (size_t)b * NN * 256;

    v4f acca = {0.f,0.f,0.f,0.f}, accb = acca;
#pragma unroll
    for (int kk = 0; kk < 8; ++kk) {
        v8s A = *(const v8s*)(wprojb + (size_t)(ot * 16 + l15) * 256 + kk * 32 + 8 * g);
        v8s Ba = *(const v8s*)(ab + (size_t)(na0 + l15) * 256 + kk * 32 + 8 * g);
        v8s Bb = *(const v8s*)(ab + (size_t)(nb0 + l15) * 256 + kk * 32 + 8 * g);
        acca = __builtin_amdgcn_mfma_f32_16x16x32_bf16(A, Ba, acca, 0, 0, 0);
        accb = __builtin_amdgcn_mfma_f32_16x16x32_bf16(A, Bb, accb, 0, 0, 0);
    }
    v4f bias = *(const v4f*)&bproj[ot * 16 + 4 * g];
#pragma unroll
    for (int r = 0; r < 4; ++r) {
        int o = ot * 16 + 4 * g + r;
        out[((size_t)b * 256 + o) * NN + na0 + l15] = acca[r] + bias[r];
        out[((size_t)b * 256 + o) * NN + nb0 + l15] = accb[r] + bias[r];
    }
}

extern "C" void kernel_launch(void* const* d_in, const int* in_sizes, int n_in,
                              void* d_out, int out_size, void* d_ws, size_t ws_size,
                              hipStream_t stream) {
    const float* x     = (const float*)d_in[0];
    const float* luma  = (const float*)d_in[1];
    const float* wqkv  = (const float*)d_in[2];
    const float* bqkv  = (const float*)d_in[3];
    const float* wproj = (const float*)d_in[4];
    const float* bproj = (const float*)d_in[5];
    const float* wc1   = (const float*)d_in[6];
    const float* bc1   = (const float*)d_in[7];
    const float* wc2   = (const float*)d_in[8];
    const float* bc2   = (const float*)d_in[9];
    const float* wg    = (const float*)d_in[10];
    const float* bg    = (const float*)d_in[11];
    const float* wbt   = (const float*)d_in[12];
    const float* bbt   = (const float*)d_in[13];
    const float* alpha = (const float*)d_in[14];
    float* out = (float*)d_out;

    float* ws = (float*)d_ws;
    size_t off = 0;
    float* twc1 = ws + off;           off += 9 * 128;
    short* tc2b = (short*)(ws + off); off += 9 * 128 * 128 / 2;
    short* wqkvb = (short*)(ws + off); off += 768 * 256 / 2;
    short* wgb = (short*)(ws + off);  off += 256 * 128 / 2;
    short* wbtb = (short*)(ws + off); off += 256 * 128 / 2;
    short* wprojb = (short*)(ws + off); off += 256 * 256 / 2;
    short* h1p = (short*)(ws + off);  off += NB * 2500 * 128 / 2;
    short* xt = (short*)(ws + off);   off += NB * NN * 256 / 2;
    short* h2t = (short*)(ws + off);  off += NB * NN * 128 / 2;
    float* gt = ws + off;             off += NB * NN * 256;
    float* btt = ws + off;            off += NB * NN * 256;
    float* invl = ws + off;           off += NB * NN;
    short* qbb = (short*)(ws + off);  off += 16 * NN * DH / 2;
    short* kbb = (short*)(ws + off);  off += 16 * NN * DH / 2;
    short* vraw = (short*)(ws + off); off += 16 * NN * DH / 2;
    short* vtt = (short*)(ws + off);  off += 16 * NN * DH / 2;
    float* vsum = ws + off;           off += 16 * DH;
    float* pl = ws + off;             off += 16 * NN * ASPLIT;
    float* pacc = ws + off;           off += (size_t)16 * NN * ASPLIT * DH;
    short* aotb = (short*)(ws + off); off += NB * NN * 256 / 2;
    (void)ws_size; (void)in_sizes; (void)n_in; (void)out_size;

    k_prep<<<768, 256, 0, stream>>>(wc1, wc2, wqkv, wg, wbt, wproj,
                                    twc1, tc2b, wqkvb, wgb, wbtb, wprojb);
    k_conv1<<<NB * 1250, 256, 0, stream>>>(luma, twc1, bc1, h1p);
    k_xt<<<NB * 4 * 36, 256, 0, stream>>>(x, xt);
    k_conv2m<<<NB * 8 * 72, 64, 0, stream>>>(h1p, tc2b, bc2, h2t);
    k_gbm<<<NB * 16 * 72, 64, 0, stream>>>(h2t, wgb, wbtb, bg, bbt, gt, btt);
    k_invl<<<NB, 256, 0, stream>>>(luma, invl);
    k_qkvm<<<NB * 48 * 72, 64, 0, stream>>>(xt, wqkvb, bqkv, gt, btt, invl, alpha,
                                            qbb, kbb, vraw);
    k_vt<<<16 * 36, 256, 0, stream>>>(vraw, vtt);
    k_vsum<<<16 * DH, 64, 0, stream>>>(vtt, vsum);
    k_attn<<<16 * 72 * ASPLIT, 64, 0, stream>>>(qbb, kbb, vtt, pl, pacc);
    k_merge<<<(16 * NN * DH + 255) / 256, 256, 0, stream>>>(pl, pacc, vsum, aotb);
    k_projm<<<NB * 16 * 72, 64, 0, stream>>>(aotb, wprojb, bproj, out);
}

// Round 6
// 137.150 us; speedup vs baseline: 3.7512x; 1.0329x over previous
//
#include <hip/hip_runtime.h>
#include <hip/hip_bf16.h>
#include <math.h>
#include <string.h>

#define NB 2
#define NN 2304        // 48*48
#define NHEADS 8
#define DH 32
#define KPW 576        // keys per wave in k_attn2 (NN/4)

typedef __attribute__((ext_vector_type(8))) short v8s;   // 8 bf16 in 4 VGPRs
typedef __attribute__((ext_vector_type(4))) float v4f;

__device__ inline unsigned short f2b(float f) {          // fp32 -> bf16 (RNE)
    unsigned u = __builtin_bit_cast(unsigned, f);
    unsigned r = u + 0x7FFFu + ((u >> 16) & 1u);
    return (unsigned short)(r >> 16);
}
__device__ inline float b2f(short s) {
    unsigned u = ((unsigned)(unsigned short)s) << 16;
    return __builtin_bit_cast(float, u);
}
__device__ inline unsigned pk2(float a, float b) {       // 2 fp32 -> packed bf16x2
    __hip_bfloat162 h = __float22bfloat162_rn(make_float2(a, b));
    unsigned r;
    memcpy(&r, &h, sizeof(r));
    return r;
}
__device__ inline float blo(unsigned u) { return __builtin_bit_cast(float, u << 16); }
__device__ inline float bhi(unsigned u) { return __builtin_bit_cast(float, u & 0xffff0000u); }

// ---------------- weight prep: transposes + bf16 conversion ----------------
__global__ void k_prep(const float* __restrict__ wc1, const float* __restrict__ wc2,
                       const float* __restrict__ wqkv, const float* __restrict__ wg,
                       const float* __restrict__ wbt, const float* __restrict__ wproj,
                       float* __restrict__ twc1, short* __restrict__ tc2b,
                       short* __restrict__ wqkvb, short* __restrict__ wgb,
                       short* __restrict__ wbtb, short* __restrict__ wprojb) {
    int i = blockIdx.x * 256 + threadIdx.x;            // 196608 threads
    if (i < 9 * 128) {                                 // twc1[k][c] = wc1[c][k]
        int k = i / 128, c = i % 128;
        twc1[i] = wc1[c * 9 + k];
    }
    if (i < 9 * 128 * 128) {                           // tc2b[s][o][ic] = wc2[o][ic][s]
        int s = i / (128 * 128);
        int rem = i % (128 * 128);
        int o = rem / 128, ic = rem % 128;
        tc2b[i] = (short)f2b(wc2[(o * 128 + ic) * 9 + s]);
    }
    if (i < 768 * 256) wqkvb[i] = (short)f2b(wqkv[i]);
    if (i < 256 * 128) { wgb[i] = (short)f2b(wg[i]); wbtb[i] = (short)f2b(wbt[i]); }
    if (i < 256 * 256) wprojb[i] = (short)f2b(wproj[i]);
}

// ---------------- conv1 -> h1p: padded(50x50) transposed [b][p][128] bf16 ----------------
__global__ void k_conv1(const float* __restrict__ luma, const float* __restrict__ twc1,
                        const float* __restrict__ bc1, short* __restrict__ h1p) {
    int c = threadIdx.x & 127;
    int p = (blockIdx.x % 1250) * 2 + (threadIdx.x >> 7);
    int b = blockIdx.x / 1250;
    int py = p / 50, px = p % 50;
    float val = 0.f;
    if (py >= 1 && py <= 48 && px >= 1 && px <= 48) {
        int y = py - 1, x = px - 1;
        const float* lb = luma + b * NN;
        float acc = bc1[c];
#pragma unroll
        for (int ky = 0; ky < 3; ++ky) {
            int yy = y + ky - 1;
            if (yy < 0 || yy >= 48) continue;
#pragma unroll
            for (int kx = 0; kx < 3; ++kx) {
                int xx = x + kx - 1;
                if (xx < 0 || xx >= 48) continue;
                acc += twc1[(ky * 3 + kx) * 128 + c] * lb[yy * 48 + xx];
            }
        }
        val = fmaxf(acc, 0.f);
    }
    h1p[((size_t)b * 2500 + p) * 128 + c] = (short)f2b(val);
}

// ---------------- x transpose: [b][256][2304] fp32 -> xt [b][2304][256] bf16 ----------------
__global__ void k_xt(const float* __restrict__ x, short* __restrict__ xt) {
    __shared__ unsigned short lds[64 * 66];            // [n][66] pad
    int blk = blockIdx.x;
    int nt = blk % 36, ct = (blk / 36) % 4, b = blk / 144;
    int n0 = nt * 64, c0 = ct * 64;
    int nc = threadIdx.x & 63, cr = threadIdx.x >> 6;
#pragma unroll
    for (int i = 0; i < 16; ++i) {
        int cs = i * 4 + cr;
        float v = x[((size_t)b * 256 + c0 + cs) * NN + n0 + nc];
        lds[nc * 66 + cs] = f2b(v);
    }
    __syncthreads();
    int cc = threadIdx.x & 31, nr = threadIdx.x >> 5;
    unsigned* xt2 = (unsigned*)xt;
#pragma unroll
    for (int j = 0; j < 8; ++j) {
        int ns = j * 8 + nr;
        unsigned w = *(unsigned*)&lds[ns * 66 + 2 * cc];
        xt2[(((size_t)b * NN + n0 + ns) * 256 + c0) / 2 + cc] = w;
    }
}

// ---------------- conv2 as 9-shift MFMA GEMM -> h2t [b][n][128] bf16 (bias+relu) ----------------
__global__ __launch_bounds__(64) void k_conv2m(const short* __restrict__ h1p,
                                               const short* __restrict__ tc2b,
                                               const float* __restrict__ bc2,
                                               short* __restrict__ h2t) {
    int lane = threadIdx.x, l15 = lane & 15, g = lane >> 4;
    int blk = blockIdx.x;
    int ntg = blk % 72, ot = (blk / 72) % 8, b = blk / (72 * 8);
    int nta = ntg * 2, ntb = ntg * 2 + 1;
    int ya = nta / 3, xa = (nta % 3) * 16;
    int yb = ntb / 3, xb = (ntb % 3) * 16;
    int p0a = (ya + 1) * 50 + xa + 1;
    int p0b = (yb + 1) * 50 + xb + 1;
    const short* hb = h1p + (size_t)b * 2500 * 128;

    v4f acca = {0.f,0.f,0.f,0.f}, accb = acca;
#pragma unroll
    for (int s = 0; s < 9; ++s) {
        int dp = (s / 3 - 1) * 50 + (s % 3 - 1);
#pragma unroll
        for (int kk = 0; kk < 4; ++kk) {
            v8s A = *(const v8s*)(tc2b + ((size_t)(s * 128 + ot * 16 + l15)) * 128 + kk * 32 + 8 * g);
            v8s Ba = *(const v8s*)(hb + (size_t)(p0a + dp + l15) * 128 + kk * 32 + 8 * g);
            v8s Bb = *(const v8s*)(hb + (size_t)(p0b + dp + l15) * 128 + kk * 32 + 8 * g);
            acca = __builtin_amdgcn_mfma_f32_16x16x32_bf16(A, Ba, acca, 0, 0, 0);
            accb = __builtin_amdgcn_mfma_f32_16x16x32_bf16(A, Bb, accb, 0, 0, 0);
        }
    }
    v4f bias = *(const v4f*)&bc2[ot * 16 + 4 * g];
    int na = ya * 48 + xa + l15, nb = yb * 48 + xb + l15;
    uint2 wa, wb;
    wa.x = pk2(fmaxf(acca[0] + bias[0], 0.f), fmaxf(acca[1] + bias[1], 0.f));
    wa.y = pk2(fmaxf(acca[2] + bias[2], 0.f), fmaxf(acca[3] + bias[3], 0.f));
    wb.x = pk2(fmaxf(accb[0] + bias[0], 0.f), fmaxf(accb[1] + bias[1], 0.f));
    wb.y = pk2(fmaxf(accb[2] + bias[2], 0.f), fmaxf(accb[3] + bias[3], 0.f));
    *(uint2*)&h2t[((size_t)b * NN + na) * 128 + ot * 16 + 4 * g] = wa;
    *(uint2*)&h2t[((size_t)b * NN + nb) * 128 + ot * 16 + 4 * g] = wb;
}

// ---------------- gamma/beta MFMA GEMMs -> gtb/bttb bf16 [b][n][256] ----------------
__global__ __launch_bounds__(64) void k_gbm(const short* __restrict__ h2t,
                                            const short* __restrict__ wgb,
                                            const short* __restrict__ wbtb,
                                            const float* __restrict__ bg,
                                            const float* __restrict__ bbt,
                                            short* __restrict__ gtb, short* __restrict__ bttb) {
    int lane = threadIdx.x, l15 = lane & 15, g = lane >> 4;
    int blk = blockIdx.x;
    int ntg = blk % 72, ot = (blk / 72) % 16, b = blk / (72 * 16);
    int na0 = ntg * 32, nb0 = ntg * 32 + 16;
    const short* hb = h2t + (size_t)b * NN * 128;

    v4f ga = {0.f,0.f,0.f,0.f}, gb = ga, ta = ga, tb = ga;
#pragma unroll
    for (int kk = 0; kk < 4; ++kk) {
        v8s Ag = *(const v8s*)(wgb + (size_t)(ot * 16 + l15) * 128 + kk * 32 + 8 * g);
        v8s At = *(const v8s*)(wbtb + (size_t)(ot * 16 + l15) * 128 + kk * 32 + 8 * g);
        v8s Ba = *(const v8s*)(hb + (size_t)(na0 + l15) * 128 + kk * 32 + 8 * g);
        v8s Bb = *(const v8s*)(hb + (size_t)(nb0 + l15) * 128 + kk * 32 + 8 * g);
        ga = __builtin_amdgcn_mfma_f32_16x16x32_bf16(Ag, Ba, ga, 0, 0, 0);
        gb = __builtin_amdgcn_mfma_f32_16x16x32_bf16(Ag, Bb, gb, 0, 0, 0);
        ta = __builtin_amdgcn_mfma_f32_16x16x32_bf16(At, Ba, ta, 0, 0, 0);
        tb = __builtin_amdgcn_mfma_f32_16x16x32_bf16(At, Bb, tb, 0, 0, 0);
    }
    v4f bgv = *(const v4f*)&bg[ot * 16 + 4 * g];
    v4f bbv = *(const v4f*)&bbt[ot * 16 + 4 * g];
    size_t oa = ((size_t)b * NN + na0 + l15) * 256 + ot * 16 + 4 * g;
    size_t ob = ((size_t)b * NN + nb0 + l15) * 256 + ot * 16 + 4 * g;
    uint2 w;
    w.x = pk2(ga[0] + bgv[0], ga[1] + bgv[1]); w.y = pk2(ga[2] + bgv[2], ga[3] + bgv[3]);
    *(uint2*)&gtb[oa] = w;
    w.x = pk2(gb[0] + bgv[0], gb[1] + bgv[1]); w.y = pk2(gb[2] + bgv[2], gb[3] + bgv[3]);
    *(uint2*)&gtb[ob] = w;
    w.x = pk2(ta[0] + bbv[0], ta[1] + bbv[1]); w.y = pk2(ta[2] + bbv[2], ta[3] + bbv[3]);
    *(uint2*)&bttb[oa] = w;
    w.x = pk2(tb[0] + bbv[0], tb[1] + bbv[1]); w.y = pk2(tb[2] + bbv[2], tb[3] + bbv[3]);
    *(uint2*)&bttb[ob] = w;
}

// ---------------- invL: avgpool3x3(1-luma) centered per batch ----------------
__global__ void k_invl(const float* __restrict__ luma, float* __restrict__ invl) {
    __shared__ float red[256];
    int b = blockIdx.x;
    const float* lb = luma + b * NN;
    float pooled[9];
    float local = 0.f;
#pragma unroll
    for (int it = 0; it < 9; ++it) {
        int n = it * 256 + threadIdx.x;
        int y = n / 48, x = n % 48;
        float s = 0.f;
        for (int ky = 0; ky < 3; ++ky) {
            int yy = y + ky - 1;
            if (yy < 0 || yy >= 48) continue;
            for (int kx = 0; kx < 3; ++kx) {
                int xx = x + kx - 1;
                if (xx < 0 || xx >= 48) continue;
                s += 1.f - lb[yy * 48 + xx];
            }
        }
        s *= (1.f / 9.f);
        pooled[it] = s;
        local += s;
    }
    red[threadIdx.x] = local;
    __syncthreads();
    for (int off = 128; off > 0; off >>= 1) {
        if (threadIdx.x < off) red[threadIdx.x] += red[threadIdx.x + off];
        __syncthreads();
    }
    float mean = red[0] * (1.f / NN);
#pragma unroll
    for (int it = 0; it < 9; ++it) {
        int n = it * 256 + threadIdx.x;
        invl[b * NN + n] = pooled[it] - mean;
    }
}

// ---------------- qkv MFMA GEMM + modulation epilogue -> qb, kb, vraw bf16 ----------------
__global__ __launch_bounds__(64) void k_qkvm(const short* __restrict__ xt,
                                             const short* __restrict__ wqkvb,
                                             const float* __restrict__ bqkv,
                                             const short* __restrict__ gtb,
                                             const short* __restrict__ bttb,
                                             const float* __restrict__ invl,
                                             const float* __restrict__ alpha_p,
                                             short* __restrict__ qb, short* __restrict__ kb,
                                             short* __restrict__ vraw) {
    int lane = threadIdx.x, l15 = lane & 15, g = lane >> 4;
    int blk = blockIdx.x;
    int ntg = blk % 72, ot = (blk / 72) % 48, b = blk / (72 * 48);
    int na0 = ntg * 32, nb0 = ntg * 32 + 16;
    const short* xb = xt + (size_t)b * NN * 256;

    v4f acca = {0.f,0.f,0.f,0.f}, accb = acca;
#pragma unroll
    for (int kk = 0; kk < 8; ++kk) {
        v8s A = *(const v8s*)(wqkvb + (size_t)(ot * 16 + l15) * 256 + kk * 32 + 8 * g);
        v8s Ba = *(const v8s*)(xb + (size_t)(na0 + l15) * 256 + kk * 32 + 8 * g);
        v8s Bb = *(const v8s*)(xb + (size_t)(nb0 + l15) * 256 + kk * 32 + 8 * g);
        acca = __builtin_amdgcn_mfma_f32_16x16x32_bf16(A, Ba, acca, 0, 0, 0);
        accb = __builtin_amdgcn_mfma_f32_16x16x32_bf16(A, Bb, accb, 0, 0, 0);
    }
    int which = ot >> 4;
    int cbase = (ot & 15) * 16 + 4 * g;
    int h = cbase >> 5, dbase = cbase & 31;
    v4f bias = *(const v4f*)&bqkv[which * 256 + cbase];
    const float scale = 0.17677669529663687f;
    float alpha = *alpha_p;
    short* dst = (which == 0) ? qb : (which == 1) ? kb : vraw;
#pragma unroll
    for (int t = 0; t < 2; ++t) {
        int n = (t == 0 ? na0 : nb0) + l15;
        v4f acc = (t == 0) ? acca : accb;
        uint2 gg = *(const uint2*)&gtb[((size_t)b * NN + n) * 256 + cbase];
        uint2 tt = *(const uint2*)&bttb[((size_t)b * NN + n) * 256 + cbase];
        float iv = (which == 0) ? alpha * invl[b * NN + n] : 0.f;
        float v0 = blo(gg.x) * (acc[0] + bias[0]) + blo(tt.x);
        float v1 = bhi(gg.x) * (acc[1] + bias[1]) + bhi(tt.x);
        float v2 = blo(gg.y) * (acc[2] + bias[2]) + blo(tt.y);
        float v3 = bhi(gg.y) * (acc[3] + bias[3]) + bhi(tt.y);
        if (which == 0) {
            v0 = (v0 + iv) * scale; v1 = (v1 + iv) * scale;
            v2 = (v2 + iv) * scale; v3 = (v3 + iv) * scale;
        }
        uint2 w;
        w.x = pk2(v0, v1);
        w.y = pk2(v2, v3);
        *(uint2*)&dst[(((size_t)b * NHEADS + h) * NN + n) * DH + dbase] = w;
    }
}

// ---------------- V transpose: vraw [bh][n][32] -> vt [bh][32][2304] ----------------
__global__ void k_vt(const short* __restrict__ vraw, short* __restrict__ vt) {
    __shared__ unsigned short lds[64 * 34];
    int bh = blockIdx.x / 36, nc = blockIdx.x % 36;
    int n0 = nc * 64;
    int dpair = threadIdx.x & 15, nsub = (threadIdx.x >> 4) & 15;
    const unsigned* vr2 = (const unsigned*)vraw;
#pragma unroll
    for (int i = 0; i < 4; ++i) {
        int ns = i * 16 + nsub;
        unsigned v = vr2[((size_t)bh * NN + n0 + ns) * 16 + dpair];
        *(unsigned*)&lds[ns * 34 + 2 * dpair] = v;
    }
    __syncthreads();
    int npair = threadIdx.x & 31, drow = threadIdx.x >> 5;
    unsigned* vt2 = (unsigned*)vt;
#pragma unroll
    for (int j = 0; j < 4; ++j) {
        int d = j * 8 + drow;
        unsigned lo = lds[(2 * npair) * 34 + d];
        unsigned hi = lds[(2 * npair + 1) * 34 + d];
        vt2[((size_t)bh * DH + d) * (NN / 2) + n0 / 2 + npair] = lo | (hi << 16);
    }
}

// ---------------- V row-sums ----------------
__global__ __launch_bounds__(64) void k_vsum(const short* __restrict__ vt,
                                             float* __restrict__ vsum) {
    int row = blockIdx.x;            // 16*32 rows
    int lane = threadIdx.x;
    const short* rp = vt + (size_t)row * NN;
    float s = 0.f;
    for (int n = lane; n < NN; n += 64) s += b2f(rp[n]);
#pragma unroll
    for (int off = 32; off > 0; off >>= 1) s += __shfl_xor(s, off);
    if (lane == 0) vsum[row] = s;
}

// ---------------- fused attention: 4 waves split K in-block, merge in LDS ----------------
// grid 1152 (XCD-swizzled -> bh = logical/72, qt = logical%72), block 256.
// p' = exp(s)-1 trick: out = (vsum + sum_k p'*v) / (NN + sum_k p').
__global__ __launch_bounds__(256) void k_attn2(const short* __restrict__ qb,
                                               const short* __restrict__ kbuf,
                                               const short* __restrict__ vt,
                                               const float* __restrict__ vsum,
                                               short* __restrict__ aotb) {
    __shared__ short plds[4][32 * 40];      // per-wave P' tile, rows padded to 80 B
    __shared__ float acc_lds[4][32][36];    // per-wave partial O, pad 36 (16B-aligned rows)
    __shared__ float ps_lds[4][32];         // per-wave row-sums of p'
    int tid = threadIdx.x;
    int w = tid >> 6, lane = tid & 63;
    int l15 = lane & 15, g = lane >> 4;
    int blk = blockIdx.x;
    int logical = (blk & 7) * 144 + (blk >> 3);   // XCD swizzle: 1152 = 8*144
    int qt = logical % 72, bh = logical / 72;
    int qbase = qt * 32;

    const short* qp = qb + ((size_t)bh * NN + qbase) * DH;
    const short* kp = kbuf + ((size_t)bh * NN + w * KPW) * DH;
    const short* vp = vt + (size_t)bh * DH * NN + w * KPW;

    v8s q0 = *(const v8s*)(qp + l15 * DH + 8 * g);
    v8s q1 = *(const v8s*)(qp + (16 + l15) * DH + 8 * g);

    v4f acc00 = {0.f,0.f,0.f,0.f}, acc01 = acc00, acc10 = acc00, acc11 = acc00;
    float ps0 = 0.f, ps1 = 0.f;
    short* pw = plds[w];

    for (int kb = 0; kb < KPW; kb += 32) {
        v8s ka0 = *(const v8s*)(kp + (kb + l15) * DH + 8 * g);
        v8s ka1 = *(const v8s*)(kp + (kb + 16 + l15) * DH + 8 * g);
        v4f s00 = __builtin_amdgcn_mfma_f32_16x16x32_bf16(ka0, q0, (v4f){0.f,0.f,0.f,0.f}, 0, 0, 0);
        v4f s01 = __builtin_amdgcn_mfma_f32_16x16x32_bf16(ka0, q1, (v4f){0.f,0.f,0.f,0.f}, 0, 0, 0);
        v4f s10 = __builtin_amdgcn_mfma_f32_16x16x32_bf16(ka1, q0, (v4f){0.f,0.f,0.f,0.f}, 0, 0, 0);
        v4f s11 = __builtin_amdgcn_mfma_f32_16x16x32_bf16(ka1, q1, (v4f){0.f,0.f,0.f,0.f}, 0, 0, 0);

        // p' = exp(s)-1; row-sum; stash P'^T -> per-wave LDS as row-major P'[q][k] bf16
#define DOFRAG(S, QTL, KT, PS)                                                   \
        {                                                                        \
            float p0 = __expf((S)[0]) - 1.f, p1 = __expf((S)[1]) - 1.f;          \
            float p2 = __expf((S)[2]) - 1.f, p3 = __expf((S)[3]) - 1.f;          \
            PS += (p0 + p1) + (p2 + p3);                                         \
            uint2 wv;                                                            \
            wv.x = pk2(p0, p1);                                                  \
            wv.y = pk2(p2, p3);                                                  \
            *(uint2*)((char*)pw + ((QTL) * 16 + l15) * 80 + ((KT) * 16 + 4 * g) * 2) = wv; \
        }
        DOFRAG(s00, 0, 0, ps0)
        DOFRAG(s01, 1, 0, ps1)
        DOFRAG(s10, 0, 1, ps0)
        DOFRAG(s11, 1, 1, ps1)
#undef DOFRAG
        // per-wave private LDS slice: DS ops of one wave execute in order -> no barrier
        v8s pa0 = *(v8s*)((char*)pw + l15 * 80 + 16 * g);
        v8s pa1 = *(v8s*)((char*)pw + (16 + l15) * 80 + 16 * g);
        v8s vb0 = *(const v8s*)(vp + (size_t)l15 * NN + kb + 8 * g);
        v8s vb1 = *(const v8s*)(vp + (size_t)(16 + l15) * NN + kb + 8 * g);
        acc00 = __builtin_amdgcn_mfma_f32_16x16x32_bf16(pa0, vb0, acc00, 0, 0, 0);
        acc01 = __builtin_amdgcn_mfma_f32_16x16x32_bf16(pa0, vb1, acc01, 0, 0, 0);
        acc10 = __builtin_amdgcn_mfma_f32_16x16x32_bf16(pa1, vb0, acc10, 0, 0, 0);
        acc11 = __builtin_amdgcn_mfma_f32_16x16x32_bf16(pa1, vb1, acc11, 0, 0, 0);
    }

    // per-wave row-sum reduction across 4 lane-groups
    ps0 += __shfl_xor(ps0, 16); ps0 += __shfl_xor(ps0, 32);
    ps1 += __shfl_xor(ps1, 16); ps1 += __shfl_xor(ps1, 32);
    if (lane < 16) ps_lds[w][l15] = ps0;
    else if (lane < 32) ps_lds[w][16 + l15] = ps1;

    // dump partial acc to LDS: frag (QTL,DT) value r -> q = QTL*16+4g+r, d = DT*16+l15
#define DUMP(ACC, QTL, DT)                                                         \
    {                                                                              \
        _Pragma("unroll")                                                          \
        for (int r = 0; r < 4; ++r)                                                \
            acc_lds[w][(QTL) * 16 + 4 * g + r][(DT) * 16 + l15] = (ACC)[r];        \
    }
    DUMP(acc00, 0, 0)
    DUMP(acc01, 1, 0)
    DUMP(acc10, 0, 1)
    DUMP(acc11, 1, 1)
#undef DUMP
    __syncthreads();

    // cooperative merge: thread t -> q = t>>3 (32), d0 = (t&7)*4
    int q = tid >> 3, d0 = (tid & 7) * 4;
    float L = (float)NN;
    v4f a = {0.f, 0.f, 0.f, 0.f};
#pragma unroll
    for (int wv = 0; wv < 4; ++wv) {
        L += ps_lds[wv][q];
        v4f t4 = *(v4f*)&acc_lds[wv][q][d0];
        a[0] += t4[0]; a[1] += t4[1]; a[2] += t4[2]; a[3] += t4[3];
    }
    const float* vs = vsum + bh * DH + d0;
    float rl = 1.f / L;
    uint2 o;
    o.x = pk2((a[0] + vs[0]) * rl, (a[1] + vs[1]) * rl);
    o.y = pk2((a[2] + vs[2]) * rl, (a[3] + vs[3]) * rl);
    int b = bh >> 3, h = bh & 7;
    *(uint2*)&aotb[((size_t)b * NN + qbase + q) * 256 + h * DH + d0] = o;
}

// ---------------- output projection MFMA GEMM ----------------
__global__ __launch_bounds__(64) void k_projm(const short* __restrict__ aotb,
                                              const short* __restrict__ wprojb,
                                              const float* __restrict__ bproj,
                                              float* __restrict__ out) {
    int lane = threadIdx.x, l15 = lane & 15, g = lane >> 4;
    int blk = blockIdx.x;
    int ntg = blk % 72, ot = (blk / 72) % 16, b = blk / (72 * 16);
    int na0 = ntg * 32, nb0 = ntg * 32 + 16;
    const short* ab = aotb + (size_t)b * NN * 256;

    v4f acca = {0.f,0.f,0.f,0.f}, accb = acca;
#pragma unroll
    for (int kk = 0; kk < 8; ++kk) {
        v8s A = *(const v8s*)(wprojb + (size_t)(ot * 16 + l15) * 256 + kk * 32 + 8 * g);
        v8s Ba = *(const v8s*)(ab + (size_t)(na0 + l15) * 256 + kk * 32 + 8 * g);
        v8s Bb = *(const v8s*)(ab + (size_t)(nb0 + l15) * 256 + kk * 32 + 8 * g);
        acca = __builtin_amdgcn_mfma_f32_16x16x32_bf16(A, Ba, acca, 0, 0, 0);
        accb = __builtin_amdgcn_mfma_f32_16x16x32_bf16(A, Bb, accb, 0, 0, 0);
    }
    v4f bias = *(const v4f*)&bproj[ot * 16 + 4 * g];
#pragma unroll
    for (int r = 0; r < 4; ++r) {
        int o = ot * 16 + 4 * g + r;
        out[((size_t)b * 256 + o) * NN + na0 + l15] = acca[r] + bias[r];
        out[((size_t)b * 256 + o) * NN + nb0 + l15] = accb[r] + bias[r];
    }
}

extern "C" void kernel_launch(void* const* d_in, const int* in_sizes, int n_in,
                              void* d_out, int out_size, void* d_ws, size_t ws_size,
                              hipStream_t stream) {
    const float* x     = (const float*)d_in[0];
    const float* luma  = (const float*)d_in[1];
    const float* wqkv  = (const float*)d_in[2];
    const float* bqkv  = (const float*)d_in[3];
    const float* wproj = (const float*)d_in[4];
    const float* bproj = (const float*)d_in[5];
    const float* wc1   = (const float*)d_in[6];
    const float* bc1   = (const float*)d_in[7];
    const float* wc2   = (const float*)d_in[8];
    const float* bc2   = (const float*)d_in[9];
    const float* wg    = (const float*)d_in[10];
    const float* bg    = (const float*)d_in[11];
    const float* wbt   = (const float*)d_in[12];
    const float* bbt   = (const float*)d_in[13];
    const float* alpha = (const float*)d_in[14];
    float* out = (float*)d_out;

    float* ws = (float*)d_ws;
    size_t off = 0;
    float* twc1 = ws + off;            off += 9 * 128;
    short* tc2b = (short*)(ws + off);  off += 9 * 128 * 128 / 2;
    short* wqkvb = (short*)(ws + off); off += 768 * 256 / 2;
    short* wgb = (short*)(ws + off);   off += 256 * 128 / 2;
    short* wbtb = (short*)(ws + off);  off += 256 * 128 / 2;
    short* wprojb = (short*)(ws + off); off += 256 * 256 / 2;
    short* h1p = (short*)(ws + off);   off += NB * 2500 * 128 / 2;
    short* xt = (short*)(ws + off);    off += NB * NN * 256 / 2;
    short* h2t = (short*)(ws + off);   off += NB * NN * 128 / 2;
    short* gtb = (short*)(ws + off);   off += NB * NN * 256 / 2;
    short* bttb = (short*)(ws + off);  off += NB * NN * 256 / 2;
    float* invl = ws + off;            off += NB * NN;
    short* qbb = (short*)(ws + off);   off += 16 * NN * DH / 2;
    short* kbb = (short*)(ws + off);   off += 16 * NN * DH / 2;
    short* vraw = (short*)(ws + off);  off += 16 * NN * DH / 2;
    short* vtt = (short*)(ws + off);   off += 16 * NN * DH / 2;
    float* vsum = ws + off;            off += 16 * DH;
    short* aotb = (short*)(ws + off);  off += NB * NN * 256 / 2;
    (void)ws_size; (void)in_sizes; (void)n_in; (void)out_size;

    k_prep<<<768, 256, 0, stream>>>(wc1, wc2, wqkv, wg, wbt, wproj,
                                    twc1, tc2b, wqkvb, wgb, wbtb, wprojb);
    k_conv1<<<NB * 1250, 256, 0, stream>>>(luma, twc1, bc1, h1p);
    k_xt<<<NB * 4 * 36, 256, 0, stream>>>(x, xt);
    k_conv2m<<<NB * 8 * 72, 64, 0, stream>>>(h1p, tc2b, bc2, h2t);
    k_gbm<<<NB * 16 * 72, 64, 0, stream>>>(h2t, wgb, wbtb, bg, bbt, gtb, bttb);
    k_invl<<<NB, 256, 0, stream>>>(luma, invl);
    k_qkvm<<<NB * 48 * 72, 64, 0, stream>>>(xt, wqkvb, bqkv, gtb, bttb, invl, alpha,
                                            qbb, kbb, vraw);
    k_vt<<<16 * 36, 256, 0, stream>>>(vraw, vtt);
    k_vsum<<<16 * DH, 64, 0, stream>>>(vtt, vsum);
    k_attn2<<<16 * 72, 256, 0, stream>>>(qbb, kbb, vtt, vsum, aotb);
    k_projm<<<NB * 16 * 72, 64, 0, stream>>>(aotb, wprojb, bproj, out);
}

// Round 7
// 129.884 us; speedup vs baseline: 3.9610x; 1.0559x over previous
//
#include <hip/hip_runtime.h>
#include <hip/hip_bf16.h>
#include <math.h>
#include <string.h>

#define NB 2
#define NN 2304        // 48*48
#define NHEADS 8
#define DH 32
#define KPW 576        // keys per wave in k_attn2 (NN/4)

typedef __attribute__((ext_vector_type(8))) short v8s;   // 8 bf16 in 4 VGPRs
typedef __attribute__((ext_vector_type(4))) float v4f;

__device__ inline unsigned short f2b(float f) {          // fp32 -> bf16 (RNE)
    unsigned u = __builtin_bit_cast(unsigned, f);
    unsigned r = u + 0x7FFFu + ((u >> 16) & 1u);
    return (unsigned short)(r >> 16);
}
__device__ inline float b2f(short s) {
    unsigned u = ((unsigned)(unsigned short)s) << 16;
    return __builtin_bit_cast(float, u);
}
__device__ inline unsigned pk2(float a, float b) {       // 2 fp32 -> packed bf16x2
    __hip_bfloat162 h = __float22bfloat162_rn(make_float2(a, b));
    unsigned r;
    memcpy(&r, &h, sizeof(r));
    return r;
}
__device__ inline float blo(unsigned u) { return __builtin_bit_cast(float, u << 16); }
__device__ inline float bhi(unsigned u) { return __builtin_bit_cast(float, u & 0xffff0000u); }

// ---------------- weight prep: transposes + bf16 conversion ----------------
__global__ void k_prep(const float* __restrict__ wc1, const float* __restrict__ wc2,
                       const float* __restrict__ wqkv, const float* __restrict__ wg,
                       const float* __restrict__ wbt, const float* __restrict__ wproj,
                       float* __restrict__ twc1, short* __restrict__ tc2b,
                       short* __restrict__ wqkvb, short* __restrict__ wgb,
                       short* __restrict__ wbtb, short* __restrict__ wprojb) {
    int i = blockIdx.x * 256 + threadIdx.x;            // 196608 threads
    if (i < 9 * 128) {                                 // twc1[k][c] = wc1[c][k]
        int k = i / 128, c = i % 128;
        twc1[i] = wc1[c * 9 + k];
    }
    if (i < 9 * 128 * 128) {                           // tc2b[s][o][ic] = wc2[o][ic][s]
        int s = i / (128 * 128);
        int rem = i % (128 * 128);
        int o = rem / 128, ic = rem % 128;
        tc2b[i] = (short)f2b(wc2[(o * 128 + ic) * 9 + s]);
    }
    if (i < 768 * 256) wqkvb[i] = (short)f2b(wqkv[i]);
    if (i < 256 * 128) { wgb[i] = (short)f2b(wg[i]); wbtb[i] = (short)f2b(wbt[i]); }
    if (i < 256 * 256) wprojb[i] = (short)f2b(wproj[i]);
}

// ---------------- conv1 -> h1p: padded(50x50) transposed [b][p][128] bf16 ----------------
__global__ void k_conv1(const float* __restrict__ luma, const float* __restrict__ twc1,
                        const float* __restrict__ bc1, short* __restrict__ h1p) {
    int c = threadIdx.x & 127;
    int p = (blockIdx.x % 1250) * 2 + (threadIdx.x >> 7);
    int b = blockIdx.x / 1250;
    int py = p / 50, px = p % 50;
    float val = 0.f;
    if (py >= 1 && py <= 48 && px >= 1 && px <= 48) {
        int y = py - 1, x = px - 1;
        const float* lb = luma + b * NN;
        float acc = bc1[c];
#pragma unroll
        for (int ky = 0; ky < 3; ++ky) {
            int yy = y + ky - 1;
            if (yy < 0 || yy >= 48) continue;
#pragma unroll
            for (int kx = 0; kx < 3; ++kx) {
                int xx = x + kx - 1;
                if (xx < 0 || xx >= 48) continue;
                acc += twc1[(ky * 3 + kx) * 128 + c] * lb[yy * 48 + xx];
            }
        }
        val = fmaxf(acc, 0.f);
    }
    h1p[((size_t)b * 2500 + p) * 128 + c] = (short)f2b(val);
}

// ---------------- x transpose (blocks 0..NB*144-1) + invL (last NB blocks) ----------------
__global__ void k_xt(const float* __restrict__ x, short* __restrict__ xt,
                     const float* __restrict__ luma, float* __restrict__ invl) {
    __shared__ unsigned short lds[64 * 66];            // [n][66] pad (xt path)
    __shared__ float red[256];                         // invl path
    int blk = blockIdx.x;
    if (blk >= NB * 144) {
        // ---- invL: avgpool3x3(1-luma) centered per batch ----
        int b = blk - NB * 144;
        const float* lb = luma + b * NN;
        float pooled[9];
        float local = 0.f;
#pragma unroll
        for (int it = 0; it < 9; ++it) {
            int n = it * 256 + threadIdx.x;
            int y = n / 48, xx0 = n % 48;
            float s = 0.f;
            for (int ky = 0; ky < 3; ++ky) {
                int yy = y + ky - 1;
                if (yy < 0 || yy >= 48) continue;
                for (int kx = 0; kx < 3; ++kx) {
                    int xx = xx0 + kx - 1;
                    if (xx < 0 || xx >= 48) continue;
                    s += 1.f - lb[yy * 48 + xx];
                }
            }
            s *= (1.f / 9.f);
            pooled[it] = s;
            local += s;
        }
        red[threadIdx.x] = local;
        __syncthreads();
        for (int off = 128; off > 0; off >>= 1) {
            if (threadIdx.x < off) red[threadIdx.x] += red[threadIdx.x + off];
            __syncthreads();
        }
        float mean = red[0] * (1.f / NN);
#pragma unroll
        for (int it = 0; it < 9; ++it) {
            int n = it * 256 + threadIdx.x;
            invl[b * NN + n] = pooled[it] - mean;
        }
        return;
    }
    // ---- x transpose: [b][256][2304] fp32 -> xt [b][2304][256] bf16 ----
    int nt = blk % 36, ct = (blk / 36) % 4, b = blk / 144;
    int n0 = nt * 64, c0 = ct * 64;
    int nc = threadIdx.x & 63, cr = threadIdx.x >> 6;
#pragma unroll
    for (int i = 0; i < 16; ++i) {
        int cs = i * 4 + cr;
        float v = x[((size_t)b * 256 + c0 + cs) * NN + n0 + nc];
        lds[nc * 66 + cs] = f2b(v);
    }
    __syncthreads();
    int cc = threadIdx.x & 31, nr = threadIdx.x >> 5;
    unsigned* xt2 = (unsigned*)xt;
#pragma unroll
    for (int j = 0; j < 8; ++j) {
        int ns = j * 8 + nr;
        unsigned w = *(unsigned*)&lds[ns * 66 + 2 * cc];
        xt2[(((size_t)b * NN + n0 + ns) * 256 + c0) / 2 + cc] = w;
    }
}

// ---------------- conv2 as 9-shift MFMA GEMM -> h2t [b][n][128] bf16 (bias+relu) ----------------
__global__ __launch_bounds__(64) void k_conv2m(const short* __restrict__ h1p,
                                               const short* __restrict__ tc2b,
                                               const float* __restrict__ bc2,
                                               short* __restrict__ h2t) {
    int lane = threadIdx.x, l15 = lane & 15, g = lane >> 4;
    int blk = blockIdx.x;
    int ntg = blk % 72, ot = (blk / 72) % 8, b = blk / (72 * 8);
    int nta = ntg * 2, ntb = ntg * 2 + 1;
    int ya = nta / 3, xa = (nta % 3) * 16;
    int yb = ntb / 3, xb = (ntb % 3) * 16;
    int p0a = (ya + 1) * 50 + xa + 1;
    int p0b = (yb + 1) * 50 + xb + 1;
    const short* hb = h1p + (size_t)b * 2500 * 128;

    v4f acca = {0.f,0.f,0.f,0.f}, accb = acca;
#pragma unroll
    for (int s = 0; s < 9; ++s) {
        int dp = (s / 3 - 1) * 50 + (s % 3 - 1);
#pragma unroll
        for (int kk = 0; kk < 4; ++kk) {
            v8s A = *(const v8s*)(tc2b + ((size_t)(s * 128 + ot * 16 + l15)) * 128 + kk * 32 + 8 * g);
            v8s Ba = *(const v8s*)(hb + (size_t)(p0a + dp + l15) * 128 + kk * 32 + 8 * g);
            v8s Bb = *(const v8s*)(hb + (size_t)(p0b + dp + l15) * 128 + kk * 32 + 8 * g);
            acca = __builtin_amdgcn_mfma_f32_16x16x32_bf16(A, Ba, acca, 0, 0, 0);
            accb = __builtin_amdgcn_mfma_f32_16x16x32_bf16(A, Bb, accb, 0, 0, 0);
        }
    }
    v4f bias = *(const v4f*)&bc2[ot * 16 + 4 * g];
    int na = ya * 48 + xa + l15, nb = yb * 48 + xb + l15;
    uint2 wa, wb;
    wa.x = pk2(fmaxf(acca[0] + bias[0], 0.f), fmaxf(acca[1] + bias[1], 0.f));
    wa.y = pk2(fmaxf(acca[2] + bias[2], 0.f), fmaxf(acca[3] + bias[3], 0.f));
    wb.x = pk2(fmaxf(accb[0] + bias[0], 0.f), fmaxf(accb[1] + bias[1], 0.f));
    wb.y = pk2(fmaxf(accb[2] + bias[2], 0.f), fmaxf(accb[3] + bias[3], 0.f));
    *(uint2*)&h2t[((size_t)b * NN + na) * 128 + ot * 16 + 4 * g] = wa;
    *(uint2*)&h2t[((size_t)b * NN + nb) * 128 + ot * 16 + 4 * g] = wb;
}

// ---------------- gamma/beta MFMA GEMMs -> gtb/bttb bf16 [b][n][256] ----------------
__global__ __launch_bounds__(64) void k_gbm(const short* __restrict__ h2t,
                                            const short* __restrict__ wgb,
                                            const short* __restrict__ wbtb,
                                            const float* __restrict__ bg,
                                            const float* __restrict__ bbt,
                                            short* __restrict__ gtb, short* __restrict__ bttb) {
    int lane = threadIdx.x, l15 = lane & 15, g = lane >> 4;
    int blk = blockIdx.x;
    int ntg = blk % 72, ot = (blk / 72) % 16, b = blk / (72 * 16);
    int na0 = ntg * 32, nb0 = ntg * 32 + 16;
    const short* hb = h2t + (size_t)b * NN * 128;

    v4f ga = {0.f,0.f,0.f,0.f}, gb = ga, ta = ga, tb = ga;
#pragma unroll
    for (int kk = 0; kk < 4; ++kk) {
        v8s Ag = *(const v8s*)(wgb + (size_t)(ot * 16 + l15) * 128 + kk * 32 + 8 * g);
        v8s At = *(const v8s*)(wbtb + (size_t)(ot * 16 + l15) * 128 + kk * 32 + 8 * g);
        v8s Ba = *(const v8s*)(hb + (size_t)(na0 + l15) * 128 + kk * 32 + 8 * g);
        v8s Bb = *(const v8s*)(hb + (size_t)(nb0 + l15) * 128 + kk * 32 + 8 * g);
        ga = __builtin_amdgcn_mfma_f32_16x16x32_bf16(Ag, Ba, ga, 0, 0, 0);
        gb = __builtin_amdgcn_mfma_f32_16x16x32_bf16(Ag, Bb, gb, 0, 0, 0);
        ta = __builtin_amdgcn_mfma_f32_16x16x32_bf16(At, Ba, ta, 0, 0, 0);
        tb = __builtin_amdgcn_mfma_f32_16x16x32_bf16(At, Bb, tb, 0, 0, 0);
    }
    v4f bgv = *(const v4f*)&bg[ot * 16 + 4 * g];
    v4f bbv = *(const v4f*)&bbt[ot * 16 + 4 * g];
    size_t oa = ((size_t)b * NN + na0 + l15) * 256 + ot * 16 + 4 * g;
    size_t ob = ((size_t)b * NN + nb0 + l15) * 256 + ot * 16 + 4 * g;
    uint2 w;
    w.x = pk2(ga[0] + bgv[0], ga[1] + bgv[1]); w.y = pk2(ga[2] + bgv[2], ga[3] + bgv[3]);
    *(uint2*)&gtb[oa] = w;
    w.x = pk2(gb[0] + bgv[0], gb[1] + bgv[1]); w.y = pk2(gb[2] + bgv[2], gb[3] + bgv[3]);
    *(uint2*)&gtb[ob] = w;
    w.x = pk2(ta[0] + bbv[0], ta[1] + bbv[1]); w.y = pk2(ta[2] + bbv[2], ta[3] + bbv[3]);
    *(uint2*)&bttb[oa] = w;
    w.x = pk2(tb[0] + bbv[0], tb[1] + bbv[1]); w.y = pk2(tb[2] + bbv[2], tb[3] + bbv[3]);
    *(uint2*)&bttb[ob] = w;
}

// ---------------- qkv MFMA GEMM + modulation epilogue -> qb, kb, vraw bf16 ----------------
// Q scale includes log2(e) so attention can use raw exp2.
__global__ __launch_bounds__(64) void k_qkvm(const short* __restrict__ xt,
                                             const short* __restrict__ wqkvb,
                                             const float* __restrict__ bqkv,
                                             const short* __restrict__ gtb,
                                             const short* __restrict__ bttb,
                                             const float* __restrict__ invl,
                                             const float* __restrict__ alpha_p,
                                             short* __restrict__ qb, short* __restrict__ kb,
                                             short* __restrict__ vraw) {
    int lane = threadIdx.x, l15 = lane & 15, g = lane >> 4;
    int blk = blockIdx.x;
    int ntg = blk % 72, ot = (blk / 72) % 48, b = blk / (72 * 48);
    int na0 = ntg * 32, nb0 = ntg * 32 + 16;
    const short* xb = xt + (size_t)b * NN * 256;

    v4f acca = {0.f,0.f,0.f,0.f}, accb = acca;
#pragma unroll
    for (int kk = 0; kk < 8; ++kk) {
        v8s A = *(const v8s*)(wqkvb + (size_t)(ot * 16 + l15) * 256 + kk * 32 + 8 * g);
        v8s Ba = *(const v8s*)(xb + (size_t)(na0 + l15) * 256 + kk * 32 + 8 * g);
        v8s Bb = *(const v8s*)(xb + (size_t)(nb0 + l15) * 256 + kk * 32 + 8 * g);
        acca = __builtin_amdgcn_mfma_f32_16x16x32_bf16(A, Ba, acca, 0, 0, 0);
        accb = __builtin_amdgcn_mfma_f32_16x16x32_bf16(A, Bb, accb, 0, 0, 0);
    }
    int which = ot >> 4;
    int cbase = (ot & 15) * 16 + 4 * g;
    int h = cbase >> 5, dbase = cbase & 31;
    v4f bias = *(const v4f*)&bqkv[which * 256 + cbase];
    const float scale = 0.25503486f;     // 32^-0.5 * log2(e)
    float alpha = *alpha_p;
    short* dst = (which == 0) ? qb : (which == 1) ? kb : vraw;
#pragma unroll
    for (int t = 0; t < 2; ++t) {
        int n = (t == 0 ? na0 : nb0) + l15;
        v4f acc = (t == 0) ? acca : accb;
        uint2 gg = *(const uint2*)&gtb[((size_t)b * NN + n) * 256 + cbase];
        uint2 tt = *(const uint2*)&bttb[((size_t)b * NN + n) * 256 + cbase];
        float iv = (which == 0) ? alpha * invl[b * NN + n] : 0.f;
        float v0 = blo(gg.x) * (acc[0] + bias[0]) + blo(tt.x);
        float v1 = bhi(gg.x) * (acc[1] + bias[1]) + bhi(tt.x);
        float v2 = blo(gg.y) * (acc[2] + bias[2]) + blo(tt.y);
        float v3 = bhi(gg.y) * (acc[3] + bias[3]) + bhi(tt.y);
        if (which == 0) {
            v0 = (v0 + iv) * scale; v1 = (v1 + iv) * scale;
            v2 = (v2 + iv) * scale; v3 = (v3 + iv) * scale;
        }
        uint2 w;
        w.x = pk2(v0, v1);
        w.y = pk2(v2, v3);
        *(uint2*)&dst[(((size_t)b * NHEADS + h) * NN + n) * DH + dbase] = w;
    }
}

// ---------------- V transpose: vraw [bh][n][32] -> vtb blocked [bh][72][32d][32k] ----------------
__global__ void k_vt(const short* __restrict__ vraw, short* __restrict__ vtb) {
    __shared__ unsigned short lds[64 * 34];
    int bh = blockIdx.x / 36, nc = blockIdx.x % 36;
    int n0 = nc * 64;
    int dpair = threadIdx.x & 15, nsub = (threadIdx.x >> 4) & 15;
    const unsigned* vr2 = (const unsigned*)vraw;
#pragma unroll
    for (int i = 0; i < 4; ++i) {
        int ns = i * 16 + nsub;
        unsigned v = vr2[((size_t)bh * NN + n0 + ns) * 16 + dpair];
        *(unsigned*)&lds[ns * 34 + 2 * dpair] = v;
    }
    __syncthreads();
    int pn = threadIdx.x & 31, drow = threadIdx.x >> 5;
    int kb0 = n0 >> 5;
    unsigned* vtb2 = (unsigned*)vtb;
#pragma unroll
    for (int j = 0; j < 4; ++j) {
        int d = j * 8 + drow;
        unsigned lo = lds[(2 * pn) * 34 + d];
        unsigned hi = lds[(2 * pn + 1) * 34 + d];
        // tile (bh, kb0 + pn/16), row d, k pair = pn&15
        vtb2[(((size_t)bh * 72 + kb0 + (pn >> 4)) * 32 + d) * 16 + (pn & 15)] = lo | (hi << 16);
    }
}

// ---------------- V row-sums (blocked layout) ----------------
__global__ __launch_bounds__(256) void k_vsum(const short* __restrict__ vtb,
                                              float* __restrict__ vsum) {
    int bh = blockIdx.x;               // 16 blocks
    int d = threadIdx.x >> 3, sub = threadIdx.x & 7;
    const unsigned* base = (const unsigned*)(vtb + (size_t)bh * 72 * 32 * 32);
    float s = 0.f;
    for (int kb = 0; kb < 72; ++kb) {
        const unsigned* row = base + ((kb * 32 + d) * 32 + sub * 4) / 2;
        unsigned a = row[0], b2 = row[1];
        s += (blo(a) + bhi(a)) + (blo(b2) + bhi(b2));
    }
    s += __shfl_xor(s, 1); s += __shfl_xor(s, 2); s += __shfl_xor(s, 4);
    if (sub == 0) vsum[bh * DH + d] = s;
}

// ---------------- fused attention: 4 waves split K in-block, merge in LDS ----------------
// grid 1152 (XCD-swizzled), block 256.  p' = exp2(s2)-1, s2 pre-scaled by log2e.
// out = (vsum + sum_k p'*v) / (NN + sum_k p').
__global__ __launch_bounds__(256) void k_attn2(const short* __restrict__ qb,
                                               const short* __restrict__ kbuf,
                                               const short* __restrict__ vtb,
                                               const float* __restrict__ vsum,
                                               short* __restrict__ aotb) {
    __shared__ short plds[4][2][32 * 40];   // per-wave DOUBLE-BUFFERED P' tile (80B rows)
    __shared__ float acc_lds[4][32][36];    // per-wave partial O
    __shared__ float ps_lds[4][32];         // per-wave row-sums of p'
    int tid = threadIdx.x;
    int w = tid >> 6, lane = tid & 63;
    int l15 = lane & 15, g = lane >> 4;
    int blk = blockIdx.x;
    int logical = (blk & 7) * 144 + (blk >> 3);   // XCD swizzle: 1152 = 8*144
    int qt = logical % 72, bh = logical / 72;
    int qbase = qt * 32;

    const short* qp = qb + ((size_t)bh * NN + qbase) * DH;
    const short* kp = kbuf + ((size_t)bh * NN + w * KPW) * DH;
    const short* vp = vtb + ((size_t)bh * 72 + w * (KPW / 32)) * 1024;  // 32x32 tiles

    v8s q0 = *(const v8s*)(qp + l15 * DH + 8 * g);
    v8s q1 = *(const v8s*)(qp + (16 + l15) * DH + 8 * g);

    v4f acc00 = {0.f,0.f,0.f,0.f}, acc01 = acc00, acc10 = acc00, acc11 = acc00;
    float ps0 = 0.f, ps1 = 0.f;

    for (int it = 0; it < KPW / 32; ++it) {
        const short* kpi = kp + it * 32 * DH;
        v8s ka0 = *(const v8s*)(kpi + l15 * DH + 8 * g);
        v8s ka1 = *(const v8s*)(kpi + (16 + l15) * DH + 8 * g);
        v4f s00 = __builtin_amdgcn_mfma_f32_16x16x32_bf16(ka0, q0, (v4f){0.f,0.f,0.f,0.f}, 0, 0, 0);
        v4f s01 = __builtin_amdgcn_mfma_f32_16x16x32_bf16(ka0, q1, (v4f){0.f,0.f,0.f,0.f}, 0, 0, 0);
        v4f s10 = __builtin_amdgcn_mfma_f32_16x16x32_bf16(ka1, q0, (v4f){0.f,0.f,0.f,0.f}, 0, 0, 0);
        v4f s11 = __builtin_amdgcn_mfma_f32_16x16x32_bf16(ka1, q1, (v4f){0.f,0.f,0.f,0.f}, 0, 0, 0);

        short* pw = plds[w][it & 1];
        // p' = exp2(s)-1; row-sum; stash P'^T -> LDS as row-major P'[q][k] bf16
#define DOFRAG(S, QTL, KT, PS)                                                   \
        {                                                                        \
            float p0 = exp2f((S)[0]) - 1.f, p1 = exp2f((S)[1]) - 1.f;            \
            float p2 = exp2f((S)[2]) - 1.f, p3 = exp2f((S)[3]) - 1.f;            \
            PS += (p0 + p1) + (p2 + p3);                                         \
            uint2 wv;                                                            \
            wv.x = pk2(p0, p1);                                                  \
            wv.y = pk2(p2, p3);                                                  \
            *(uint2*)((char*)pw + ((QTL) * 16 + l15) * 80 + ((KT) * 16 + 4 * g) * 2) = wv; \
        }
        DOFRAG(s00, 0, 0, ps0)
        DOFRAG(s01, 1, 0, ps1)
        DOFRAG(s10, 0, 1, ps0)
        DOFRAG(s11, 1, 1, ps1)
#undef DOFRAG
        // per-wave private LDS slice, double-buffered: wave-ordered DS, no barrier
        v8s pa0 = *(v8s*)((char*)pw + l15 * 80 + 16 * g);
        v8s pa1 = *(v8s*)((char*)pw + (16 + l15) * 80 + 16 * g);
        const short* vpi = vp + it * 1024;
        v8s vb0 = *(const v8s*)(vpi + l15 * 32 + 8 * g);           // d-tile 0: 1KB contiguous
        v8s vb1 = *(const v8s*)(vpi + (16 + l15) * 32 + 8 * g);    // d-tile 1
        acc00 = __builtin_amdgcn_mfma_f32_16x16x32_bf16(pa0, vb0, acc00, 0, 0, 0);
        acc01 = __builtin_amdgcn_mfma_f32_16x16x32_bf16(pa0, vb1, acc01, 0, 0, 0);
        acc10 = __builtin_amdgcn_mfma_f32_16x16x32_bf16(pa1, vb0, acc10, 0, 0, 0);
        acc11 = __builtin_amdgcn_mfma_f32_16x16x32_bf16(pa1, vb1, acc11, 0, 0, 0);
    }

    // per-wave row-sum reduction across 4 lane-groups
    ps0 += __shfl_xor(ps0, 16); ps0 += __shfl_xor(ps0, 32);
    ps1 += __shfl_xor(ps1, 16); ps1 += __shfl_xor(ps1, 32);
    if (lane < 16) ps_lds[w][l15] = ps0;
    else if (lane < 32) ps_lds[w][16 + l15] = ps1;

#define DUMP(ACC, QTL, DT)                                                         \
    {                                                                              \
        _Pragma("unroll")                                                          \
        for (int r = 0; r < 4; ++r)                                                \
            acc_lds[w][(QTL) * 16 + 4 * g + r][(DT) * 16 + l15] = (ACC)[r];        \
    }
    DUMP(acc00, 0, 0)
    DUMP(acc01, 1, 0)
    DUMP(acc10, 0, 1)
    DUMP(acc11, 1, 1)
#undef DUMP
    __syncthreads();

    // cooperative merge: thread t -> q = t>>3 (32), d0 = (t&7)*4
    int q = tid >> 3, d0 = (tid & 7) * 4;
    float L = (float)NN;
    v4f a = {0.f, 0.f, 0.f, 0.f};
#pragma unroll
    for (int wv = 0; wv < 4; ++wv) {
        L += ps_lds[wv][q];
        v4f t4 = *(v4f*)&acc_lds[wv][q][d0];
        a[0] += t4[0]; a[1] += t4[1]; a[2] += t4[2]; a[3] += t4[3];
    }
    const float* vs = vsum + bh * DH + d0;
    float rl = 1.f / L;
    uint2 o;
    o.x = pk2((a[0] + vs[0]) * rl, (a[1] + vs[1]) * rl);
    o.y = pk2((a[2] + vs[2]) * rl, (a[3] + vs[3]) * rl);
    int b = bh >> 3, h = bh & 7;
    *(uint2*)&aotb[((size_t)b * NN + qbase + q) * 256 + h * DH + d0] = o;
}

// ---------------- output projection MFMA GEMM ----------------
__global__ __launch_bounds__(64) void k_projm(const short* __restrict__ aotb,
                                              const short* __restrict__ wprojb,
                                              const float* __restrict__ bproj,
                                              float* __restrict__ out) {
    int lane = threadIdx.x, l15 = lane & 15, g = lane >> 4;
    int blk = blockIdx.x;
    int ntg = blk % 72, ot = (blk / 72) % 16, b = blk / (72 * 16);
    int na0 = ntg * 32, nb0 = ntg * 32 + 16;
    const short* ab = aotb + (size_t)b * NN * 256;

    v4f acca = {0.f,0.f,0.f,0.f}, accb = acca;
#pragma unroll
    for (int kk = 0; kk < 8; ++kk) {
        v8s A = *(const v8s*)(wprojb + (size_t)(ot * 16 + l15) * 256 + kk * 32 + 8 * g);
        v8s Ba = *(const v8s*)(ab + (size_t)(na0 + l15) * 256 + kk * 32 + 8 * g);
        v8s Bb = *(const v8s*)(ab + (size_t)(nb0 + l15) * 256 + kk * 32 + 8 * g);
        acca = __builtin_amdgcn_mfma_f32_16x16x32_bf16(A, Ba, acca, 0, 0, 0);
        accb = __builtin_amdgcn_mfma_f32_16x16x32_bf16(A, Bb, accb, 0, 0, 0);
    }
    v4f bias = *(const v4f*)&bproj[ot * 16 + 4 * g];
#pragma unroll
    for (int r = 0; r < 4; ++r) {
        int o = ot * 16 + 4 * g + r;
        out[((size_t)b * 256 + o) * NN + na0 + l15] = acca[r] + bias[r];
        out[((size_t)b * 256 + o) * NN + nb0 + l15] = accb[r] + bias[r];
    }
}

extern "C" void kernel_launch(void* const* d_in, const int* in_sizes, int n_in,
                              void* d_out, int out_size, void* d_ws, size_t ws_size,
                              hipStream_t stream) {
    const float* x     = (const float*)d_in[0];
    const float* luma  = (const float*)d_in[1];
    const float* wqkv  = (const float*)d_in[2];
    const float* bqkv  = (const float*)d_in[3];
    const float* wproj = (const float*)d_in[4];
    const float* bproj = (const float*)d_in[5];
    const float* wc1   = (const float*)d_in[6];
    const float* bc1   = (const float*)d_in[7];
    const float* wc2   = (const float*)d_in[8];
    const float* bc2   = (const float*)d_in[9];
    const float* wg    = (const float*)d_in[10];
    const float* bg    = (const float*)d_in[11];
    const float* wbt   = (const float*)d_in[12];
    const float* bbt   = (const float*)d_in[13];
    const float* alpha = (const float*)d_in[14];
    float* out = (float*)d_out;

    float* ws = (float*)d_ws;
    size_t off = 0;
    float* twc1 = ws + off;            off += 9 * 128;
    short* tc2b = (short*)(ws + off);  off += 9 * 128 * 128 / 2;
    short* wqkvb = (short*)(ws + off); off += 768 * 256 / 2;
    short* wgb = (short*)(ws + off);   off += 256 * 128 / 2;
    short* wbtb = (short*)(ws + off);  off += 256 * 128 / 2;
    short* wprojb = (short*)(ws + off); off += 256 * 256 / 2;
    short* h1p = (short*)(ws + off);   off += NB * 2500 * 128 / 2;
    short* xt = (short*)(ws + off);    off += NB * NN * 256 / 2;
    short* h2t = (short*)(ws + off);   off += NB * NN * 128 / 2;
    short* gtb = (short*)(ws + off);   off += NB * NN * 256 / 2;
    short* bttb = (short*)(ws + off);  off += NB * NN * 256 / 2;
    float* invl = ws + off;            off += NB * NN;
    short* qbb = (short*)(ws + off);   off += 16 * NN * DH / 2;
    short* kbb = (short*)(ws + off);   off += 16 * NN * DH / 2;
    short* vraw = (short*)(ws + off);  off += 16 * NN * DH / 2;
    short* vtb = (short*)(ws + off);   off += 16 * NN * DH / 2;   // blocked [bh][72][32][32]
    float* vsum = ws + off;            off += 16 * DH;
    short* aotb = (short*)(ws + off);  off += NB * NN * 256 / 2;
    (void)ws_size; (void)in_sizes; (void)n_in; (void)out_size;

    k_prep<<<768, 256, 0, stream>>>(wc1, wc2, wqkv, wg, wbt, wproj,
                                    twc1, tc2b, wqkvb, wgb, wbtb, wprojb);
    k_conv1<<<NB * 1250, 256, 0, stream>>>(luma, twc1, bc1, h1p);
    k_xt<<<NB * 144 + NB, 256, 0, stream>>>(x, xt, luma, invl);
    k_conv2m<<<NB * 8 * 72, 64, 0, stream>>>(h1p, tc2b, bc2, h2t);
    k_gbm<<<NB * 16 * 72, 64, 0, stream>>>(h2t, wgb, wbtb, bg, bbt, gtb, bttb);
    k_qkvm<<<NB * 48 * 72, 64, 0, stream>>>(xt, wqkvb, bqkv, gtb, bttb, invl, alpha,
                                            qbb, kbb, vraw);
    k_vt<<<16 * 36, 256, 0, stream>>>(vraw, vtb);
    k_vsum<<<16, 256, 0, stream>>>(vtb, vsum);
    k_attn2<<<16 * 72, 256, 0, stream>>>(qbb, kbb, vtb, vsum, aotb);
    k_projm<<<NB * 16 * 72, 64, 0, stream>>>(aotb, wprojb, bproj, out);
}

// Round 8
// 113.646 us; speedup vs baseline: 4.5270x; 1.1429x over previous
//
#include <hip/hip_runtime.h>
#include <hip/hip_bf16.h>
#include <math.h>
#include <string.h>

#define NB 2
#define NN 2304        // 48*48
#define NHEADS 8
#define DH 32
#define KPW 576        // keys per wave in k_attn2 (NN/4)

typedef __attribute__((ext_vector_type(8))) short v8s;   // 8 bf16 in 4 VGPRs
typedef __attribute__((ext_vector_type(4))) float v4f;

__device__ inline unsigned short f2b(float f) {          // fp32 -> bf16 (RNE)
    unsigned u = __builtin_bit_cast(unsigned, f);
    unsigned r = u + 0x7FFFu + ((u >> 16) & 1u);
    return (unsigned short)(r >> 16);
}
__device__ inline float b2f(short s) {
    unsigned u = ((unsigned)(unsigned short)s) << 16;
    return __builtin_bit_cast(float, u);
}
__device__ inline unsigned pk2(float a, float b) {       // 2 fp32 -> packed bf16x2
    __hip_bfloat162 h = __float22bfloat162_rn(make_float2(a, b));
    unsigned r;
    memcpy(&r, &h, sizeof(r));
    return r;
}
__device__ inline float blo(unsigned u) { return __builtin_bit_cast(float, u << 16); }
__device__ inline float bhi(unsigned u) { return __builtin_bit_cast(float, u & 0xffff0000u); }

// ---------------- weight prep: transposes + bf16 conversion + vsum zero ----------------
__global__ void k_prep(const float* __restrict__ wc1, const float* __restrict__ wc2,
                       const float* __restrict__ wqkv, const float* __restrict__ wg,
                       const float* __restrict__ wbt, const float* __restrict__ wproj,
                       float* __restrict__ twc1, short* __restrict__ tc2b,
                       short* __restrict__ wqkvb, short* __restrict__ wgb,
                       short* __restrict__ wbtb, short* __restrict__ wprojb,
                       float* __restrict__ vsum) {
    int i = blockIdx.x * 256 + threadIdx.x;            // 196608 threads
    if (i < 16 * DH) vsum[i] = 0.f;                    // zero vsum accumulators
    if (i < 9 * 128) {                                 // twc1[k][c] = wc1[c][k]
        int k = i / 128, c = i % 128;
        twc1[i] = wc1[c * 9 + k];
    }
    if (i < 9 * 128 * 128) {                           // tc2b[s][o][ic] = wc2[o][ic][s]
        int s = i / (128 * 128);
        int rem = i % (128 * 128);
        int o = rem / 128, ic = rem % 128;
        tc2b[i] = (short)f2b(wc2[(o * 128 + ic) * 9 + s]);
    }
    if (i < 768 * 256) wqkvb[i] = (short)f2b(wqkv[i]);
    if (i < 256 * 128) { wgb[i] = (short)f2b(wg[i]); wbtb[i] = (short)f2b(wbt[i]); }
    if (i < 256 * 256) wprojb[i] = (short)f2b(wproj[i]);
}

// ---------------- conv1 -> h1p: padded(50x50) transposed [b][p][128] bf16 ----------------
__global__ void k_conv1(const float* __restrict__ luma, const float* __restrict__ twc1,
                        const float* __restrict__ bc1, short* __restrict__ h1p) {
    int c = threadIdx.x & 127;
    int p = (blockIdx.x % 1250) * 2 + (threadIdx.x >> 7);
    int b = blockIdx.x / 1250;
    int py = p / 50, px = p % 50;
    float val = 0.f;
    if (py >= 1 && py <= 48 && px >= 1 && px <= 48) {
        int y = py - 1, x = px - 1;
        const float* lb = luma + b * NN;
        float acc = bc1[c];
#pragma unroll
        for (int ky = 0; ky < 3; ++ky) {
            int yy = y + ky - 1;
            if (yy < 0 || yy >= 48) continue;
#pragma unroll
            for (int kx = 0; kx < 3; ++kx) {
                int xx = x + kx - 1;
                if (xx < 0 || xx >= 48) continue;
                acc += twc1[(ky * 3 + kx) * 128 + c] * lb[yy * 48 + xx];
            }
        }
        val = fmaxf(acc, 0.f);
    }
    h1p[((size_t)b * 2500 + p) * 128 + c] = (short)f2b(val);
}

// ---------------- x transpose (blocks 0..NB*144-1) + invL (last NB blocks) ----------------
__global__ void k_xt(const float* __restrict__ x, short* __restrict__ xt,
                     const float* __restrict__ luma, float* __restrict__ invl) {
    __shared__ unsigned short lds[64 * 66];            // [n][66] pad (xt path)
    __shared__ float red[256];                         // invl path
    int blk = blockIdx.x;
    if (blk >= NB * 144) {
        // ---- invL: avgpool3x3(1-luma) centered per batch ----
        int b = blk - NB * 144;
        const float* lb = luma + b * NN;
        float pooled[9];
        float local = 0.f;
#pragma unroll
        for (int it = 0; it < 9; ++it) {
            int n = it * 256 + threadIdx.x;
            int y = n / 48, xx0 = n % 48;
            float s = 0.f;
            for (int ky = 0; ky < 3; ++ky) {
                int yy = y + ky - 1;
                if (yy < 0 || yy >= 48) continue;
                for (int kx = 0; kx < 3; ++kx) {
                    int xx = xx0 + kx - 1;
                    if (xx < 0 || xx >= 48) continue;
                    s += 1.f - lb[yy * 48 + xx];
                }
            }
            s *= (1.f / 9.f);
            pooled[it] = s;
            local += s;
        }
        red[threadIdx.x] = local;
        __syncthreads();
        for (int off = 128; off > 0; off >>= 1) {
            if (threadIdx.x < off) red[threadIdx.x] += red[threadIdx.x + off];
            __syncthreads();
        }
        float mean = red[0] * (1.f / NN);
#pragma unroll
        for (int it = 0; it < 9; ++it) {
            int n = it * 256 + threadIdx.x;
            invl[b * NN + n] = pooled[it] - mean;
        }
        return;
    }
    // ---- x transpose: [b][256][2304] fp32 -> xt [b][2304][256] bf16 ----
    int nt = blk % 36, ct = (blk / 36) % 4, b = blk / 144;
    int n0 = nt * 64, c0 = ct * 64;
    int nc = threadIdx.x & 63, cr = threadIdx.x >> 6;
#pragma unroll
    for (int i = 0; i < 16; ++i) {
        int cs = i * 4 + cr;
        float v = x[((size_t)b * 256 + c0 + cs) * NN + n0 + nc];
        lds[nc * 66 + cs] = f2b(v);
    }
    __syncthreads();
    int cc = threadIdx.x & 31, nr = threadIdx.x >> 5;
    unsigned* xt2 = (unsigned*)xt;
#pragma unroll
    for (int j = 0; j < 8; ++j) {
        int ns = j * 8 + nr;
        unsigned w = *(unsigned*)&lds[ns * 66 + 2 * cc];
        xt2[(((size_t)b * NN + n0 + ns) * 256 + c0) / 2 + cc] = w;
    }
}

// ---------------- conv2 as 9-shift MFMA GEMM -> h2t [b][n][128] bf16 (bias+relu) ----------------
__global__ __launch_bounds__(64) void k_conv2m(const short* __restrict__ h1p,
                                               const short* __restrict__ tc2b,
                                               const float* __restrict__ bc2,
                                               short* __restrict__ h2t) {
    int lane = threadIdx.x, l15 = lane & 15, g = lane >> 4;
    int blk = blockIdx.x;
    int ntg = blk % 72, ot = (blk / 72) % 8, b = blk / (72 * 8);
    int nta = ntg * 2, ntb = ntg * 2 + 1;
    int ya = nta / 3, xa = (nta % 3) * 16;
    int yb = ntb / 3, xb = (ntb % 3) * 16;
    int p0a = (ya + 1) * 50 + xa + 1;
    int p0b = (yb + 1) * 50 + xb + 1;
    const short* hb = h1p + (size_t)b * 2500 * 128;

    v4f acca = {0.f,0.f,0.f,0.f}, accb = acca;
#pragma unroll
    for (int s = 0; s < 9; ++s) {
        int dp = (s / 3 - 1) * 50 + (s % 3 - 1);
#pragma unroll
        for (int kk = 0; kk < 4; ++kk) {
            v8s A = *(const v8s*)(tc2b + ((size_t)(s * 128 + ot * 16 + l15)) * 128 + kk * 32 + 8 * g);
            v8s Ba = *(const v8s*)(hb + (size_t)(p0a + dp + l15) * 128 + kk * 32 + 8 * g);
            v8s Bb = *(const v8s*)(hb + (size_t)(p0b + dp + l15) * 128 + kk * 32 + 8 * g);
            acca = __builtin_amdgcn_mfma_f32_16x16x32_bf16(A, Ba, acca, 0, 0, 0);
            accb = __builtin_amdgcn_mfma_f32_16x16x32_bf16(A, Bb, accb, 0, 0, 0);
        }
    }
    v4f bias = *(const v4f*)&bc2[ot * 16 + 4 * g];
    int na = ya * 48 + xa + l15, nb = yb * 48 + xb + l15;
    uint2 wa, wb;
    wa.x = pk2(fmaxf(acca[0] + bias[0], 0.f), fmaxf(acca[1] + bias[1], 0.f));
    wa.y = pk2(fmaxf(acca[2] + bias[2], 0.f), fmaxf(acca[3] + bias[3], 0.f));
    wb.x = pk2(fmaxf(accb[0] + bias[0], 0.f), fmaxf(accb[1] + bias[1], 0.f));
    wb.y = pk2(fmaxf(accb[2] + bias[2], 0.f), fmaxf(accb[3] + bias[3], 0.f));
    *(uint2*)&h2t[((size_t)b * NN + na) * 128 + ot * 16 + 4 * g] = wa;
    *(uint2*)&h2t[((size_t)b * NN + nb) * 128 + ot * 16 + 4 * g] = wb;
}

// ---------------- gamma/beta MFMA GEMMs -> gtb/bttb bf16 [b][n][256] ----------------
__global__ __launch_bounds__(64) void k_gbm(const short* __restrict__ h2t,
                                            const short* __restrict__ wgb,
                                            const short* __restrict__ wbtb,
                                            const float* __restrict__ bg,
                                            const float* __restrict__ bbt,
                                            short* __restrict__ gtb, short* __restrict__ bttb) {
    int lane = threadIdx.x, l15 = lane & 15, g = lane >> 4;
    int blk = blockIdx.x;
    int ntg = blk % 72, ot = (blk / 72) % 16, b = blk / (72 * 16);
    int na0 = ntg * 32, nb0 = ntg * 32 + 16;
    const short* hb = h2t + (size_t)b * NN * 128;

    v4f ga = {0.f,0.f,0.f,0.f}, gb = ga, ta = ga, tb = ga;
#pragma unroll
    for (int kk = 0; kk < 4; ++kk) {
        v8s Ag = *(const v8s*)(wgb + (size_t)(ot * 16 + l15) * 128 + kk * 32 + 8 * g);
        v8s At = *(const v8s*)(wbtb + (size_t)(ot * 16 + l15) * 128 + kk * 32 + 8 * g);
        v8s Ba = *(const v8s*)(hb + (size_t)(na0 + l15) * 128 + kk * 32 + 8 * g);
        v8s Bb = *(const v8s*)(hb + (size_t)(nb0 + l15) * 128 + kk * 32 + 8 * g);
        ga = __builtin_amdgcn_mfma_f32_16x16x32_bf16(Ag, Ba, ga, 0, 0, 0);
        gb = __builtin_amdgcn_mfma_f32_16x16x32_bf16(Ag, Bb, gb, 0, 0, 0);
        ta = __builtin_amdgcn_mfma_f32_16x16x32_bf16(At, Ba, ta, 0, 0, 0);
        tb = __builtin_amdgcn_mfma_f32_16x16x32_bf16(At, Bb, tb, 0, 0, 0);
    }
    v4f bgv = *(const v4f*)&bg[ot * 16 + 4 * g];
    v4f bbv = *(const v4f*)&bbt[ot * 16 + 4 * g];
    size_t oa = ((size_t)b * NN + na0 + l15) * 256 + ot * 16 + 4 * g;
    size_t ob = ((size_t)b * NN + nb0 + l15) * 256 + ot * 16 + 4 * g;
    uint2 w;
    w.x = pk2(ga[0] + bgv[0], ga[1] + bgv[1]); w.y = pk2(ga[2] + bgv[2], ga[3] + bgv[3]);
    *(uint2*)&gtb[oa] = w;
    w.x = pk2(gb[0] + bgv[0], gb[1] + bgv[1]); w.y = pk2(gb[2] + bgv[2], gb[3] + bgv[3]);
    *(uint2*)&gtb[ob] = w;
    w.x = pk2(ta[0] + bbv[0], ta[1] + bbv[1]); w.y = pk2(ta[2] + bbv[2], ta[3] + bbv[3]);
    *(uint2*)&bttb[oa] = w;
    w.x = pk2(tb[0] + bbv[0], tb[1] + bbv[1]); w.y = pk2(tb[2] + bbv[2], tb[3] + bbv[3]);
    *(uint2*)&bttb[ob] = w;
}

// ---------------- qkv MFMA GEMM + modulation epilogue -> qb, kb, vraw bf16 ----------------
// Q scale includes log2(e) so attention uses raw v_exp_f32.
__global__ __launch_bounds__(64) void k_qkvm(const short* __restrict__ xt,
                                             const short* __restrict__ wqkvb,
                                             const float* __restrict__ bqkv,
                                             const short* __restrict__ gtb,
                                             const short* __restrict__ bttb,
                                             const float* __restrict__ invl,
                                             const float* __restrict__ alpha_p,
                                             short* __restrict__ qb, short* __restrict__ kb,
                                             short* __restrict__ vraw) {
    int lane = threadIdx.x, l15 = lane & 15, g = lane >> 4;
    int blk = blockIdx.x;
    int ntg = blk % 72, ot = (blk / 72) % 48, b = blk / (72 * 48);
    int na0 = ntg * 32, nb0 = ntg * 32 + 16;
    const short* xb = xt + (size_t)b * NN * 256;

    v4f acca = {0.f,0.f,0.f,0.f}, accb = acca;
#pragma unroll
    for (int kk = 0; kk < 8; ++kk) {
        v8s A = *(const v8s*)(wqkvb + (size_t)(ot * 16 + l15) * 256 + kk * 32 + 8 * g);
        v8s Ba = *(const v8s*)(xb + (size_t)(na0 + l15) * 256 + kk * 32 + 8 * g);
        v8s Bb = *(const v8s*)(xb + (size_t)(nb0 + l15) * 256 + kk * 32 + 8 * g);
        acca = __builtin_amdgcn_mfma_f32_16x16x32_bf16(A, Ba, acca, 0, 0, 0);
        accb = __builtin_amdgcn_mfma_f32_16x16x32_bf16(A, Bb, accb, 0, 0, 0);
    }
    int which = ot >> 4;
    int cbase = (ot & 15) * 16 + 4 * g;
    int h = cbase >> 5, dbase = cbase & 31;
    v4f bias = *(const v4f*)&bqkv[which * 256 + cbase];
    const float scale = 0.25503486f;     // 32^-0.5 * log2(e)
    float alpha = *alpha_p;
    short* dst = (which == 0) ? qb : (which == 1) ? kb : vraw;
#pragma unroll
    for (int t = 0; t < 2; ++t) {
        int n = (t == 0 ? na0 : nb0) + l15;
        v4f acc = (t == 0) ? acca : accb;
        uint2 gg = *(const uint2*)&gtb[((size_t)b * NN + n) * 256 + cbase];
        uint2 tt = *(const uint2*)&bttb[((size_t)b * NN + n) * 256 + cbase];
        float iv = (which == 0) ? alpha * invl[b * NN + n] : 0.f;
        float v0 = blo(gg.x) * (acc[0] + bias[0]) + blo(tt.x);
        float v1 = bhi(gg.x) * (acc[1] + bias[1]) + bhi(tt.x);
        float v2 = blo(gg.y) * (acc[2] + bias[2]) + blo(tt.y);
        float v3 = bhi(gg.y) * (acc[3] + bias[3]) + bhi(tt.y);
        if (which == 0) {
            v0 = (v0 + iv) * scale; v1 = (v1 + iv) * scale;
            v2 = (v2 + iv) * scale; v3 = (v3 + iv) * scale;
        }
        uint2 w;
        w.x = pk2(v0, v1);
        w.y = pk2(v2, v3);
        *(uint2*)&dst[(((size_t)b * NHEADS + h) * NN + n) * DH + dbase] = w;
    }
}

// ---------------- V transpose -> vtb blocked [bh][72][32d][32k] + vsum atomics ----------------
__global__ void k_vt(const short* __restrict__ vraw, short* __restrict__ vtb,
                     float* __restrict__ vsum) {
    __shared__ unsigned short lds[64 * 34];
    int bh = blockIdx.x / 36, nc = blockIdx.x % 36;
    int n0 = nc * 64;
    int dpair = threadIdx.x & 15, nsub = (threadIdx.x >> 4) & 15;
    const unsigned* vr2 = (const unsigned*)vraw;
#pragma unroll
    for (int i = 0; i < 4; ++i) {
        int ns = i * 16 + nsub;
        unsigned v = vr2[((size_t)bh * NN + n0 + ns) * 16 + dpair];
        *(unsigned*)&lds[ns * 34 + 2 * dpair] = v;
    }
    __syncthreads();
    int pn = threadIdx.x & 31, drow = threadIdx.x >> 5;
    int kb0 = n0 >> 5;
    unsigned* vtb2 = (unsigned*)vtb;
#pragma unroll
    for (int j = 0; j < 4; ++j) {
        int d = j * 8 + drow;
        unsigned lo = lds[(2 * pn) * 34 + d];
        unsigned hi = lds[(2 * pn + 1) * 34 + d];
        vtb2[(((size_t)bh * 72 + kb0 + (pn >> 4)) * 32 + d) * 16 + (pn & 15)] = lo | (hi << 16);
    }
    // vsum partial: 32 threads, one per d, sum this block's 64 keys, atomic into global
    if (threadIdx.x < 32) {
        int d = threadIdx.x;
        float s = 0.f;
        for (int ns = 0; ns < 64; ++ns) s += b2f((short)lds[ns * 34 + d]);
        atomicAdd(&vsum[bh * DH + d], s);
    }
}

// ---------------- fused attention: 4 waves split K in-block, merge in LDS ----------------
// grid 1152 (XCD-swizzled), block 256.  p' = exp2(s)-1 (s pre-scaled by log2e).
// out = (vsum + sum_k p'*v) / (NN + sum_k p'); row-sums of p' via MFMA ones-trick.
__global__ __launch_bounds__(256) void k_attn2(const short* __restrict__ qb,
                                               const short* __restrict__ kbuf,
                                               const short* __restrict__ vtb,
                                               const float* __restrict__ vsum,
                                               short* __restrict__ aotb) {
    __shared__ short plds[4][32 * 40];      // per-wave P' tile, rows padded to 80 B
    __shared__ float acc_lds[4][32][36];    // per-wave partial O
    __shared__ float ps_lds[4][32];         // per-wave row-sums of p'
    int tid = threadIdx.x;
    int w = tid >> 6, lane = tid & 63;
    int l15 = lane & 15, g = lane >> 4;
    int blk = blockIdx.x;
    int logical = (blk & 7) * 144 + (blk >> 3);   // XCD swizzle: 1152 = 8*144
    int qt = logical % 72, bh = logical / 72;
    int qbase = qt * 32;

    const short* qp = qb + ((size_t)bh * NN + qbase) * DH;
    const short* kp = kbuf + ((size_t)bh * NN + w * KPW) * DH;
    const short* vp = vtb + ((size_t)bh * 72 + w * (KPW / 32)) * 1024;  // 32x32 tiles

    v8s q0 = *(const v8s*)(qp + l15 * DH + 8 * g);
    v8s q1 = *(const v8s*)(qp + (16 + l15) * DH + 8 * g);

    const short one_b = (short)0x3F80;      // bf16 1.0
    const v8s ones = {one_b, one_b, one_b, one_b, one_b, one_b, one_b, one_b};

    v4f acc00 = {0.f,0.f,0.f,0.f}, acc01 = acc00, acc10 = acc00, acc11 = acc00;
    v4f acc_ps0 = {0.f,0.f,0.f,0.f}, acc_ps1 = acc_ps0;
    short* pw = plds[w];

    for (int it = 0; it < KPW / 32; ++it) {
        const short* kpi = kp + it * 32 * DH;
        v8s ka0 = *(const v8s*)(kpi + l15 * DH + 8 * g);
        v8s ka1 = *(const v8s*)(kpi + (16 + l15) * DH + 8 * g);
        v4f s00 = __builtin_amdgcn_mfma_f32_16x16x32_bf16(ka0, q0, (v4f){0.f,0.f,0.f,0.f}, 0, 0, 0);
        v4f s01 = __builtin_amdgcn_mfma_f32_16x16x32_bf16(ka0, q1, (v4f){0.f,0.f,0.f,0.f}, 0, 0, 0);
        v4f s10 = __builtin_amdgcn_mfma_f32_16x16x32_bf16(ka1, q0, (v4f){0.f,0.f,0.f,0.f}, 0, 0, 0);
        v4f s11 = __builtin_amdgcn_mfma_f32_16x16x32_bf16(ka1, q1, (v4f){0.f,0.f,0.f,0.f}, 0, 0, 0);

        // p' = v_exp(s)-1; stash P'^T -> LDS as row-major P'[q][k] bf16 (no VALU row-sum)
#define DOFRAG(S, QTL, KT)                                                       \
        {                                                                        \
            float p0 = __builtin_amdgcn_exp2f((S)[0]) - 1.f;                     \
            float p1 = __builtin_amdgcn_exp2f((S)[1]) - 1.f;                     \
            float p2 = __builtin_amdgcn_exp2f((S)[2]) - 1.f;                     \
            float p3 = __builtin_amdgcn_exp2f((S)[3]) - 1.f;                     \
            uint2 wv;                                                            \
            wv.x = pk2(p0, p1);                                                  \
            wv.y = pk2(p2, p3);                                                  \
            *(uint2*)((char*)pw + ((QTL) * 16 + l15) * 80 + ((KT) * 16 + 4 * g) * 2) = wv; \
        }
        DOFRAG(s00, 0, 0)
        DOFRAG(s01, 1, 0)
        DOFRAG(s10, 0, 1)
        DOFRAG(s11, 1, 1)
#undef DOFRAG
        // per-wave private LDS slice: wave-ordered DS, no barrier needed
        v8s pa0 = *(v8s*)((char*)pw + l15 * 80 + 16 * g);
        v8s pa1 = *(v8s*)((char*)pw + (16 + l15) * 80 + 16 * g);
        const short* vpi = vp + it * 1024;
        v8s vb0 = *(const v8s*)(vpi + l15 * 32 + 8 * g);           // d-tile 0: contiguous
        v8s vb1 = *(const v8s*)(vpi + (16 + l15) * 32 + 8 * g);    // d-tile 1
        acc00 = __builtin_amdgcn_mfma_f32_16x16x32_bf16(pa0, vb0, acc00, 0, 0, 0);
        acc01 = __builtin_amdgcn_mfma_f32_16x16x32_bf16(pa0, vb1, acc01, 0, 0, 0);
        acc10 = __builtin_amdgcn_mfma_f32_16x16x32_bf16(pa1, vb0, acc10, 0, 0, 0);
        acc11 = __builtin_amdgcn_mfma_f32_16x16x32_bf16(pa1, vb1, acc11, 0, 0, 0);
        // row-sums of p' on the MFMA pipe: D[q][*] = sum_k P'[q][k]
        acc_ps0 = __builtin_amdgcn_mfma_f32_16x16x32_bf16(pa0, ones, acc_ps0, 0, 0, 0);
        acc_ps1 = __builtin_amdgcn_mfma_f32_16x16x32_bf16(pa1, ones, acc_ps1, 0, 0, 0);
    }

    // acc_ps[r] = rowsum(q = 4g+r), identical across l15 -> one lane-group writes
    if (l15 == 0) {
#pragma unroll
        for (int r = 0; r < 4; ++r) {
            ps_lds[w][4 * g + r] = acc_ps0[r];
            ps_lds[w][16 + 4 * g + r] = acc_ps1[r];
        }
    }

#define DUMP(ACC, QTL, DT)                                                         \
    {                                                                              \
        _Pragma("unroll")                                                          \
        for (int r = 0; r < 4; ++r)                                                \
            acc_lds[w][(QTL) * 16 + 4 * g + r][(DT) * 16 + l15] = (ACC)[r];        \
    }
    DUMP(acc00, 0, 0)
    DUMP(acc01, 1, 0)
    DUMP(acc10, 0, 1)
    DUMP(acc11, 1, 1)
#undef DUMP
    __syncthreads();

    // cooperative merge: thread t -> q = t>>3 (32), d0 = (t&7)*4
    int q = tid >> 3, d0 = (tid & 7) * 4;
    float L = (float)NN;
    v4f a = {0.f, 0.f, 0.f, 0.f};
#pragma unroll
    for (int wv = 0; wv < 4; ++wv) {
        L += ps_lds[wv][q];
        v4f t4 = *(v4f*)&acc_lds[wv][q][d0];
        a[0] += t4[0]; a[1] += t4[1]; a[2] += t4[2]; a[3] += t4[3];
    }
    const float* vs = vsum + bh * DH + d0;
    float rl = 1.f / L;
    uint2 o;
    o.x = pk2((a[0] + vs[0]) * rl, (a[1] + vs[1]) * rl);
    o.y = pk2((a[2] + vs[2]) * rl, (a[3] + vs[3]) * rl);
    int b = bh >> 3, h = bh & 7;
    *(uint2*)&aotb[((size_t)b * NN + qbase + q) * 256 + h * DH + d0] = o;
}

// ---------------- output projection MFMA GEMM ----------------
__global__ __launch_bounds__(64) void k_projm(const short* __restrict__ aotb,
                                              const short* __restrict__ wprojb,
                                              const float* __restrict__ bproj,
                                              float* __restrict__ out) {
    int lane = threadIdx.x, l15 = lane & 15, g = lane >> 4;
    int blk = blockIdx.x;
    int ntg = blk % 72, ot = (blk / 72) % 16, b = blk / (72 * 16);
    int na0 = ntg * 32, nb0 = ntg * 32 + 16;
    const short* ab = aotb + (size_t)b * NN * 256;

    v4f acca = {0.f,0.f,0.f,0.f}, accb = acca;
#pragma unroll
    for (int kk = 0; kk < 8; ++kk) {
        v8s A = *(const v8s*)(wprojb + (size_t)(ot * 16 + l15) * 256 + kk * 32 + 8 * g);
        v8s Ba = *(const v8s*)(ab + (size_t)(na0 + l15) * 256 + kk * 32 + 8 * g);
        v8s Bb = *(const v8s*)(ab + (size_t)(nb0 + l15) * 256 + kk * 32 + 8 * g);
        acca = __builtin_amdgcn_mfma_f32_16x16x32_bf16(A, Ba, acca, 0, 0, 0);
        accb = __builtin_amdgcn_mfma_f32_16x16x32_bf16(A, Bb, accb, 0, 0, 0);
    }
    v4f bias = *(const v4f*)&bproj[ot * 16 + 4 * g];
#pragma unroll
    for (int r = 0; r < 4; ++r) {
        int o = ot * 16 + 4 * g + r;
        out[((size_t)b * 256 + o) * NN + na0 + l15] = acca[r] + bias[r];
        out[((size_t)b * 256 + o) * NN + nb0 + l15] = accb[r] + bias[r];
    }
}

extern "C" void kernel_launch(void* const* d_in, const int* in_sizes, int n_in,
                              void* d_out, int out_size, void* d_ws, size_t ws_size,
                              hipStream_t stream) {
    const float* x     = (const float*)d_in[0];
    const float* luma  = (const float*)d_in[1];
    const float* wqkv  = (const float*)d_in[2];
    const float* bqkv  = (const float*)d_in[3];
    const float* wproj = (const float*)d_in[4];
    const float* bproj = (const float*)d_in[5];
    const float* wc1   = (const float*)d_in[6];
    const float* bc1   = (const float*)d_in[7];
    const float* wc2   = (const float*)d_in[8];
    const float* bc2   = (const float*)d_in[9];
    const float* wg    = (const float*)d_in[10];
    const float* bg    = (const float*)d_in[11];
    const float* wbt   = (const float*)d_in[12];
    const float* bbt   = (const float*)d_in[13];
    const float* alpha = (const float*)d_in[14];
    float* out = (float*)d_out;

    float* ws = (float*)d_ws;
    size_t off = 0;
    float* twc1 = ws + off;            off += 9 * 128;
    short* tc2b = (short*)(ws + off);  off += 9 * 128 * 128 / 2;
    short* wqkvb = (short*)(ws + off); off += 768 * 256 / 2;
    short* wgb = (short*)(ws + off);   off += 256 * 128 / 2;
    short* wbtb = (short*)(ws + off);  off += 256 * 128 / 2;
    short* wprojb = (short*)(ws + off); off += 256 * 256 / 2;
    short* h1p = (short*)(ws + off);   off += NB * 2500 * 128 / 2;
    short* xt = (short*)(ws + off);    off += NB * NN * 256 / 2;
    short* h2t = (short*)(ws + off);   off += NB * NN * 128 / 2;
    short* gtb = (short*)(ws + off);   off += NB * NN * 256 / 2;
    short* bttb = (short*)(ws + off);  off += NB * NN * 256 / 2;
    float* invl = ws + off;            off += NB * NN;
    short* qbb = (short*)(ws + off);   off += 16 * NN * DH / 2;
    short* kbb = (short*)(ws + off);   off += 16 * NN * DH / 2;
    short* vraw = (short*)(ws + off);  off += 16 * NN * DH / 2;
    short* vtb = (short*)(ws + off);   off += 16 * NN * DH / 2;   // blocked [bh][72][32][32]
    float* vsum = ws + off;            off += 16 * DH;
    short* aotb = (short*)(ws + off);  off += NB * NN * 256 / 2;
    (void)ws_size; (void)in_sizes; (void)n_in; (void)out_size;

    k_prep<<<768, 256, 0, stream>>>(wc1, wc2, wqkv, wg, wbt, wproj,
                                    twc1, tc2b, wqkvb, wgb, wbtb, wprojb, vsum);
    k_conv1<<<NB * 1250, 256, 0, stream>>>(luma, twc1, bc1, h1p);
    k_xt<<<NB * 144 + NB, 256, 0, stream>>>(x, xt, luma, invl);
    k_conv2m<<<NB * 8 * 72, 64, 0, stream>>>(h1p, tc2b, bc2, h2t);
    k_gbm<<<NB * 16 * 72, 64, 0, stream>>>(h2t, wgb, wbtb, bg, bbt, gtb, bttb);
    k_qkvm<<<NB * 48 * 72, 64, 0, stream>>>(xt, wqkvb, bqkv, gtb, bttb, invl, alpha,
                                            qbb, kbb, vraw);
    k_vt<<<16 * 36, 256, 0, stream>>>(vraw, vtb, vsum);
    k_attn2<<<16 * 72, 256, 0, stream>>>(qbb, kbb, vtb, vsum, aotb);
    k_projm<<<NB * 16 * 72, 64, 0, stream>>>(aotb, wprojb, bproj, out);
}

// Round 9
// 110.986 us; speedup vs baseline: 4.6355x; 1.0240x over previous
//
#include <hip/hip_runtime.h>
#include <hip/hip_bf16.h>
#include <math.h>
#include <string.h>

#define NB 2
#define NN 2304        // 48*48
#define NHEADS 8
#define DH 32
#define KPW 576        // keys per wave in k_attn2 (NN/4)

typedef __attribute__((ext_vector_type(8))) short v8s;   // 8 bf16 in 4 VGPRs
typedef __attribute__((ext_vector_type(4))) float v4f;

__device__ inline unsigned short f2b(float f) {          // fp32 -> bf16 (RNE)
    unsigned u = __builtin_bit_cast(unsigned, f);
    unsigned r = u + 0x7FFFu + ((u >> 16) & 1u);
    return (unsigned short)(r >> 16);
}
__device__ inline float b2f(short s) {
    unsigned u = ((unsigned)(unsigned short)s) << 16;
    return __builtin_bit_cast(float, u);
}
__device__ inline unsigned pk2(float a, float b) {       // 2 fp32 -> packed bf16x2
    __hip_bfloat162 h = __float22bfloat162_rn(make_float2(a, b));
    unsigned r;
    memcpy(&r, &h, sizeof(r));
    return r;
}
__device__ inline float blo(unsigned u) { return __builtin_bit_cast(float, u << 16); }
__device__ inline float bhi(unsigned u) { return __builtin_bit_cast(float, u & 0xffff0000u); }

// ---------------- weight prep: transposes + bf16 conversion + vsum zero ----------------
__global__ void k_prep(const float* __restrict__ wc1, const float* __restrict__ wc2,
                       const float* __restrict__ wqkv, const float* __restrict__ wg,
                       const float* __restrict__ wbt, const float* __restrict__ wproj,
                       float* __restrict__ twc1, short* __restrict__ tc2b,
                       short* __restrict__ wqkvb, short* __restrict__ wgb,
                       short* __restrict__ wbtb, short* __restrict__ wprojb,
                       float* __restrict__ vsum) {
    int i = blockIdx.x * 256 + threadIdx.x;            // 196608 threads
    if (i < 16 * DH) vsum[i] = 0.f;
    if (i < 9 * 128) {                                 // twc1[k][c] = wc1[c][k]
        int k = i / 128, c = i % 128;
        twc1[i] = wc1[c * 9 + k];
    }
    if (i < 9 * 128 * 128) {                           // tc2b[s][o][ic] = wc2[o][ic][s]
        int s = i / (128 * 128);
        int rem = i % (128 * 128);
        int o = rem / 128, ic = rem % 128;
        tc2b[i] = (short)f2b(wc2[(o * 128 + ic) * 9 + s]);
    }
    if (i < 768 * 256) wqkvb[i] = (short)f2b(wqkv[i]);
    if (i < 256 * 128) { wgb[i] = (short)f2b(wg[i]); wbtb[i] = (short)f2b(wbt[i]); }
    if (i < 256 * 256) wprojb[i] = (short)f2b(wproj[i]);
}

// ---------------- fused: x transpose | invL | conv1 ----------------
// blocks [0, NB*144): xt ; [NB*144, NB*144+NB): invl ; rest: conv1
__global__ void k_front(const float* __restrict__ x, short* __restrict__ xt,
                        const float* __restrict__ luma, float* __restrict__ invl,
                        const float* __restrict__ twc1, const float* __restrict__ bc1,
                        short* __restrict__ h1p) {
    __shared__ unsigned short lds[64 * 66];
    __shared__ float red[256];
    int blk = blockIdx.x;
    if (blk >= NB * 144 + NB) {
        // ---- conv1 -> h1p padded(50x50) transposed [b][p][128] bf16 ----
        int cb = blk - (NB * 144 + NB);
        int c = threadIdx.x & 127;
        int p = (cb % 1250) * 2 + (threadIdx.x >> 7);
        int b = cb / 1250;
        int py = p / 50, px = p % 50;
        float val = 0.f;
        if (py >= 1 && py <= 48 && px >= 1 && px <= 48) {
            int y = py - 1, xx0 = px - 1;
            const float* lb = luma + b * NN;
            float acc = bc1[c];
#pragma unroll
            for (int ky = 0; ky < 3; ++ky) {
                int yy = y + ky - 1;
                if (yy < 0 || yy >= 48) continue;
#pragma unroll
                for (int kx = 0; kx < 3; ++kx) {
                    int xx = xx0 + kx - 1;
                    if (xx < 0 || xx >= 48) continue;
                    acc += twc1[(ky * 3 + kx) * 128 + c] * lb[yy * 48 + xx];
                }
            }
            val = fmaxf(acc, 0.f);
        }
        h1p[((size_t)b * 2500 + p) * 128 + c] = (short)f2b(val);
        return;
    }
    if (blk >= NB * 144) {
        // ---- invL: avgpool3x3(1-luma) centered per batch ----
        int b = blk - NB * 144;
        const float* lb = luma + b * NN;
        float pooled[9];
        float local = 0.f;
#pragma unroll
        for (int it = 0; it < 9; ++it) {
            int n = it * 256 + threadIdx.x;
            int y = n / 48, xx0 = n % 48;
            float s = 0.f;
            for (int ky = 0; ky < 3; ++ky) {
                int yy = y + ky - 1;
                if (yy < 0 || yy >= 48) continue;
                for (int kx = 0; kx < 3; ++kx) {
                    int xx = xx0 + kx - 1;
                    if (xx < 0 || xx >= 48) continue;
                    s += 1.f - lb[yy * 48 + xx];
                }
            }
            s *= (1.f / 9.f);
            pooled[it] = s;
            local += s;
        }
        red[threadIdx.x] = local;
        __syncthreads();
        for (int off = 128; off > 0; off >>= 1) {
            if (threadIdx.x < off) red[threadIdx.x] += red[threadIdx.x + off];
            __syncthreads();
        }
        float mean = red[0] * (1.f / NN);
#pragma unroll
        for (int it = 0; it < 9; ++it) {
            int n = it * 256 + threadIdx.x;
            invl[b * NN + n] = pooled[it] - mean;
        }
        return;
    }
    // ---- x transpose: [b][256][2304] fp32 -> xt [b][2304][256] bf16 ----
    int nt = blk % 36, ct = (blk / 36) % 4, b = blk / 144;
    int n0 = nt * 64, c0 = ct * 64;
    int nc = threadIdx.x & 63, cr = threadIdx.x >> 6;
#pragma unroll
    for (int i = 0; i < 16; ++i) {
        int cs = i * 4 + cr;
        float v = x[((size_t)b * 256 + c0 + cs) * NN + n0 + nc];
        lds[nc * 66 + cs] = f2b(v);
    }
    __syncthreads();
    int cc = threadIdx.x & 31, nr = threadIdx.x >> 5;
    unsigned* xt2 = (unsigned*)xt;
#pragma unroll
    for (int j = 0; j < 8; ++j) {
        int ns = j * 8 + nr;
        unsigned w = *(unsigned*)&lds[ns * 66 + 2 * cc];
        xt2[(((size_t)b * NN + n0 + ns) * 256 + c0) / 2 + cc] = w;
    }
}

// ---------------- conv2 as 9-shift MFMA GEMM, 4 n-tiles/block ----------------
// grid: NB * 8ot * 36ntg, 1 wave
__global__ __launch_bounds__(64) void k_conv2m(const short* __restrict__ h1p,
                                               const short* __restrict__ tc2b,
                                               const float* __restrict__ bc2,
                                               short* __restrict__ h2t) {
    int lane = threadIdx.x, l15 = lane & 15, g = lane >> 4;
    int blk = blockIdx.x;
    int ntg = blk % 36, ot = (blk / 36) % 8, b = blk / (36 * 8);
    int p0[4], na[4];
#pragma unroll
    for (int j = 0; j < 4; ++j) {
        int nt = ntg * 4 + j;
        int y = nt / 3, xx = (nt % 3) * 16;
        p0[j] = (y + 1) * 50 + xx + 1;
        na[j] = y * 48 + xx + l15;
    }
    const short* hb = h1p + (size_t)b * 2500 * 128;

    v4f acc[4] = {{0.f,0.f,0.f,0.f},{0.f,0.f,0.f,0.f},{0.f,0.f,0.f,0.f},{0.f,0.f,0.f,0.f}};
#pragma unroll
    for (int s = 0; s < 9; ++s) {
        int dp = (s / 3 - 1) * 50 + (s % 3 - 1);
#pragma unroll
        for (int kk = 0; kk < 4; ++kk) {
            v8s A = *(const v8s*)(tc2b + ((size_t)(s * 128 + ot * 16 + l15)) * 128 + kk * 32 + 8 * g);
#pragma unroll
            for (int j = 0; j < 4; ++j) {
                v8s B = *(const v8s*)(hb + (size_t)(p0[j] + dp + l15) * 128 + kk * 32 + 8 * g);
                acc[j] = __builtin_amdgcn_mfma_f32_16x16x32_bf16(A, B, acc[j], 0, 0, 0);
            }
        }
    }
    v4f bias = *(const v4f*)&bc2[ot * 16 + 4 * g];
#pragma unroll
    for (int j = 0; j < 4; ++j) {
        uint2 w;
        w.x = pk2(fmaxf(acc[j][0] + bias[0], 0.f), fmaxf(acc[j][1] + bias[1], 0.f));
        w.y = pk2(fmaxf(acc[j][2] + bias[2], 0.f), fmaxf(acc[j][3] + bias[3], 0.f));
        *(uint2*)&h2t[((size_t)b * NN + na[j]) * 128 + ot * 16 + 4 * g] = w;
    }
}

// ---------------- gamma/beta MFMA GEMMs, 64 n/block -> gtb/bttb bf16 [b][n][256] ----------------
__global__ __launch_bounds__(64) void k_gbm(const short* __restrict__ h2t,
                                            const short* __restrict__ wgb,
                                            const short* __restrict__ wbtb,
                                            const float* __restrict__ bg,
                                            const float* __restrict__ bbt,
                                            short* __restrict__ gtb, short* __restrict__ bttb) {
    int lane = threadIdx.x, l15 = lane & 15, g = lane >> 4;
    int blk = blockIdx.x;
    int ntg = blk % 36, ot = (blk / 36) % 16, b = blk / (36 * 16);
    int n0 = ntg * 64;
    const short* hb = h2t + (size_t)b * NN * 128;

    v4f ga[4] = {{0.f,0.f,0.f,0.f},{0.f,0.f,0.f,0.f},{0.f,0.f,0.f,0.f},{0.f,0.f,0.f,0.f}};
    v4f ta[4] = {{0.f,0.f,0.f,0.f},{0.f,0.f,0.f,0.f},{0.f,0.f,0.f,0.f},{0.f,0.f,0.f,0.f}};
#pragma unroll
    for (int kk = 0; kk < 4; ++kk) {
        v8s Ag = *(const v8s*)(wgb + (size_t)(ot * 16 + l15) * 128 + kk * 32 + 8 * g);
        v8s At = *(const v8s*)(wbtb + (size_t)(ot * 16 + l15) * 128 + kk * 32 + 8 * g);
#pragma unroll
        for (int j = 0; j < 4; ++j) {
            v8s B = *(const v8s*)(hb + (size_t)(n0 + j * 16 + l15) * 128 + kk * 32 + 8 * g);
            ga[j] = __builtin_amdgcn_mfma_f32_16x16x32_bf16(Ag, B, ga[j], 0, 0, 0);
            ta[j] = __builtin_amdgcn_mfma_f32_16x16x32_bf16(At, B, ta[j], 0, 0, 0);
        }
    }
    v4f bgv = *(const v4f*)&bg[ot * 16 + 4 * g];
    v4f bbv = *(const v4f*)&bbt[ot * 16 + 4 * g];
#pragma unroll
    for (int j = 0; j < 4; ++j) {
        size_t o = ((size_t)b * NN + n0 + j * 16 + l15) * 256 + ot * 16 + 4 * g;
        uint2 w;
        w.x = pk2(ga[j][0] + bgv[0], ga[j][1] + bgv[1]);
        w.y = pk2(ga[j][2] + bgv[2], ga[j][3] + bgv[3]);
        *(uint2*)&gtb[o] = w;
        w.x = pk2(ta[j][0] + bbv[0], ta[j][1] + bbv[1]);
        w.y = pk2(ta[j][2] + bbv[2], ta[j][3] + bbv[3]);
        *(uint2*)&bttb[o] = w;
    }
}

// ---------------- qkv MFMA GEMM, 32oc x 64n/block + modulation epilogue ----------------
// Q scale includes log2(e) so attention uses raw v_exp_f32.
__global__ __launch_bounds__(64) void k_qkvm(const short* __restrict__ xt,
                                             const short* __restrict__ wqkvb,
                                             const float* __restrict__ bqkv,
                                             const short* __restrict__ gtb,
                                             const short* __restrict__ bttb,
                                             const float* __restrict__ invl,
                                             const float* __restrict__ alpha_p,
                                             short* __restrict__ qb, short* __restrict__ kb,
                                             short* __restrict__ vraw) {
    int lane = threadIdx.x, l15 = lane & 15, g = lane >> 4;
    int blk = blockIdx.x;
    int ntg = blk % 36, otg = (blk / 36) % 24, b = blk / (36 * 24);
    int n0 = ntg * 64;
    const short* xb = xt + (size_t)b * NN * 256;

    v4f acc[2][4];
#pragma unroll
    for (int oa = 0; oa < 2; ++oa)
#pragma unroll
        for (int j = 0; j < 4; ++j) acc[oa][j] = (v4f){0.f, 0.f, 0.f, 0.f};
#pragma unroll
    for (int kk = 0; kk < 8; ++kk) {
        v8s A0 = *(const v8s*)(wqkvb + (size_t)(otg * 32 + l15) * 256 + kk * 32 + 8 * g);
        v8s A1 = *(const v8s*)(wqkvb + (size_t)(otg * 32 + 16 + l15) * 256 + kk * 32 + 8 * g);
#pragma unroll
        for (int j = 0; j < 4; ++j) {
            v8s B = *(const v8s*)(xb + (size_t)(n0 + j * 16 + l15) * 256 + kk * 32 + 8 * g);
            acc[0][j] = __builtin_amdgcn_mfma_f32_16x16x32_bf16(A0, B, acc[0][j], 0, 0, 0);
            acc[1][j] = __builtin_amdgcn_mfma_f32_16x16x32_bf16(A1, B, acc[1][j], 0, 0, 0);
        }
    }
    const float scale = 0.25503486f;     // 32^-0.5 * log2(e)
    float alpha = *alpha_p;
#pragma unroll
    for (int oa = 0; oa < 2; ++oa) {
        int ocb = otg * 32 + oa * 16;
        int which = ocb >> 8;
        int cbase = (ocb & 255) + 4 * g;
        int h = cbase >> 5, dbase = cbase & 31;
        v4f bias = *(const v4f*)&bqkv[ocb + 4 * g];
        short* dst = (which == 0) ? qb : (which == 1) ? kb : vraw;
#pragma unroll
        for (int j = 0; j < 4; ++j) {
            int n = n0 + j * 16 + l15;
            v4f a = acc[oa][j];
            uint2 gg = *(const uint2*)&gtb[((size_t)b * NN + n) * 256 + cbase];
            uint2 tt = *(const uint2*)&bttb[((size_t)b * NN + n) * 256 + cbase];
            float iv = (which == 0) ? alpha * invl[b * NN + n] : 0.f;
            float v0 = blo(gg.x) * (a[0] + bias[0]) + blo(tt.x);
            float v1 = bhi(gg.x) * (a[1] + bias[1]) + bhi(tt.x);
            float v2 = blo(gg.y) * (a[2] + bias[2]) + blo(tt.y);
            float v3 = bhi(gg.y) * (a[3] + bias[3]) + bhi(tt.y);
            if (which == 0) {
                v0 = (v0 + iv) * scale; v1 = (v1 + iv) * scale;
                v2 = (v2 + iv) * scale; v3 = (v3 + iv) * scale;
            }
            uint2 w;
            w.x = pk2(v0, v1);
            w.y = pk2(v2, v3);
            *(uint2*)&dst[(((size_t)b * NHEADS + h) * NN + n) * DH + dbase] = w;
        }
    }
}

// ---------------- V transpose -> vtb blocked [bh][72][32d][32k] + vsum atomics ----------------
__global__ void k_vt(const short* __restrict__ vraw, short* __restrict__ vtb,
                     float* __restrict__ vsum) {
    __shared__ unsigned short lds[64 * 34];
    int bh = blockIdx.x / 36, nc = blockIdx.x % 36;
    int n0 = nc * 64;
    int dpair = threadIdx.x & 15, nsub = (threadIdx.x >> 4) & 15;
    const unsigned* vr2 = (const unsigned*)vraw;
#pragma unroll
    for (int i = 0; i < 4; ++i) {
        int ns = i * 16 + nsub;
        unsigned v = vr2[((size_t)bh * NN + n0 + ns) * 16 + dpair];
        *(unsigned*)&lds[ns * 34 + 2 * dpair] = v;
    }
    __syncthreads();
    int pn = threadIdx.x & 31, drow = threadIdx.x >> 5;
    int kb0 = n0 >> 5;
    unsigned* vtb2 = (unsigned*)vtb;
#pragma unroll
    for (int j = 0; j < 4; ++j) {
        int d = j * 8 + drow;
        unsigned lo = lds[(2 * pn) * 34 + d];
        unsigned hi = lds[(2 * pn + 1) * 34 + d];
        vtb2[(((size_t)bh * 72 + kb0 + (pn >> 4)) * 32 + d) * 16 + (pn & 15)] = lo | (hi << 16);
    }
    if (threadIdx.x < 32) {
        int d = threadIdx.x;
        float s = 0.f;
        for (int ns = 0; ns < 64; ++ns) s += b2f((short)lds[ns * 34 + d]);
        atomicAdd(&vsum[bh * DH + d], s);
    }
}

// ---------------- fused attention: QBLK=64, 4 waves split K, merge in LDS ----------------
// grid 576 (XCD-swizzled), block 256.  p' = exp2(s)-1 (s pre-scaled by log2e).
// out = (vsum + sum_k p'*v) / (NN + sum_k p'); row-sums via MFMA ones-trick.
__global__ __launch_bounds__(256) void k_attn2(const short* __restrict__ qb,
                                               const short* __restrict__ kbuf,
                                               const short* __restrict__ vtb,
                                               const float* __restrict__ vsum,
                                               short* __restrict__ aotb) {
    __shared__ short plds[4][64 * 40];      // per-wave P' tile, 64 rows x 80 B
    __shared__ float acc_lds[4][64][35];    // per-wave partial O, pad 35
    __shared__ float ps_lds[4][64];         // per-wave row-sums of p'
    int tid = threadIdx.x;
    int w = tid >> 6, lane = tid & 63;
    int l15 = lane & 15, g = lane >> 4;
    int blk = blockIdx.x;
    int logical = (blk & 7) * 72 + (blk >> 3);   // XCD swizzle: 576 = 8*72
    int qt = logical % 36, bh = logical / 36;
    int qbase = qt * 64;

    const short* qp = qb + ((size_t)bh * NN + qbase) * DH;
    const short* kp = kbuf + ((size_t)bh * NN + w * KPW) * DH;
    const short* vp = vtb + ((size_t)bh * 72 + w * (KPW / 32)) * 1024;  // 32x32 tiles

    v8s q0 = *(const v8s*)(qp + l15 * DH + 8 * g);
    v8s q1 = *(const v8s*)(qp + (16 + l15) * DH + 8 * g);
    v8s q2 = *(const v8s*)(qp + (32 + l15) * DH + 8 * g);
    v8s q3 = *(const v8s*)(qp + (48 + l15) * DH + 8 * g);

    const short one_b = (short)0x3F80;      // bf16 1.0
    const v8s ones = {one_b, one_b, one_b, one_b, one_b, one_b, one_b, one_b};

    v4f acc[2][4];                          // [d-tile][q-frag]
#pragma unroll
    for (int dt = 0; dt < 2; ++dt)
#pragma unroll
        for (int qf = 0; qf < 4; ++qf) acc[dt][qf] = (v4f){0.f, 0.f, 0.f, 0.f};
    v4f ps[4] = {{0.f,0.f,0.f,0.f},{0.f,0.f,0.f,0.f},{0.f,0.f,0.f,0.f},{0.f,0.f,0.f,0.f}};
    short* pw = plds[w];

    for (int it = 0; it < KPW / 32; ++it) {
        const short* kpi = kp + it * 32 * DH;
        v8s ka0 = *(const v8s*)(kpi + l15 * DH + 8 * g);
        v8s ka1 = *(const v8s*)(kpi + (16 + l15) * DH + 8 * g);
        v4f s00 = __builtin_amdgcn_mfma_f32_16x16x32_bf16(ka0, q0, (v4f){0.f,0.f,0.f,0.f}, 0, 0, 0);
        v4f s01 = __builtin_amdgcn_mfma_f32_16x16x32_bf16(ka0, q1, (v4f){0.f,0.f,0.f,0.f}, 0, 0, 0);
        v4f s02 = __builtin_amdgcn_mfma_f32_16x16x32_bf16(ka0, q2, (v4f){0.f,0.f,0.f,0.f}, 0, 0, 0);
        v4f s03 = __builtin_amdgcn_mfma_f32_16x16x32_bf16(ka0, q3, (v4f){0.f,0.f,0.f,0.f}, 0, 0, 0);
        v4f s10 = __builtin_amdgcn_mfma_f32_16x16x32_bf16(ka1, q0, (v4f){0.f,0.f,0.f,0.f}, 0, 0, 0);
        v4f s11 = __builtin_amdgcn_mfma_f32_16x16x32_bf16(ka1, q1, (v4f){0.f,0.f,0.f,0.f}, 0, 0, 0);
        v4f s12 = __builtin_amdgcn_mfma_f32_16x16x32_bf16(ka1, q2, (v4f){0.f,0.f,0.f,0.f}, 0, 0, 0);
        v4f s13 = __builtin_amdgcn_mfma_f32_16x16x32_bf16(ka1, q3, (v4f){0.f,0.f,0.f,0.f}, 0, 0, 0);

        // p' = v_exp(s)-1; stash P'^T -> LDS as row-major P'[q][k] bf16
#define DOFRAG(S, QF, KT)                                                        \
        {                                                                        \
            float p0 = __builtin_amdgcn_exp2f((S)[0]) - 1.f;                     \
            float p1 = __builtin_amdgcn_exp2f((S)[1]) - 1.f;                     \
            float p2 = __builtin_amdgcn_exp2f((S)[2]) - 1.f;                     \
            float p3 = __builtin_amdgcn_exp2f((S)[3]) - 1.f;                     \
            uint2 wv;                                                            \
            wv.x = pk2(p0, p1);                                                  \
            wv.y = pk2(p2, p3);                                                  \
            *(uint2*)((char*)pw + ((QF) * 16 + l15) * 80 + ((KT) * 16 + 4 * g) * 2) = wv; \
        }
        DOFRAG(s00, 0, 0)
        DOFRAG(s01, 1, 0)
        DOFRAG(s02, 2, 0)
        DOFRAG(s03, 3, 0)
        DOFRAG(s10, 0, 1)
        DOFRAG(s11, 1, 1)
        DOFRAG(s12, 2, 1)
        DOFRAG(s13, 3, 1)
#undef DOFRAG
        // per-wave private LDS slice: wave-ordered DS, no barrier needed
        v8s pa0 = *(v8s*)((char*)pw + l15 * 80 + 16 * g);
        v8s pa1 = *(v8s*)((char*)pw + (16 + l15) * 80 + 16 * g);
        v8s pa2 = *(v8s*)((char*)pw + (32 + l15) * 80 + 16 * g);
        v8s pa3 = *(v8s*)((char*)pw + (48 + l15) * 80 + 16 * g);
        const short* vpi = vp + it * 1024;
        v8s vb0 = *(const v8s*)(vpi + l15 * 32 + 8 * g);
        v8s vb1 = *(const v8s*)(vpi + (16 + l15) * 32 + 8 * g);
        __builtin_amdgcn_s_setprio(1);
        acc[0][0] = __builtin_amdgcn_mfma_f32_16x16x32_bf16(pa0, vb0, acc[0][0], 0, 0, 0);
        acc[1][0] = __builtin_amdgcn_mfma_f32_16x16x32_bf16(pa0, vb1, acc[1][0], 0, 0, 0);
        acc[0][1] = __builtin_amdgcn_mfma_f32_16x16x32_bf16(pa1, vb0, acc[0][1], 0, 0, 0);
        acc[1][1] = __builtin_amdgcn_mfma_f32_16x16x32_bf16(pa1, vb1, acc[1][1], 0, 0, 0);
        acc[0][2] = __builtin_amdgcn_mfma_f32_16x16x32_bf16(pa2, vb0, acc[0][2], 0, 0, 0);
        acc[1][2] = __builtin_amdgcn_mfma_f32_16x16x32_bf16(pa2, vb1, acc[1][2], 0, 0, 0);
        acc[0][3] = __builtin_amdgcn_mfma_f32_16x16x32_bf16(pa3, vb0, acc[0][3], 0, 0, 0);
        acc[1][3] = __builtin_amdgcn_mfma_f32_16x16x32_bf16(pa3, vb1, acc[1][3], 0, 0, 0);
        ps[0] = __builtin_amdgcn_mfma_f32_16x16x32_bf16(pa0, ones, ps[0], 0, 0, 0);
        ps[1] = __builtin_amdgcn_mfma_f32_16x16x32_bf16(pa1, ones, ps[1], 0, 0, 0);
        ps[2] = __builtin_amdgcn_mfma_f32_16x16x32_bf16(pa2, ones, ps[2], 0, 0, 0);
        ps[3] = __builtin_amdgcn_mfma_f32_16x16x32_bf16(pa3, ones, ps[3], 0, 0, 0);
        __builtin_amdgcn_s_setprio(0);
    }

    // ps[qf][r] = rowsum(q = qf*16 + 4g + r), identical across l15
    if (l15 == 0) {
#pragma unroll
        for (int qf = 0; qf < 4; ++qf)
#pragma unroll
            for (int r = 0; r < 4; ++r)
                ps_lds[w][qf * 16 + 4 * g + r] = ps[qf][r];
    }
#pragma unroll
    for (int qf = 0; qf < 4; ++qf)
#pragma unroll
        for (int dt = 0; dt < 2; ++dt)
#pragma unroll
            for (int r = 0; r < 4; ++r)
                acc_lds[w][qf * 16 + 4 * g + r][dt * 16 + l15] = acc[dt][qf][r];
    __syncthreads();

    // cooperative merge: thread t -> q = t>>2 (64), d0 = (t&3)*8 (8 d's)
    int q = tid >> 2, d0 = (tid & 3) * 8;
    float L = (float)NN;
    float a[8] = {0.f, 0.f, 0.f, 0.f, 0.f, 0.f, 0.f, 0.f};
#pragma unroll
    for (int wv = 0; wv < 4; ++wv) {
        L += ps_lds[wv][q];
        const float* row = &acc_lds[wv][q][d0];
#pragma unroll
        for (int j = 0; j < 8; ++j) a[j] += row[j];
    }
    const float* vs = vsum + bh * DH + d0;
    float rl = 1.f / L;
    uint4 o;
    o.x = pk2((a[0] + vs[0]) * rl, (a[1] + vs[1]) * rl);
    o.y = pk2((a[2] + vs[2]) * rl, (a[3] + vs[3]) * rl);
    o.z = pk2((a[4] + vs[4]) * rl, (a[5] + vs[5]) * rl);
    o.w = pk2((a[6] + vs[6]) * rl, (a[7] + vs[7]) * rl);
    int b = bh >> 3, h = bh & 7;
    *(uint4*)&aotb[((size_t)b * NN + qbase + q) * 256 + h * DH + d0] = o;
}

// ---------------- output projection MFMA GEMM, 32o x 64n/block ----------------
__global__ __launch_bounds__(64) void k_projm(const short* __restrict__ aotb,
                                              const short* __restrict__ wprojb,
                                              const float* __restrict__ bproj,
                                              float* __restrict__ out) {
    int lane = threadIdx.x, l15 = lane & 15, g = lane >> 4;
    int blk = blockIdx.x;
    int ntg = blk % 36, otg = (blk / 36) % 8, b = blk / (36 * 8);
    int n0 = ntg * 64;
    const short* ab = aotb + (size_t)b * NN * 256;

    v4f acc[2][4];
#pragma unroll
    for (int oa = 0; oa < 2; ++oa)
#pragma unroll
        for (int j = 0; j < 4; ++j) acc[oa][j] = (v4f){0.f, 0.f, 0.f, 0.f};
#pragma unroll
    for (int kk = 0; kk < 8; ++kk) {
        v8s A0 = *(const v8s*)(wprojb + (size_t)(otg * 32 + l15) * 256 + kk * 32 + 8 * g);
        v8s A1 = *(const v8s*)(wprojb + (size_t)(otg * 32 + 16 + l15) * 256 + kk * 32 + 8 * g);
#pragma unroll
        for (int j = 0; j < 4; ++j) {
            v8s B = *(const v8s*)(ab + (size_t)(n0 + j * 16 + l15) * 256 + kk * 32 + 8 * g);
            acc[0][j] = __builtin_amdgcn_mfma_f32_16x16x32_bf16(A0, B, acc[0][j], 0, 0, 0);
            acc[1][j] = __builtin_amdgcn_mfma_f32_16x16x32_bf16(A1, B, acc[1][j], 0, 0, 0);
        }
    }
#pragma unroll
    for (int oa = 0; oa < 2; ++oa) {
        v4f bias = *(const v4f*)&bproj[otg * 32 + oa * 16 + 4 * g];
#pragma unroll
        for (int j = 0; j < 4; ++j) {
#pragma unroll
            for (int r = 0; r < 4; ++r) {
                int o = otg * 32 + oa * 16 + 4 * g + r;
                out[((size_t)b * 256 + o) * NN + n0 + j * 16 + l15] = acc[oa][j][r] + bias[r];
            }
        }
    }
}

extern "C" void kernel_launch(void* const* d_in, const int* in_sizes, int n_in,
                              void* d_out, int out_size, void* d_ws, size_t ws_size,
                              hipStream_t stream) {
    const float* x     = (const float*)d_in[0];
    const float* luma  = (const float*)d_in[1];
    const float* wqkv  = (const float*)d_in[2];
    const float* bqkv  = (const float*)d_in[3];
    const float* wproj = (const float*)d_in[4];
    const float* bproj = (const float*)d_in[5];
    const float* wc1   = (const float*)d_in[6];
    const float* bc1   = (const float*)d_in[7];
    const float* wc2   = (const float*)d_in[8];
    const float* bc2   = (const float*)d_in[9];
    const float* wg    = (const float*)d_in[10];
    const float* bg    = (const float*)d_in[11];
    const float* wbt   = (const float*)d_in[12];
    const float* bbt   = (const float*)d_in[13];
    const float* alpha = (const float*)d_in[14];
    float* out = (float*)d_out;

    float* ws = (float*)d_ws;
    size_t off = 0;
    float* twc1 = ws + off;            off += 9 * 128;
    short* tc2b = (short*)(ws + off);  off += 9 * 128 * 128 / 2;
    short* wqkvb = (short*)(ws + off); off += 768 * 256 / 2;
    short* wgb = (short*)(ws + off);   off += 256 * 128 / 2;
    short* wbtb = (short*)(ws + off);  off += 256 * 128 / 2;
    short* wprojb = (short*)(ws + off); off += 256 * 256 / 2;
    short* h1p = (short*)(ws + off);   off += NB * 2500 * 128 / 2;
    short* xt = (short*)(ws + off);    off += NB * NN * 256 / 2;
    short* h2t = (short*)(ws + off);   off += NB * NN * 128 / 2;
    short* gtb = (short*)(ws + off);   off += NB * NN * 256 / 2;
    short* bttb = (short*)(ws + off);  off += NB * NN * 256 / 2;
    float* invl = ws + off;            off += NB * NN;
    short* qbb = (short*)(ws + off);   off += 16 * NN * DH / 2;
    short* kbb = (short*)(ws + off);   off += 16 * NN * DH / 2;
    short* vraw = (short*)(ws + off);  off += 16 * NN * DH / 2;
    short* vtb = (short*)(ws + off);   off += 16 * NN * DH / 2;   // blocked [bh][72][32][32]
    float* vsum = ws + off;            off += 16 * DH;
    short* aotb = (short*)(ws + off);  off += NB * NN * 256 / 2;
    (void)ws_size; (void)in_sizes; (void)n_in; (void)out_size;

    k_prep<<<768, 256, 0, stream>>>(wc1, wc2, wqkv, wg, wbt, wproj,
                                    twc1, tc2b, wqkvb, wgb, wbtb, wprojb, vsum);
    k_front<<<NB * 144 + NB + NB * 1250, 256, 0, stream>>>(x, xt, luma, invl, twc1, bc1, h1p);
    k_conv2m<<<NB * 8 * 36, 64, 0, stream>>>(h1p, tc2b, bc2, h2t);
    k_gbm<<<NB * 16 * 36, 64, 0, stream>>>(h2t, wgb, wbtb, bg, bbt, gtb, bttb);
    k_qkvm<<<NB * 24 * 36, 64, 0, stream>>>(xt, wqkvb, bqkv, gtb, bttb, invl, alpha,
                                            qbb, kbb, vraw);
    k_vt<<<16 * 36, 256, 0, stream>>>(vraw, vtb, vsum);
    k_attn2<<<576, 256, 0, stream>>>(qbb, kbb, vtb, vsum, aotb);
    k_projm<<<NB * 8 * 36, 64, 0, stream>>>(aotb, wprojb, bproj, out);
}

// Round 10
// 98.571 us; speedup vs baseline: 5.2193x; 1.1259x over previous
//
#include <hip/hip_runtime.h>
#include <hip/hip_bf16.h>
#include <math.h>
#include <string.h>

#define NB 2
#define NN 2304        // 48*48
#define NHEADS 8
#define DH 32
#define AW 8           // waves per attn block
#define KPW 288        // keys per wave (NN/8)

typedef __attribute__((ext_vector_type(8))) short v8s;   // 8 bf16 in 4 VGPRs
typedef __attribute__((ext_vector_type(4))) float v4f;

__device__ inline unsigned short f2b(float f) {          // fp32 -> bf16 (RNE)
    unsigned u = __builtin_bit_cast(unsigned, f);
    unsigned r = u + 0x7FFFu + ((u >> 16) & 1u);
    return (unsigned short)(r >> 16);
}
__device__ inline float b2f(short s) {
    unsigned u = ((unsigned)(unsigned short)s) << 16;
    return __builtin_bit_cast(float, u);
}
__device__ inline unsigned pk2(float a, float b) {       // 2 fp32 -> packed bf16x2
    __hip_bfloat162 h = __float22bfloat162_rn(make_float2(a, b));
    unsigned r;
    memcpy(&r, &h, sizeof(r));
    return r;
}
__device__ inline float blo(unsigned u) { return __builtin_bit_cast(float, u << 16); }
__device__ inline float bhi(unsigned u) { return __builtin_bit_cast(float, u & 0xffff0000u); }

// ---------------- weight prep: transposes + bf16 conversion + vsum zero ----------------
__global__ void k_prep(const float* __restrict__ wc1, const float* __restrict__ wc2,
                       const float* __restrict__ wqkv, const float* __restrict__ wg,
                       const float* __restrict__ wbt, const float* __restrict__ wproj,
                       float* __restrict__ twc1, short* __restrict__ tc2b,
                       short* __restrict__ wqkvb, short* __restrict__ wgb,
                       short* __restrict__ wbtb, short* __restrict__ wprojb,
                       float* __restrict__ vsum) {
    int i = blockIdx.x * 256 + threadIdx.x;            // 196608 threads
    if (i < 16 * DH) vsum[i] = 0.f;
    if (i < 9 * 128) {                                 // twc1[k][c] = wc1[c][k]
        int k = i / 128, c = i % 128;
        twc1[i] = wc1[c * 9 + k];
    }
    if (i < 9 * 128 * 128) {                           // tc2b[s][o][ic] = wc2[o][ic][s]
        int s = i / (128 * 128);
        int rem = i % (128 * 128);
        int o = rem / 128, ic = rem % 128;
        tc2b[i] = (short)f2b(wc2[(o * 128 + ic) * 9 + s]);
    }
    if (i < 768 * 256) wqkvb[i] = (short)f2b(wqkv[i]);
    if (i < 256 * 128) { wgb[i] = (short)f2b(wg[i]); wbtb[i] = (short)f2b(wbt[i]); }
    if (i < 256 * 256) wprojb[i] = (short)f2b(wproj[i]);
}

// ---------------- fused: x transpose | invL | conv1 ----------------
__global__ void k_front(const float* __restrict__ x, short* __restrict__ xt,
                        const float* __restrict__ luma, float* __restrict__ invl,
                        const float* __restrict__ twc1, const float* __restrict__ bc1,
                        short* __restrict__ h1p) {
    __shared__ unsigned short lds[64 * 66];
    __shared__ float red[256];
    int blk = blockIdx.x;
    if (blk >= NB * 144 + NB) {
        // ---- conv1 -> h1p padded(50x50) transposed [b][p][128] bf16 ----
        int cb = blk - (NB * 144 + NB);
        int c = threadIdx.x & 127;
        int p = (cb % 1250) * 2 + (threadIdx.x >> 7);
        int b = cb / 1250;
        int py = p / 50, px = p % 50;
        float val = 0.f;
        if (py >= 1 && py <= 48 && px >= 1 && px <= 48) {
            int y = py - 1, xx0 = px - 1;
            const float* lb = luma + b * NN;
            float acc = bc1[c];
#pragma unroll
            for (int ky = 0; ky < 3; ++ky) {
                int yy = y + ky - 1;
                if (yy < 0 || yy >= 48) continue;
#pragma unroll
                for (int kx = 0; kx < 3; ++kx) {
                    int xx = xx0 + kx - 1;
                    if (xx < 0 || xx >= 48) continue;
                    acc += twc1[(ky * 3 + kx) * 128 + c] * lb[yy * 48 + xx];
                }
            }
            val = fmaxf(acc, 0.f);
        }
        h1p[((size_t)b * 2500 + p) * 128 + c] = (short)f2b(val);
        return;
    }
    if (blk >= NB * 144) {
        // ---- invL: avgpool3x3(1-luma) centered per batch ----
        int b = blk - NB * 144;
        const float* lb = luma + b * NN;
        float pooled[9];
        float local = 0.f;
#pragma unroll
        for (int it = 0; it < 9; ++it) {
            int n = it * 256 + threadIdx.x;
            int y = n / 48, xx0 = n % 48;
            float s = 0.f;
            for (int ky = 0; ky < 3; ++ky) {
                int yy = y + ky - 1;
                if (yy < 0 || yy >= 48) continue;
                for (int kx = 0; kx < 3; ++kx) {
                    int xx = xx0 + kx - 1;
                    if (xx < 0 || xx >= 48) continue;
                    s += 1.f - lb[yy * 48 + xx];
                }
            }
            s *= (1.f / 9.f);
            pooled[it] = s;
            local += s;
        }
        red[threadIdx.x] = local;
        __syncthreads();
        for (int off = 128; off > 0; off >>= 1) {
            if (threadIdx.x < off) red[threadIdx.x] += red[threadIdx.x + off];
            __syncthreads();
        }
        float mean = red[0] * (1.f / NN);
#pragma unroll
        for (int it = 0; it < 9; ++it) {
            int n = it * 256 + threadIdx.x;
            invl[b * NN + n] = pooled[it] - mean;
        }
        return;
    }
    // ---- x transpose: [b][256][2304] fp32 -> xt [b][2304][256] bf16 ----
    int nt = blk % 36, ct = (blk / 36) % 4, b = blk / 144;
    int n0 = nt * 64, c0 = ct * 64;
    int nc = threadIdx.x & 63, cr = threadIdx.x >> 6;
#pragma unroll
    for (int i = 0; i < 16; ++i) {
        int cs = i * 4 + cr;
        float v = x[((size_t)b * 256 + c0 + cs) * NN + n0 + nc];
        lds[nc * 66 + cs] = f2b(v);
    }
    __syncthreads();
    int cc = threadIdx.x & 31, nr = threadIdx.x >> 5;
    unsigned* xt2 = (unsigned*)xt;
#pragma unroll
    for (int j = 0; j < 8; ++j) {
        int ns = j * 8 + nr;
        unsigned w = *(unsigned*)&lds[ns * 66 + 2 * cc];
        xt2[(((size_t)b * NN + n0 + ns) * 256 + c0) / 2 + cc] = w;
    }
}

// ---------------- conv2 as 9-shift MFMA GEMM, 4 n-tiles/block ----------------
__global__ __launch_bounds__(64) void k_conv2m(const short* __restrict__ h1p,
                                               const short* __restrict__ tc2b,
                                               const float* __restrict__ bc2,
                                               short* __restrict__ h2t) {
    int lane = threadIdx.x, l15 = lane & 15, g = lane >> 4;
    int blk = blockIdx.x;
    int ntg = blk % 36, ot = (blk / 36) % 8, b = blk / (36 * 8);
    int p0[4], na[4];
#pragma unroll
    for (int j = 0; j < 4; ++j) {
        int nt = ntg * 4 + j;
        int y = nt / 3, xx = (nt % 3) * 16;
        p0[j] = (y + 1) * 50 + xx + 1;
        na[j] = y * 48 + xx + l15;
    }
    const short* hb = h1p + (size_t)b * 2500 * 128;

    v4f acc[4] = {{0.f,0.f,0.f,0.f},{0.f,0.f,0.f,0.f},{0.f,0.f,0.f,0.f},{0.f,0.f,0.f,0.f}};
#pragma unroll
    for (int s = 0; s < 9; ++s) {
        int dp = (s / 3 - 1) * 50 + (s % 3 - 1);
#pragma unroll
        for (int kk = 0; kk < 4; ++kk) {
            v8s A = *(const v8s*)(tc2b + ((size_t)(s * 128 + ot * 16 + l15)) * 128 + kk * 32 + 8 * g);
#pragma unroll
            for (int j = 0; j < 4; ++j) {
                v8s B = *(const v8s*)(hb + (size_t)(p0[j] + dp + l15) * 128 + kk * 32 + 8 * g);
                acc[j] = __builtin_amdgcn_mfma_f32_16x16x32_bf16(A, B, acc[j], 0, 0, 0);
            }
        }
    }
    v4f bias = *(const v4f*)&bc2[ot * 16 + 4 * g];
#pragma unroll
    for (int j = 0; j < 4; ++j) {
        uint2 w;
        w.x = pk2(fmaxf(acc[j][0] + bias[0], 0.f), fmaxf(acc[j][1] + bias[1], 0.f));
        w.y = pk2(fmaxf(acc[j][2] + bias[2], 0.f), fmaxf(acc[j][3] + bias[3], 0.f));
        *(uint2*)&h2t[((size_t)b * NN + na[j]) * 128 + ot * 16 + 4 * g] = w;
    }
}

// ---------------- gamma/beta MFMA GEMMs, 64 n/block -> gtb/bttb bf16 [b][n][256] ----------------
__global__ __launch_bounds__(64) void k_gbm(const short* __restrict__ h2t,
                                            const short* __restrict__ wgb,
                                            const short* __restrict__ wbtb,
                                            const float* __restrict__ bg,
                                            const float* __restrict__ bbt,
                                            short* __restrict__ gtb, short* __restrict__ bttb) {
    int lane = threadIdx.x, l15 = lane & 15, g = lane >> 4;
    int blk = blockIdx.x;
    int ntg = blk % 36, ot = (blk / 36) % 16, b = blk / (36 * 16);
    int n0 = ntg * 64;
    const short* hb = h2t + (size_t)b * NN * 128;

    v4f ga[4] = {{0.f,0.f,0.f,0.f},{0.f,0.f,0.f,0.f},{0.f,0.f,0.f,0.f},{0.f,0.f,0.f,0.f}};
    v4f ta[4] = {{0.f,0.f,0.f,0.f},{0.f,0.f,0.f,0.f},{0.f,0.f,0.f,0.f},{0.f,0.f,0.f,0.f}};
#pragma unroll
    for (int kk = 0; kk < 4; ++kk) {
        v8s Ag = *(const v8s*)(wgb + (size_t)(ot * 16 + l15) * 128 + kk * 32 + 8 * g);
        v8s At = *(const v8s*)(wbtb + (size_t)(ot * 16 + l15) * 128 + kk * 32 + 8 * g);
#pragma unroll
        for (int j = 0; j < 4; ++j) {
            v8s B = *(const v8s*)(hb + (size_t)(n0 + j * 16 + l15) * 128 + kk * 32 + 8 * g);
            ga[j] = __builtin_amdgcn_mfma_f32_16x16x32_bf16(Ag, B, ga[j], 0, 0, 0);
            ta[j] = __builtin_amdgcn_mfma_f32_16x16x32_bf16(At, B, ta[j], 0, 0, 0);
        }
    }
    v4f bgv = *(const v4f*)&bg[ot * 16 + 4 * g];
    v4f bbv = *(const v4f*)&bbt[ot * 16 + 4 * g];
#pragma unroll
    for (int j = 0; j < 4; ++j) {
        size_t o = ((size_t)b * NN + n0 + j * 16 + l15) * 256 + ot * 16 + 4 * g;
        uint2 w;
        w.x = pk2(ga[j][0] + bgv[0], ga[j][1] + bgv[1]);
        w.y = pk2(ga[j][2] + bgv[2], ga[j][3] + bgv[3]);
        *(uint2*)&gtb[o] = w;
        w.x = pk2(ta[j][0] + bbv[0], ta[j][1] + bbv[1]);
        w.y = pk2(ta[j][2] + bbv[2], ta[j][3] + bbv[3]);
        *(uint2*)&bttb[o] = w;
    }
}

// ---------------- qkv MFMA GEMM, 32oc x 64n/block + modulation epilogue ----------------
__global__ __launch_bounds__(64) void k_qkvm(const short* __restrict__ xt,
                                             const short* __restrict__ wqkvb,
                                             const float* __restrict__ bqkv,
                                             const short* __restrict__ gtb,
                                             const short* __restrict__ bttb,
                                             const float* __restrict__ invl,
                                             const float* __restrict__ alpha_p,
                                             short* __restrict__ qb, short* __restrict__ kb,
                                             short* __restrict__ vraw) {
    int lane = threadIdx.x, l15 = lane & 15, g = lane >> 4;
    int blk = blockIdx.x;
    int ntg = blk % 36, otg = (blk / 36) % 24, b = blk / (36 * 24);
    int n0 = ntg * 64;
    const short* xb = xt + (size_t)b * NN * 256;

    v4f acc[2][4];
#pragma unroll
    for (int oa = 0; oa < 2; ++oa)
#pragma unroll
        for (int j = 0; j < 4; ++j) acc[oa][j] = (v4f){0.f, 0.f, 0.f, 0.f};
#pragma unroll
    for (int kk = 0; kk < 8; ++kk) {
        v8s A0 = *(const v8s*)(wqkvb + (size_t)(otg * 32 + l15) * 256 + kk * 32 + 8 * g);
        v8s A1 = *(const v8s*)(wqkvb + (size_t)(otg * 32 + 16 + l15) * 256 + kk * 32 + 8 * g);
#pragma unroll
        for (int j = 0; j < 4; ++j) {
            v8s B = *(const v8s*)(xb + (size_t)(n0 + j * 16 + l15) * 256 + kk * 32 + 8 * g);
            acc[0][j] = __builtin_amdgcn_mfma_f32_16x16x32_bf16(A0, B, acc[0][j], 0, 0, 0);
            acc[1][j] = __builtin_amdgcn_mfma_f32_16x16x32_bf16(A1, B, acc[1][j], 0, 0, 0);
        }
    }
    const float scale = 0.25503486f;     // 32^-0.5 * log2(e)
    float alpha = *alpha_p;
#pragma unroll
    for (int oa = 0; oa < 2; ++oa) {
        int ocb = otg * 32 + oa * 16;
        int which = ocb >> 8;
        int cbase = (ocb & 255) + 4 * g;
        int h = cbase >> 5, dbase = cbase & 31;
        v4f bias = *(const v4f*)&bqkv[ocb + 4 * g];
        short* dst = (which == 0) ? qb : (which == 1) ? kb : vraw;
#pragma unroll
        for (int j = 0; j < 4; ++j) {
            int n = n0 + j * 16 + l15;
            v4f a = acc[oa][j];
            uint2 gg = *(const uint2*)&gtb[((size_t)b * NN + n) * 256 + cbase];
            uint2 tt = *(const uint2*)&bttb[((size_t)b * NN + n) * 256 + cbase];
            float iv = (which == 0) ? alpha * invl[b * NN + n] : 0.f;
            float v0 = blo(gg.x) * (a[0] + bias[0]) + blo(tt.x);
            float v1 = bhi(gg.x) * (a[1] + bias[1]) + bhi(tt.x);
            float v2 = blo(gg.y) * (a[2] + bias[2]) + blo(tt.y);
            float v3 = bhi(gg.y) * (a[3] + bias[3]) + bhi(tt.y);
            if (which == 0) {
                v0 = (v0 + iv) * scale; v1 = (v1 + iv) * scale;
                v2 = (v2 + iv) * scale; v3 = (v3 + iv) * scale;
            }
            uint2 w;
            w.x = pk2(v0, v1);
            w.y = pk2(v2, v3);
            *(uint2*)&dst[(((size_t)b * NHEADS + h) * NN + n) * DH + dbase] = w;
        }
    }
}

// ---------------- V transpose -> vtb blocked [bh][72][32d][32k] + vsum atomics ----------------
__global__ void k_vt(const short* __restrict__ vraw, short* __restrict__ vtb,
                     float* __restrict__ vsum) {
    __shared__ unsigned short lds[64 * 34];
    int bh = blockIdx.x / 36, nc = blockIdx.x % 36;
    int n0 = nc * 64;
    int dpair = threadIdx.x & 15, nsub = (threadIdx.x >> 4) & 15;
    const unsigned* vr2 = (const unsigned*)vraw;
#pragma unroll
    for (int i = 0; i < 4; ++i) {
        int ns = i * 16 + nsub;
        unsigned v = vr2[((size_t)bh * NN + n0 + ns) * 16 + dpair];
        *(unsigned*)&lds[ns * 34 + 2 * dpair] = v;
    }
    __syncthreads();
    int pn = threadIdx.x & 31, drow = threadIdx.x >> 5;
    int kb0 = n0 >> 5;
    unsigned* vtb2 = (unsigned*)vtb;
#pragma unroll
    for (int j = 0; j < 4; ++j) {
        int d = j * 8 + drow;
        unsigned lo = lds[(2 * pn) * 34 + d];
        unsigned hi = lds[(2 * pn + 1) * 34 + d];
        vtb2[(((size_t)bh * 72 + kb0 + (pn >> 4)) * 32 + d) * 16 + (pn & 15)] = lo | (hi << 16);
    }
    if (threadIdx.x < 32) {
        int d = threadIdx.x;
        float s = 0.f;
        for (int ns = 0; ns < 64; ++ns) s += b2f((short)lds[ns * 34 + d]);
        atomicAdd(&vsum[bh * DH + d], s);
    }
}

// ---------------- fused attention: QBLK=32, 8 waves split K in-block, bf16 LDS merge ----------------
// grid 1152 (XCD-swizzled), block 512.  p' = exp2(s)-1 (s pre-scaled by log2e).
// out = (vsum + sum_k p'*v) / (NN + sum_k p'); row-sums via MFMA ones-trick.
__global__ __launch_bounds__(512) void k_attn2(const short* __restrict__ qb,
                                               const short* __restrict__ kbuf,
                                               const short* __restrict__ vtb,
                                               const float* __restrict__ vsum,
                                               short* __restrict__ aotb) {
    __shared__ short plds[AW][32 * 40];     // per-wave P' tile, 32 rows x 80 B
    __shared__ short acch[AW][32][33];      // per-wave partial O (bf16), pad 33
    __shared__ float ps_lds[AW][32];        // per-wave row-sums of p'
    int tid = threadIdx.x;
    int w = tid >> 6, lane = tid & 63;
    int l15 = lane & 15, g = lane >> 4;
    int blk = blockIdx.x;
    int logical = (blk & 7) * 144 + (blk >> 3);   // XCD swizzle: 1152 = 8*144
    int qt = logical % 72, bh = logical / 72;
    int qbase = qt * 32;

    const short* qp = qb + ((size_t)bh * NN + qbase) * DH;
    const short* kp = kbuf + ((size_t)bh * NN + w * KPW) * DH;
    const short* vp = vtb + ((size_t)bh * 72 + w * (KPW / 32)) * 1024;  // 32x32 tiles

    v8s q0 = *(const v8s*)(qp + l15 * DH + 8 * g);
    v8s q1 = *(const v8s*)(qp + (16 + l15) * DH + 8 * g);

    const short one_b = (short)0x3F80;      // bf16 1.0
    const v8s ones = {one_b, one_b, one_b, one_b, one_b, one_b, one_b, one_b};

    v4f acc00 = {0.f,0.f,0.f,0.f}, acc01 = acc00, acc10 = acc00, acc11 = acc00;
    v4f ps0 = {0.f,0.f,0.f,0.f}, ps1 = ps0;
    short* pw = plds[w];

    for (int it = 0; it < KPW / 32; ++it) {
        const short* kpi = kp + it * 32 * DH;
        v8s ka0 = *(const v8s*)(kpi + l15 * DH + 8 * g);
        v8s ka1 = *(const v8s*)(kpi + (16 + l15) * DH + 8 * g);
        v4f s00 = __builtin_amdgcn_mfma_f32_16x16x32_bf16(ka0, q0, (v4f){0.f,0.f,0.f,0.f}, 0, 0, 0);
        v4f s01 = __builtin_amdgcn_mfma_f32_16x16x32_bf16(ka0, q1, (v4f){0.f,0.f,0.f,0.f}, 0, 0, 0);
        v4f s10 = __builtin_amdgcn_mfma_f32_16x16x32_bf16(ka1, q0, (v4f){0.f,0.f,0.f,0.f}, 0, 0, 0);
        v4f s11 = __builtin_amdgcn_mfma_f32_16x16x32_bf16(ka1, q1, (v4f){0.f,0.f,0.f,0.f}, 0, 0, 0);

        // p' = v_exp(s)-1; stash P'^T -> LDS as row-major P'[q][k] bf16
#define DOFRAG(S, QF, KT)                                                        \
        {                                                                        \
            float p0 = __builtin_amdgcn_exp2f((S)[0]) - 1.f;                     \
            float p1 = __builtin_amdgcn_exp2f((S)[1]) - 1.f;                     \
            float p2 = __builtin_amdgcn_exp2f((S)[2]) - 1.f;                     \
            float p3 = __builtin_amdgcn_exp2f((S)[3]) - 1.f;                     \
            uint2 wv;                                                            \
            wv.x = pk2(p0, p1);                                                  \
            wv.y = pk2(p2, p3);                                                  \
            *(uint2*)((char*)pw + ((QF) * 16 + l15) * 80 + ((KT) * 16 + 4 * g) * 2) = wv; \
        }
        DOFRAG(s00, 0, 0)
        DOFRAG(s01, 1, 0)
        DOFRAG(s10, 0, 1)
        DOFRAG(s11, 1, 1)
#undef DOFRAG
        // per-wave private LDS slice: wave-ordered DS, no barrier needed
        v8s pa0 = *(v8s*)((char*)pw + l15 * 80 + 16 * g);
        v8s pa1 = *(v8s*)((char*)pw + (16 + l15) * 80 + 16 * g);
        const short* vpi = vp + it * 1024;
        v8s vb0 = *(const v8s*)(vpi + l15 * 32 + 8 * g);
        v8s vb1 = *(const v8s*)(vpi + (16 + l15) * 32 + 8 * g);
        __builtin_amdgcn_s_setprio(1);
        acc00 = __builtin_amdgcn_mfma_f32_16x16x32_bf16(pa0, vb0, acc00, 0, 0, 0);
        acc01 = __builtin_amdgcn_mfma_f32_16x16x32_bf16(pa0, vb1, acc01, 0, 0, 0);
        acc10 = __builtin_amdgcn_mfma_f32_16x16x32_bf16(pa1, vb0, acc10, 0, 0, 0);
        acc11 = __builtin_amdgcn_mfma_f32_16x16x32_bf16(pa1, vb1, acc11, 0, 0, 0);
        ps0 = __builtin_amdgcn_mfma_f32_16x16x32_bf16(pa0, ones, ps0, 0, 0, 0);
        ps1 = __builtin_amdgcn_mfma_f32_16x16x32_bf16(pa1, ones, ps1, 0, 0, 0);
        __builtin_amdgcn_s_setprio(0);
    }

    // ps[r] = rowsum(q = 4g+r), identical across l15 -> one lane-group writes
    if (l15 == 0) {
#pragma unroll
        for (int r = 0; r < 4; ++r) {
            ps_lds[w][4 * g + r] = ps0[r];
            ps_lds[w][16 + 4 * g + r] = ps1[r];
        }
    }
    // dump partial acc (bf16) to LDS: frag (QF,DT) value r -> q = QF*16+4g+r, d = DT*16+l15
#pragma unroll
    for (int r = 0; r < 4; ++r) {
        acch[w][4 * g + r][l15]      = (short)f2b(acc00[r]);
        acch[w][4 * g + r][16 + l15] = (short)f2b(acc01[r]);
        acch[w][16 + 4 * g + r][l15]      = (short)f2b(acc10[r]);
        acch[w][16 + 4 * g + r][16 + l15] = (short)f2b(acc11[r]);
    }
    __syncthreads();

    // cooperative merge: thread t -> q = t>>4 (32), dp = t&15 -> d0 = 2*dp
    int q = tid >> 4, d0 = (tid & 15) * 2;
    float L = (float)NN;
    float a0 = 0.f, a1 = 0.f;
#pragma unroll
    for (int wv = 0; wv < AW; ++wv) {
        L += ps_lds[wv][q];
        a0 += b2f(acch[wv][q][d0]);
        a1 += b2f(acch[wv][q][d0 + 1]);
    }
    const float* vs = vsum + bh * DH + d0;
    float rl = 1.f / L;
    unsigned o = pk2((a0 + vs[0]) * rl, (a1 + vs[1]) * rl);
    int b = bh >> 3, h = bh & 7;
    *(unsigned*)&aotb[((size_t)b * NN + qbase + q) * 256 + h * DH + d0] = o;
}

// ---------------- output projection MFMA GEMM, 32o x 64n/block ----------------
__global__ __launch_bounds__(64) void k_projm(const short* __restrict__ aotb,
                                              const short* __restrict__ wprojb,
                                              const float* __restrict__ bproj,
                                              float* __restrict__ out) {
    int lane = threadIdx.x, l15 = lane & 15, g = lane >> 4;
    int blk = blockIdx.x;
    int ntg = blk % 36, otg = (blk / 36) % 8, b = blk / (36 * 8);
    int n0 = ntg * 64;
    const short* ab = aotb + (size_t)b * NN * 256;

    v4f acc[2][4];
#pragma unroll
    for (int oa = 0; oa < 2; ++oa)
#pragma unroll
        for (int j = 0; j < 4; ++j) acc[oa][j] = (v4f){0.f, 0.f, 0.f, 0.f};
#pragma unroll
    for (int kk = 0; kk < 8; ++kk) {
        v8s A0 = *(const v8s*)(wprojb + (size_t)(otg * 32 + l15) * 256 + kk * 32 + 8 * g);
        v8s A1 = *(const v8s*)(wprojb + (size_t)(otg * 32 + 16 + l15) * 256 + kk * 32 + 8 * g);
#pragma unroll
        for (int j = 0; j < 4; ++j) {
            v8s B = *(const v8s*)(ab + (size_t)(n0 + j * 16 + l15) * 256 + kk * 32 + 8 * g);
            acc[0][j] = __builtin_amdgcn_mfma_f32_16x16x32_bf16(A0, B, acc[0][j], 0, 0, 0);
            acc[1][j] = __builtin_amdgcn_mfma_f32_16x16x32_bf16(A1, B, acc[1][j], 0, 0, 0);
        }
    }
#pragma unroll
    for (int oa = 0; oa < 2; ++oa) {
        v4f bias = *(const v4f*)&bproj[otg * 32 + oa * 16 + 4 * g];
#pragma unroll
        for (int j = 0; j < 4; ++j) {
#pragma unroll
            for (int r = 0; r < 4; ++r) {
                int o = otg * 32 + oa * 16 + 4 * g + r;
                out[((size_t)b * 256 + o) * NN + n0 + j * 16 + l15] = acc[oa][j][r] + bias[r];
            }
        }
    }
}

extern "C" void kernel_launch(void* const* d_in, const int* in_sizes, int n_in,
                              void* d_out, int out_size, void* d_ws, size_t ws_size,
                              hipStream_t stream) {
    const float* x     = (const float*)d_in[0];
    const float* luma  = (const float*)d_in[1];
    const float* wqkv  = (const float*)d_in[2];
    const float* bqkv  = (const float*)d_in[3];
    const float* wproj = (const float*)d_in[4];
    const float* bproj = (const float*)d_in[5];
    const float* wc1   = (const float*)d_in[6];
    const float* bc1   = (const float*)d_in[7];
    const float* wc2   = (const float*)d_in[8];
    const float* bc2   = (const float*)d_in[9];
    const float* wg    = (const float*)d_in[10];
    const float* bg    = (const float*)d_in[11];
    const float* wbt   = (const float*)d_in[12];
    const float* bbt   = (const float*)d_in[13];
    const float* alpha = (const float*)d_in[14];
    float* out = (float*)d_out;

    float* ws = (float*)d_ws;
    size_t off = 0;
    float* twc1 = ws + off;            off += 9 * 128;
    short* tc2b = (short*)(ws + off);  off += 9 * 128 * 128 / 2;
    short* wqkvb = (short*)(ws + off); off += 768 * 256 / 2;
    short* wgb = (short*)(ws + off);   off += 256 * 128 / 2;
    short* wbtb = (short*)(ws + off);  off += 256 * 128 / 2;
    short* wprojb = (short*)(ws + off); off += 256 * 256 / 2;
    short* h1p = (short*)(ws + off);   off += NB * 2500 * 128 / 2;
    short* xt = (short*)(ws + off);    off += NB * NN * 256 / 2;
    short* h2t = (short*)(ws + off);   off += NB * NN * 128 / 2;
    short* gtb = (short*)(ws + off);   off += NB * NN * 256 / 2;
    short* bttb = (short*)(ws + off);  off += NB * NN * 256 / 2;
    float* invl = ws + off;            off += NB * NN;
    short* qbb = (short*)(ws + off);   off += 16 * NN * DH / 2;
    short* kbb = (short*)(ws + off);   off += 16 * NN * DH / 2;
    short* vraw = (short*)(ws + off);  off += 16 * NN * DH / 2;
    short* vtb = (short*)(ws + off);   off += 16 * NN * DH / 2;   // blocked [bh][72][32][32]
    float* vsum = ws + off;            off += 16 * DH;
    short* aotb = (short*)(ws + off);  off += NB * NN * 256 / 2;
    (void)ws_size; (void)in_sizes; (void)n_in; (void)out_size;

    k_prep<<<768, 256, 0, stream>>>(wc1, wc2, wqkv, wg, wbt, wproj,
                                    twc1, tc2b, wqkvb, wgb, wbtb, wprojb, vsum);
    k_front<<<NB * 144 + NB + NB * 1250, 256, 0, stream>>>(x, xt, luma, invl, twc1, bc1, h1p);
    k_conv2m<<<NB * 8 * 36, 64, 0, stream>>>(h1p, tc2b, bc2, h2t);
    k_gbm<<<NB * 16 * 36, 64, 0, stream>>>(h2t, wgb, wbtb, bg, bbt, gtb, bttb);
    k_qkvm<<<NB * 24 * 36, 64, 0, stream>>>(xt, wqkvb, bqkv, gtb, bttb, invl, alpha,
                                            qbb, kbb, vraw);
    k_vt<<<16 * 36, 256, 0, stream>>>(vraw, vtb, vsum);
    k_attn2<<<1152, 512, 0, stream>>>(qbb, kbb, vtb, vsum, aotb);
    k_projm<<<NB * 8 * 36, 64, 0, stream>>>(aotb, wprojb, bproj, out);
}